// Round 1
// baseline (35464.719 us; speedup 1.0000x reference)
//
#include <hip/hip_runtime.h>
#include <math.h>

#define BB 128
#define SS 72
#define NITER 16
#define D_IN 512
#define D_MODEL 1024
#define MEMN 25
#define HEADS 8
#define DHH 64
#define N_SO 256
#define N_SA 64
#define SA_SZ 2080
#define SO_SZ 32896
#define NCLS 1968
#define TED 128
#define ROWS (BB*SS)
#define TRACE_SLOTS (MEMN + NITER)   /* 41 */
#define KS 16
#define KLEN 2056                    /* 32896/16 */

__device__ __forceinline__ float sigmoidf_(float x){ return 1.f/(1.f+expf(-x)); }

__device__ __forceinline__ float bsum256(float v, float* red){
  int tid = threadIdx.x; red[tid] = v; __syncthreads();
#pragma unroll
  for (int s = 128; s > 0; s >>= 1){ if (tid < s) red[tid] += red[tid+s]; __syncthreads(); }
  float r = red[0]; __syncthreads(); return r;
}

__device__ __forceinline__ long triu_off(int n, int i){
  return (long)i*n - ((long)i*(i-1))/2;
}

// ---------------- setup kernels ----------------
__global__ void k_embed(const int* __restrict__ x, const float* __restrict__ emb,
                        float* __restrict__ out){
  int gid = blockIdx.x*256 + threadIdx.x;
  if (gid >= ROWS*TED) return;
  int row = gid >> 7, k = gid & 127;
  out[gid] = emb[x[row]*TED + k];
}

__global__ void k_init_pairs(int n, int npairs, const float* __restrict__ decay,
                             int2* __restrict__ pairs, float* __restrict__ rv){
  int p = blockIdx.x*256 + threadIdx.x;
  if (p >= npairs) return;
  double nn = (double)n;
  double disc = (2.0*nn+1.0)*(2.0*nn+1.0) - 8.0*(double)p;
  int i = (int)floor(((2.0*nn+1.0) - sqrt(disc))*0.5);
  if (i < 0) i = 0; if (i > n-1) i = n-1;
  while (i+1 < n && triu_off(n, i+1) <= (long)p) i++;
  while (i > 0 && triu_off(n, i) > (long)p) i--;
  int j = i + (int)((long)p - triu_off(n, i));
  pairs[p] = make_int2(i, j);
  float dc = decay[p]; dc = fminf(fmaxf(dc, 0.f), 15.f);
  rv[p] = expf(-dc);
}

__global__ void k_init_act(const float* __restrict__ sa, float* __restrict__ act){
  int gid = blockIdx.x*256 + threadIdx.x;
  if (gid >= BB*D_MODEL) return;
  act[gid] = sa[gid & 1023];
}

__global__ void k_zero(float* __restrict__ p, int n){
  int gid = blockIdx.x*256 + threadIdx.x;
  if (gid < n) p[gid] = 0.f;
}

__global__ void k_init_trace(const float* __restrict__ st, float* __restrict__ trace){
  int gid = blockIdx.x*256 + threadIdx.x;
  if (gid >= BB*MEMN*D_MODEL) return;
  int d = gid & 1023;
  int m = (gid >> 10) % MEMN;
  int b = (gid >> 10) / MEMN;
  trace[(size_t)b*TRACE_SLOTS*D_MODEL + (size_t)m*D_MODEL + d] = st[d*MEMN + m];
}

__global__ void k_init_ao(const float* __restrict__ sa, const int2* __restrict__ pairs,
                          float* __restrict__ ao){
  int p = blockIdx.x*256 + threadIdx.x;
  if (p >= SO_SZ) return;
  int b = blockIdx.y;
  int2 ij = pairs[p];
  ao[(size_t)b*SO_SZ + p] = sa[ij.x]*sa[ij.y];
}

// ---------------- generic fp32 GEMM:  C[M,N] = A[M,K] @ W[wrow0:,wcol0:] (+bias) ----------------
template<int MB, bool ACCUM>
__global__ void k_gemm(const float* __restrict__ A, int lda,
                       const float* __restrict__ W, int ldw, int wrow0, int wcol0,
                       const float* __restrict__ bias,
                       float* __restrict__ C, int ldc, int N, int K){
  constexpr int KC = 64;
  const int tid = threadIdx.x;
  const int col = blockIdx.x*256 + tid;
  const int row0 = blockIdx.y*MB;
  __shared__ float As[MB][KC];
  float acc[MB];
#pragma unroll
  for (int r = 0; r < MB; r++) acc[r] = 0.f;
  for (int kk = 0; kk < K; kk += KC){
    const int kc = min(KC, K - kk);
    __syncthreads();
    for (int idx = tid; idx < MB*KC; idx += 256){
      int r = idx >> 6, k = idx & 63;
      As[r][k] = (k < kc) ? A[(size_t)(row0+r)*lda + kk + k] : 0.f;
    }
    __syncthreads();
    for (int k = 0; k < kc; k++){
      float w = W[(size_t)(wrow0+kk+k)*ldw + wcol0 + col];
#pragma unroll
      for (int r = 0; r < MB; r++) acc[r] = fmaf(As[r][k], w, acc[r]);
    }
  }
#pragma unroll
  for (int r = 0; r < MB; r++){
    size_t o = (size_t)(row0+r)*ldc + col;
    if (ACCUM) C[o] += acc[r];
    else       C[o] = acc[r] + bias[col];
  }
}

// ---------------- LayerNorm (block per row) ----------------
__global__ void k_ln(const float* __restrict__ X, const float* __restrict__ g,
                     const float* __restrict__ bta, float* __restrict__ Y, int D){
  const int row = blockIdx.x, tid = threadIdx.x;
  __shared__ float red[256];
  const float* xr = X + (size_t)row*D;
  float s = 0.f;
  for (int c = tid; c < D; c += 256) s += xr[c];
  float mean = bsum256(s, red) / (float)D;
  float s2 = 0.f;
  for (int c = tid; c < D; c += 256){ float d = xr[c]-mean; s2 += d*d; }
  float var = bsum256(s2, red) / (float)D;
  float inv = 1.f / sqrtf(var + 1e-5f);
  float* yr = Y + (size_t)row*D;
  for (int c = tid; c < D; c += 256) yr[c] = (xr[c]-mean)*inv*g[c] + bta[c];
}

// ---------------- GLU + LN -> write state into trace slot ----------------
__global__ void k_glu_ln(const float* __restrict__ syn, const float* __restrict__ g,
                         const float* __restrict__ bta, float* __restrict__ traceSlot){
  const int b = blockIdx.x, tid = threadIdx.x;
  __shared__ float vals[D_MODEL];
  __shared__ float red[256];
  const float* sr = syn + (size_t)b*2048;
  for (int c = tid; c < 1024; c += 256){
    float a = sr[c], gg = sr[c+1024];
    vals[c] = a * sigmoidf_(gg);
  }
  __syncthreads();
  float s = 0.f;
  for (int c = tid; c < 1024; c += 256) s += vals[c];
  float mean = bsum256(s, red) * (1.f/1024.f);
  float s2 = 0.f;
  for (int c = tid; c < 1024; c += 256){ float d = vals[c]-mean; s2 += d*d; }
  float var = bsum256(s2, red) * (1.f/1024.f);
  float inv = 1.f / sqrtf(var + 1e-5f);
  float* out = traceSlot + (size_t)b*(TRACE_SLOTS*D_MODEL);
  for (int c = tid; c < 1024; c += 256) out[c] = (vals[c]-mean)*inv*g[c] + bta[c];
}

// ---------------- attention: block per (b,h), 128 threads ----------------
__global__ void k_attn(const float* __restrict__ qh, const float* __restrict__ Km,
                       const float* __restrict__ Vm, float* __restrict__ o){
  const int bh = blockIdx.x, b = bh >> 3, h = bh & 7;
  const int tid = threadIdx.x;
  __shared__ float qs[DHH];
  __shared__ float attn[SS];
  __shared__ float red[128];
  if (tid < DHH) qs[tid] = qh[(size_t)b*D_IN + h*DHH + tid];
  __syncthreads();
  float sc = -1e30f;
  if (tid < SS){
    const float* kp = Km + ((size_t)(b*SS+tid)*HEADS + h)*DHH;
    float d = 0.f;
#pragma unroll
    for (int i = 0; i < DHH; i++) d = fmaf(qs[i], kp[i], d);
    sc = d * 0.125f;
  }
  red[tid] = sc; __syncthreads();
  for (int s2 = 64; s2 > 0; s2 >>= 1){ if (tid < s2) red[tid] = fmaxf(red[tid], red[tid+s2]); __syncthreads(); }
  float m = red[0]; __syncthreads();
  float e = (tid < SS) ? expf(sc - m) : 0.f;
  red[tid] = e; __syncthreads();
  for (int s2 = 64; s2 > 0; s2 >>= 1){ if (tid < s2) red[tid] += red[tid+s2]; __syncthreads(); }
  float inv = 1.f / red[0]; __syncthreads();
  if (tid < SS) attn[tid] = e * inv;
  __syncthreads();
  if (tid < DHH){
    const float* vp = Vm + ((size_t)(b*SS)*HEADS + h)*DHH + tid;
    float acc = 0.f;
    for (int s2 = 0; s2 < SS; s2++) acc = fmaf(attn[s2], vp[(size_t)s2*D_IN], acc);
    o[(size_t)b*D_IN + h*DHH + tid] = acc;
  }
}

// ---------------- neuron update (trace->tp1->GLU->tp2->GLU) ----------------
__global__ void k_neuron(const float* __restrict__ trace,
                         const float* __restrict__ tp1w, const float* __restrict__ tp1b,
                         const float* __restrict__ tp2w, const float* __restrict__ tp2b,
                         float* __restrict__ act, int t){
  int gid = blockIdx.x*256 + threadIdx.x;
  if (gid >= BB*D_MODEL) return;
  int b = gid >> 10, d = gid & 1023;
  const float* tr = trace + (size_t)b*(TRACE_SLOTS*D_MODEL) + (size_t)(t+1)*D_MODEL + d;
  float trv[MEMN];
#pragma unroll
  for (int m = 0; m < MEMN; m++) trv[m] = tr[(size_t)m*D_MODEL];
  float h[32];
#pragma unroll
  for (int hh = 0; hh < 32; hh++){
    float acc = tp1b[d*32 + hh];
    const float* wp = tp1w + (size_t)hh*1024 + d;
#pragma unroll
    for (int m = 0; m < MEMN; m++) acc = fmaf(trv[m], wp[(size_t)m*32*1024], acc);
    h[hh] = acc;
  }
  float o0 = tp2b[d*2+0], o1 = tp2b[d*2+1];
#pragma unroll
  for (int j = 0; j < 16; j++){
    float hgv = h[j] * sigmoidf_(h[j+16]);
    o0 = fmaf(hgv, tp2w[(size_t)(j*2+0)*1024 + d], o0);
    o1 = fmaf(hgv, tp2w[(size_t)(j*2+1)*1024 + d], o1);
  }
  act[gid] = o0 * sigmoidf_(o1);
}

// ---------------- sync accumulators ----------------
__global__ void k_syncA(const float* __restrict__ act, const float* __restrict__ rv,
                        const int2* __restrict__ pairs, float* __restrict__ aa,
                        float* __restrict__ syncv, int t){
  int p = blockIdx.x*256 + threadIdx.x;
  if (p >= SA_SZ) return;
  int b = blockIdx.y;
  int2 ij = pairs[p];
  const float* ab = act + (size_t)b*D_MODEL + (D_MODEL - N_SA);
  float r = rv[p];
  size_t idx = (size_t)b*SA_SZ + p;
  float a = fmaf(r, aa[idx], ab[ij.x]*ab[ij.y]);
  aa[idx] = a;
  float bb = 0.f;
  for (int i = 0; i <= t; i++) bb = fmaf(r, bb, 1.f);
  syncv[idx] = a / sqrtf(bb);
}

__global__ void k_syncO(const float* __restrict__ act, const float* __restrict__ rv,
                        const int2* __restrict__ pairs, float* __restrict__ ao,
                        float* __restrict__ syncv, int t){
  int p = blockIdx.x*256 + threadIdx.x;
  if (p >= SO_SZ) return;
  int b = blockIdx.y;
  int2 ij = pairs[p];
  const float* ab = act + (size_t)b*D_MODEL;
  float r = rv[p];
  size_t idx = (size_t)b*SO_SZ + p;
  float a = fmaf(r, ao[idx], ab[ij.x]*ab[ij.y]);
  ao[idx] = a;
  float bb = 1.f;
  for (int i = 0; i <= t; i++) bb = fmaf(r, bb, 1.f);
  syncv[idx] = a / sqrtf(bb);
}

// ---------------- big GEMM: part[z] = sync_o @ out_w (k-chunk z), 128x64 tiles ----------------
__global__ void k_bigemm(const float* __restrict__ A, const float* __restrict__ W,
                         float* __restrict__ part){
  const int tid = threadIdx.x;
  const int c0 = blockIdx.x * 64;
  const int z = blockIdx.y;
  const int k0 = z * KLEN;
  const int kend = min(SO_SZ, k0 + KLEN);
  const int cp = tid & 31;
  const int rg = tid >> 5;
  __shared__ float As[128][32];
  float acc0[16], acc1[16];
#pragma unroll
  for (int r = 0; r < 16; r++){ acc0[r] = 0.f; acc1[r] = 0.f; }
  const int col0 = c0 + cp, col1 = c0 + 32 + cp;
  const bool v0 = col0 < NCLS, v1 = col1 < NCLS;
  for (int kk = k0; kk < kend; kk += 32){
    int kc = min(32, kend - kk);
    __syncthreads();
    for (int idx = tid; idx < 128*32; idx += 256){
      int r = idx >> 5, k = idx & 31;
      As[r][k] = (k < kc) ? A[(size_t)r*SO_SZ + kk + k] : 0.f;
    }
    __syncthreads();
    for (int k = 0; k < kc; k++){
      float w0 = v0 ? W[(size_t)(kk+k)*NCLS + col0] : 0.f;
      float w1 = v1 ? W[(size_t)(kk+k)*NCLS + col1] : 0.f;
#pragma unroll
      for (int r = 0; r < 16; r++){
        float a = As[rg*16 + r][k];
        acc0[r] = fmaf(a, w0, acc0[r]);
        acc1[r] = fmaf(a, w1, acc1[r]);
      }
    }
  }
  float* pc = part + (size_t)z * BB * NCLS;
#pragma unroll
  for (int r = 0; r < 16; r++){
    int row = rg*16 + r;
    if (v0) pc[(size_t)row*NCLS + col0] = acc0[r];
    if (v1) pc[(size_t)row*NCLS + col1] = acc1[r];
  }
}

// ---------------- combine partials + bias, write preds + certainties ----------------
__global__ void k_output(const float* __restrict__ part, const float* __restrict__ outb,
                         float* __restrict__ dout, int t){
  const int b = blockIdx.x, tid = threadIdx.x;
  __shared__ float pred[NCLS];
  __shared__ float red[256];
  float lmax = -1e30f;
  for (int c = tid; c < NCLS; c += 256){
    float s = outb[c];
    const float* pp = part + (size_t)b*NCLS + c;
#pragma unroll
    for (int z = 0; z < KS; z++) s += pp[(size_t)z*BB*NCLS];
    pred[c] = s;
    dout[((size_t)b*NCLS + c)*NITER + t] = s;
    lmax = fmaxf(lmax, s);
  }
  red[tid] = lmax; __syncthreads();
  for (int s2 = 128; s2 > 0; s2 >>= 1){ if (tid < s2) red[tid] = fmaxf(red[tid], red[tid+s2]); __syncthreads(); }
  float m = red[0]; __syncthreads();
  float se = 0.f;
  for (int c = tid; c < NCLS; c += 256) se += expf(pred[c]-m);
  float Z = bsum256(se, red);
  float logZ = m + logf(Z);
  float ent = 0.f;
  for (int c = tid; c < NCLS; c += 256){ float lp = pred[c]-logZ; ent += expf(lp)*lp; }
  float E = bsum256(ent, red);
  if (tid == 0){
    float ne = -E * (1.f/logf((float)NCLS));
    float* cp = dout + (size_t)BB*NCLS*NITER + (size_t)b*2*NITER + t;
    cp[0]     = ne;
    cp[NITER] = 1.f - ne;
  }
}

// ---------------- launch ----------------
extern "C" void kernel_launch(void* const* d_in, const int* in_sizes, int n_in,
                              void* d_out, int out_size, void* d_ws, size_t ws_size,
                              hipStream_t stream){
  const int*   x           = (const int*)  d_in[0];
  const float* emb         = (const float*)d_in[1];
  const float* kv_w        = (const float*)d_in[2];
  const float* kv_b        = (const float*)d_in[3];
  const float* kv_ln_g     = (const float*)d_in[4];
  const float* kv_ln_b     = (const float*)d_in[5];
  const float* q_w         = (const float*)d_in[6];
  const float* q_b         = (const float*)d_in[7];
  const float* in_proj_w   = (const float*)d_in[8];
  const float* in_proj_b   = (const float*)d_in[9];
  const float* out_proj_w  = (const float*)d_in[10];
  const float* out_proj_b  = (const float*)d_in[11];
  const float* syn_w       = (const float*)d_in[12];
  const float* syn_b       = (const float*)d_in[13];
  const float* syn_ln_g    = (const float*)d_in[14];
  const float* syn_ln_b    = (const float*)d_in[15];
  const float* tp1_w       = (const float*)d_in[16];
  const float* tp1_b       = (const float*)d_in[17];
  const float* tp2_w       = (const float*)d_in[18];
  const float* tp2_b       = (const float*)d_in[19];
  const float* start_act   = (const float*)d_in[20];
  const float* start_trace = (const float*)d_in[21];
  const float* decay_action= (const float*)d_in[22];
  const float* decay_out   = (const float*)d_in[23];
  const float* out_w       = (const float*)d_in[24];
  const float* out_b       = (const float*)d_in[25];
  float* dout = (float*)d_out;

  // ---- workspace layout (floats), with setup/iter aliasing ----
  float* w = (float*)d_ws;
  size_t off = 0;
  auto alloc = [&](size_t n){ float* p = w + off; off += n; return p; };
  float* region0 = alloc((size_t)KS*BB*NCLS);        // embx (setup) / bigemm partials (iter)
  float* region1 = alloc((size_t)ROWS*D_IN);         // kv (setup) / a_o (iter)
  float* Kmat    = alloc((size_t)ROWS*D_IN);
  float* Vmat    = alloc((size_t)ROWS*D_IN);
  float* trace   = alloc((size_t)BB*TRACE_SLOTS*D_MODEL);
  float* sync_o  = alloc((size_t)BB*SO_SZ);
  float* a_a     = alloc((size_t)BB*SA_SZ);
  float* sync_a  = alloc((size_t)BB*SA_SZ);
  float* act     = alloc((size_t)BB*D_MODEL);
  float* qbuf    = alloc((size_t)BB*D_IN);
  float* qhbuf   = alloc((size_t)BB*D_IN);
  float* obuf    = alloc((size_t)BB*D_IN);
  float* o2buf   = alloc((size_t)BB*D_IN);
  float* synbuf  = alloc((size_t)BB*2048);
  float* r_a     = alloc(SA_SZ);
  float* r_o     = alloc(SO_SZ);
  int2*  pairsA  = (int2*)alloc(2*SA_SZ);
  int2*  pairsO  = (int2*)alloc(2*SO_SZ);
  float* embx  = region0;
  float* part  = region0;
  float* kvbuf = region1;
  float* a_o   = region1;

  dim3 blk(256);

  // ---- setup ----
  k_embed<<<(ROWS*TED+255)/256, blk, 0, stream>>>(x, emb, embx);
  k_gemm<8,false><<<dim3(2, ROWS/8), blk, 0, stream>>>(embx, TED, kv_w, D_IN, 0, 0, kv_b, kvbuf, D_IN, D_IN, TED);
  k_ln<<<ROWS, blk, 0, stream>>>(kvbuf, kv_ln_g, kv_ln_b, kvbuf, D_IN);
  k_gemm<8,false><<<dim3(2, ROWS/8), blk, 0, stream>>>(kvbuf, D_IN, in_proj_w, 1536, 0, 512,  in_proj_b+512,  Kmat, D_IN, D_IN, D_IN);
  k_gemm<8,false><<<dim3(2, ROWS/8), blk, 0, stream>>>(kvbuf, D_IN, in_proj_w, 1536, 0, 1024, in_proj_b+1024, Vmat, D_IN, D_IN, D_IN);
  k_init_pairs<<<(SA_SZ+255)/256, blk, 0, stream>>>(N_SA, SA_SZ, decay_action, pairsA, r_a);
  k_init_pairs<<<(SO_SZ+255)/256, blk, 0, stream>>>(N_SO, SO_SZ, decay_out,    pairsO, r_o);
  k_init_act<<<(BB*D_MODEL+255)/256, blk, 0, stream>>>(start_act, act);
  k_zero<<<(BB*SA_SZ+255)/256, blk, 0, stream>>>(a_a, BB*SA_SZ);
  k_init_trace<<<(BB*MEMN*D_MODEL+255)/256, blk, 0, stream>>>(start_trace, trace);
  k_init_ao<<<dim3((SO_SZ+255)/256, BB), blk, 0, stream>>>(start_act, pairsO, a_o);

  // ---- 16 recurrent iterations ----
  for (int t = 0; t < NITER; t++){
    k_syncA<<<dim3((SA_SZ+255)/256, BB), blk, 0, stream>>>(act, r_a, pairsA, a_a, sync_a, t);
    k_gemm<8,false><<<dim3(2,16), blk, 0, stream>>>(sync_a, SA_SZ, q_w, D_IN, 0, 0, q_b, qbuf, D_IN, D_IN, SA_SZ);
    k_gemm<8,false><<<dim3(2,16), blk, 0, stream>>>(qbuf, D_IN, in_proj_w, 1536, 0, 0, in_proj_b, qhbuf, D_IN, D_IN, D_IN);
    k_attn<<<BB*HEADS, 128, 0, stream>>>(qhbuf, Kmat, Vmat, obuf);
    k_gemm<8,false><<<dim3(2,16), blk, 0, stream>>>(obuf, D_IN, out_proj_w, D_IN, 0, 0, out_proj_b, o2buf, D_IN, D_IN, D_IN);
    k_gemm<8,false><<<dim3(8,16), blk, 0, stream>>>(o2buf, D_IN, syn_w, 2048, 0, 0, syn_b, synbuf, 2048, 2048, D_IN);
    k_gemm<8,true ><<<dim3(8,16), blk, 0, stream>>>(act, D_MODEL, syn_w, 2048, 512, 0, nullptr, synbuf, 2048, 2048, D_MODEL);
    k_glu_ln<<<BB, blk, 0, stream>>>(synbuf, syn_ln_g, syn_ln_b, trace + (size_t)(MEMN+t)*D_MODEL);
    k_neuron<<<(BB*D_MODEL+255)/256, blk, 0, stream>>>(trace, tp1_w, tp1_b, tp2_w, tp2_b, act, t);
    k_syncO<<<dim3((SO_SZ+255)/256, BB), blk, 0, stream>>>(act, r_o, pairsO, a_o, sync_o, t);
    k_bigemm<<<dim3(31, KS), blk, 0, stream>>>(sync_o, out_w, part);
    k_output<<<BB, blk, 0, stream>>>(part, out_b, dout, t);
  }
}

// Round 3
// 16475.073 us; speedup vs baseline: 2.1526x; 2.1526x over previous
//
#include <hip/hip_runtime.h>
#include <math.h>

#define BB 128
#define SS 72
#define NITER 16
#define D_IN 512
#define D_MODEL 1024
#define MEMN 25
#define HEADS 8
#define DHH 64
#define N_SO 256
#define N_SA 64
#define SA_SZ 2080
#define SO_SZ 32896
#define NCLS 1968
#define TED 128
#define ROWS (BB*SS)
#define TRACE_SLOTS (MEMN + NITER)   /* 41 */

/* big-GEMM (sync_o @ out_w) tiling */
#define BGN 64          /* cols per block */
#define BGKS 16         /* k splits */
#define BGKLEN 2056     /* 32896/16 */
#define BGSTEPS 33      /* ceil(2056/64); last step has 8 valid k */
#define NPART 1984      /* 31*64 padded col count */

typedef _Float16 half_t;
typedef _Float16 half8 __attribute__((ext_vector_type(8)));
typedef float f32x4v __attribute__((ext_vector_type(4)));

__device__ __forceinline__ float sigmoidf_(float x){ return 1.f/(1.f+expf(-x)); }

__device__ __forceinline__ float bsum256(float v, float* red){
  int tid = threadIdx.x; red[tid] = v; __syncthreads();
#pragma unroll
  for (int s = 128; s > 0; s >>= 1){ if (tid < s) red[tid] += red[tid+s]; __syncthreads(); }
  float r = red[0]; __syncthreads(); return r;
}

__device__ __forceinline__ long triu_off(int n, int i){
  return (long)i*n - ((long)i*(i-1))/2;
}

__device__ __forceinline__ int swzA(int b){ return b ^ (((b>>9)&1)<<5); }

// ---------------- setup kernels ----------------
__global__ void k_embed(const int* __restrict__ x, const float* __restrict__ emb,
                        float* __restrict__ out){
  int gid = blockIdx.x*256 + threadIdx.x;
  if (gid >= ROWS*TED) return;
  int row = gid >> 7, k = gid & 127;
  out[gid] = emb[x[row]*TED + k];
}

__global__ void k_init_pairs(int n, int npairs, const float* __restrict__ decay,
                             int2* __restrict__ pairs, float* __restrict__ rv){
  int p = blockIdx.x*256 + threadIdx.x;
  if (p >= npairs) return;
  double nn = (double)n;
  double disc = (2.0*nn+1.0)*(2.0*nn+1.0) - 8.0*(double)p;
  int i = (int)floor(((2.0*nn+1.0) - sqrt(disc))*0.5);
  if (i < 0) i = 0; if (i > n-1) i = n-1;
  while (i+1 < n && triu_off(n, i+1) <= (long)p) i++;
  while (i > 0 && triu_off(n, i) > (long)p) i--;
  int j = i + (int)((long)p - triu_off(n, i));
  pairs[p] = make_int2(i, j);
  float dc = decay[p]; dc = fminf(fmaxf(dc, 0.f), 15.f);
  rv[p] = expf(-dc);
}

__global__ void k_init_act(const float* __restrict__ sa, float* __restrict__ act){
  int gid = blockIdx.x*256 + threadIdx.x;
  if (gid >= BB*D_MODEL) return;
  act[gid] = sa[gid & 1023];
}

__global__ void k_zero(float* __restrict__ p, int n){
  int gid = blockIdx.x*256 + threadIdx.x;
  if (gid < n) p[gid] = 0.f;
}

__global__ void k_init_trace(const float* __restrict__ st, float* __restrict__ trace){
  int gid = blockIdx.x*256 + threadIdx.x;
  if (gid >= BB*MEMN*D_MODEL) return;
  int d = gid & 1023;
  int m = (gid >> 10) % MEMN;
  int b = (gid >> 10) / MEMN;
  trace[(size_t)b*TRACE_SLOTS*D_MODEL + (size_t)m*D_MODEL + d] = st[d*MEMN + m];
}

__global__ void k_init_ao(const float* __restrict__ sa, const int2* __restrict__ pairs,
                          float* __restrict__ ao){
  int p = blockIdx.x*256 + threadIdx.x;
  if (p >= SO_SZ) return;
  int b = blockIdx.y;
  int2 ij = pairs[p];
  ao[(size_t)b*SO_SZ + p] = sa[ij.x]*sa[ij.y];
}

// ---------------- generic fp32 GEMM:  C[M,N] = A[M,K] @ W[wrow0:,wcol0:] (+bias) ----------------
template<int MB, bool ACCUM>
__global__ void k_gemm(const float* __restrict__ A, int lda,
                       const float* __restrict__ W, int ldw, int wrow0, int wcol0,
                       const float* __restrict__ bias,
                       float* __restrict__ C, int ldc, int N, int K){
  constexpr int KC = 64;
  const int tid = threadIdx.x;
  const int col = blockIdx.x*256 + tid;
  const int row0 = blockIdx.y*MB;
  __shared__ float As[MB][KC];
  float acc[MB];
#pragma unroll
  for (int r = 0; r < MB; r++) acc[r] = 0.f;
  for (int kk = 0; kk < K; kk += KC){
    const int kc = min(KC, K - kk);
    __syncthreads();
    for (int idx = tid; idx < MB*KC; idx += 256){
      int r = idx / KC, k = idx % KC;
      As[r][k] = (k < kc) ? A[(size_t)(row0+r)*lda + kk + k] : 0.f;
    }
    __syncthreads();
    for (int k = 0; k < kc; k++){
      float w = W[(size_t)(wrow0+kk+k)*ldw + wcol0 + col];
#pragma unroll
      for (int r = 0; r < MB; r++) acc[r] = fmaf(As[r][k], w, acc[r]);
    }
  }
#pragma unroll
  for (int r = 0; r < MB; r++){
    size_t o = (size_t)(row0+r)*ldc + col;
    if (ACCUM) C[o] += acc[r];
    else       C[o] = acc[r] + bias[col];
  }
}

// ---------------- LayerNorm (block per row) ----------------
__global__ void k_ln(const float* __restrict__ X, const float* __restrict__ g,
                     const float* __restrict__ bta, float* __restrict__ Y, int D){
  const int row = blockIdx.x, tid = threadIdx.x;
  __shared__ float red[256];
  const float* xr = X + (size_t)row*D;
  float s = 0.f;
  for (int c = tid; c < D; c += 256) s += xr[c];
  float mean = bsum256(s, red) / (float)D;
  float s2 = 0.f;
  for (int c = tid; c < D; c += 256){ float d = xr[c]-mean; s2 += d*d; }
  float var = bsum256(s2, red) / (float)D;
  float inv = 1.f / sqrtf(var + 1e-5f);
  float* yr = Y + (size_t)row*D;
  for (int c = tid; c < D; c += 256) yr[c] = (xr[c]-mean)*inv*g[c] + bta[c];
}

// ---------------- GLU + LN -> write state into trace slot ----------------
__global__ void k_glu_ln(const float* __restrict__ syn, const float* __restrict__ g,
                         const float* __restrict__ bta, float* __restrict__ traceSlot){
  const int b = blockIdx.x, tid = threadIdx.x;
  __shared__ float vals[D_MODEL];
  __shared__ float red[256];
  const float* sr = syn + (size_t)b*2048;
  for (int c = tid; c < 1024; c += 256){
    float a = sr[c], gg = sr[c+1024];
    vals[c] = a * sigmoidf_(gg);
  }
  __syncthreads();
  float s = 0.f;
  for (int c = tid; c < 1024; c += 256) s += vals[c];
  float mean = bsum256(s, red) * (1.f/1024.f);
  float s2 = 0.f;
  for (int c = tid; c < 1024; c += 256){ float d = vals[c]-mean; s2 += d*d; }
  float var = bsum256(s2, red) * (1.f/1024.f);
  float inv = 1.f / sqrtf(var + 1e-5f);
  float* out = traceSlot + (size_t)b*(TRACE_SLOTS*D_MODEL);
  for (int c = tid; c < 1024; c += 256) out[c] = (vals[c]-mean)*inv*g[c] + bta[c];
}

// ---------------- attention: block per (b,h), 128 threads ----------------
__global__ void k_attn(const float* __restrict__ qh, const float* __restrict__ Km,
                       const float* __restrict__ Vm, float* __restrict__ o){
  const int bh = blockIdx.x, b = bh >> 3, h = bh & 7;
  const int tid = threadIdx.x;
  __shared__ float qs[DHH];
  __shared__ float attn[SS];
  __shared__ float red[128];
  if (tid < DHH) qs[tid] = qh[(size_t)b*D_IN + h*DHH + tid];
  __syncthreads();
  float sc = -1e30f;
  if (tid < SS){
    const float* kp = Km + ((size_t)(b*SS+tid)*HEADS + h)*DHH;
    float d = 0.f;
#pragma unroll
    for (int i = 0; i < DHH; i++) d = fmaf(qs[i], kp[i], d);
    sc = d * 0.125f;
  }
  red[tid] = sc; __syncthreads();
  for (int s2 = 64; s2 > 0; s2 >>= 1){ if (tid < s2) red[tid] = fmaxf(red[tid], red[tid+s2]); __syncthreads(); }
  float m = red[0]; __syncthreads();
  float e = (tid < SS) ? expf(sc - m) : 0.f;
  red[tid] = e; __syncthreads();
  for (int s2 = 64; s2 > 0; s2 >>= 1){ if (tid < s2) red[tid] += red[tid+s2]; __syncthreads(); }
  float inv = 1.f / red[0]; __syncthreads();
  if (tid < SS) attn[tid] = e * inv;
  __syncthreads();
  if (tid < DHH){
    const float* vp = Vm + ((size_t)(b*SS)*HEADS + h)*DHH + tid;
    float acc = 0.f;
    for (int s2 = 0; s2 < SS; s2++) acc = fmaf(attn[s2], vp[(size_t)s2*D_IN], acc);
    o[(size_t)b*D_IN + h*DHH + tid] = acc;
  }
}

// ---------------- neuron update (trace->tp1->GLU->tp2->GLU) ----------------
__global__ void k_neuron(const float* __restrict__ trace,
                         const float* __restrict__ tp1w, const float* __restrict__ tp1b,
                         const float* __restrict__ tp2w, const float* __restrict__ tp2b,
                         float* __restrict__ act, int t){
  int gid = blockIdx.x*256 + threadIdx.x;
  if (gid >= BB*D_MODEL) return;
  int b = gid >> 10, d = gid & 1023;
  const float* tr = trace + (size_t)b*(TRACE_SLOTS*D_MODEL) + (size_t)(t+1)*D_MODEL + d;
  float trv[MEMN];
#pragma unroll
  for (int m = 0; m < MEMN; m++) trv[m] = tr[(size_t)m*D_MODEL];
  float h[32];
#pragma unroll
  for (int hh = 0; hh < 32; hh++){
    float acc = tp1b[d*32 + hh];
    const float* wp = tp1w + (size_t)hh*1024 + d;
#pragma unroll
    for (int m = 0; m < MEMN; m++) acc = fmaf(trv[m], wp[(size_t)m*32*1024], acc);
    h[hh] = acc;
  }
  float o0 = tp2b[d*2+0], o1 = tp2b[d*2+1];
#pragma unroll
  for (int j = 0; j < 16; j++){
    float hgv = h[j] * sigmoidf_(h[j+16]);
    o0 = fmaf(hgv, tp2w[(size_t)(j*2+0)*1024 + d], o0);
    o1 = fmaf(hgv, tp2w[(size_t)(j*2+1)*1024 + d], o1);
  }
  act[gid] = o0 * sigmoidf_(o1);
}

// ---------------- sync accumulators ----------------
__global__ void k_syncA(const float* __restrict__ act, const float* __restrict__ rv,
                        const int2* __restrict__ pairs, float* __restrict__ aa,
                        float* __restrict__ syncv, int t){
  int p = blockIdx.x*256 + threadIdx.x;
  if (p >= SA_SZ) return;
  int b = blockIdx.y;
  int2 ij = pairs[p];
  const float* ab = act + (size_t)b*D_MODEL + (D_MODEL - N_SA);
  float r = rv[p];
  size_t idx = (size_t)b*SA_SZ + p;
  float a = fmaf(r, aa[idx], ab[ij.x]*ab[ij.y]);
  aa[idx] = a;
  float bb = 0.f;
  for (int i = 0; i <= t; i++) bb = fmaf(r, bb, 1.f);
  syncv[idx] = a / sqrtf(bb);
}

__global__ void k_syncO(const float* __restrict__ act, const float* __restrict__ rv,
                        const int2* __restrict__ pairs, float* __restrict__ ao,
                        half_t* __restrict__ syncv, int t){
  int p = blockIdx.x*256 + threadIdx.x;
  if (p >= SO_SZ) return;
  int b = blockIdx.y;
  int2 ij = pairs[p];
  const float* ab = act + (size_t)b*D_MODEL;
  float r = rv[p];
  size_t idx = (size_t)b*SO_SZ + p;
  float a = fmaf(r, ao[idx], ab[ij.x]*ab[ij.y]);
  ao[idx] = a;
  float bb = 1.f;
  for (int i = 0; i <= t; i++) bb = fmaf(r, bb, 1.f);
  syncv[idx] = (half_t)(a / sqrtf(bb));
}

// ---------------- big GEMM via fp16 MFMA: part[z][m][n] = sync_o @ out_w (k-chunk z) ----------------
__global__ __launch_bounds__(256)
void k_bigemm2(const half_t* __restrict__ Ah, const float* __restrict__ W,
               float* __restrict__ part){
  __shared__ half_t As[2][128*64];   // 128 rows x 64 k-halfs, st_16x32 XOR-swizzled
  __shared__ half_t Ws[2][64*66];    // 64 k-rows x 66 halfs (64 cols + pad)
  const int tid = threadIdx.x;
  const int z = blockIdx.y;
  const int nb0 = blockIdx.x * BGN;
  const int l = tid & 63, wv = tid >> 6;
  const int mw = (wv >> 1) * 64, nw = (wv & 1) * 32;
  const int c = l & 15, g = l >> 4;
  const int k0 = z * BGKLEN;

  f32x4v acc[4][2];
#pragma unroll
  for (int i = 0; i < 4; i++)
#pragma unroll
    for (int j2 = 0; j2 < 2; j2++)
#pragma unroll
      for (int r = 0; r < 4; r++) acc[i][j2][r] = 0.f;

  auto stage = [&](int s, int buf){
    const int kv = min(64, BGKLEN - s*64);   // 64 or 8 (tail)
    // ---- A tile: 128m x 64k halfs, as 1024 16B chunks (8 chunks/row), swizzled linear ----
#pragma unroll
    for (int it = 0; it < 4; it++){
      int ch = tid + it*256;
      int m = ch >> 3, kg = ch & 7, kl = kg*8;
      half8 v;
      if (kl < kv) v = *(const half8*)(Ah + (size_t)m*SO_SZ + k0 + s*64 + kl);
      else { 
#pragma unroll
        for (int j = 0; j < 8; j++) v[j] = (half_t)0.f; 
      }
      *(half8*)((char*)(&As[buf][0]) + swzA(ch*16)) = v;
    }
    // ---- W tile: 64k x 64n fp32 -> fp16, rows padded to 66 halfs ----
    {
      int k = tid >> 2, cs = (tid & 3) * 16;
      const float* wr = W + (size_t)(k0 + s*64 + k) * NCLS + nb0 + cs;
      char* dst = (char*)(&Ws[buf][0]) + (size_t)(k*66 + cs) * 2;
      bool kvalid = (k < kv);
#pragma unroll
      for (int q = 0; q < 4; q++){
        float x0 = 0.f, x1 = 0.f, x2 = 0.f, x3 = 0.f;
        int col = nb0 + cs + q*4;
        if (kvalid && col < NCLS){
          float4 wvv = *(const float4*)(wr + q*4);
          x0 = wvv.x; x1 = wvv.y; x2 = wvv.z; x3 = wvv.w;
        }
        union { half_t h[4]; unsigned int u[2]; } pk;
        pk.h[0] = (half_t)x0; pk.h[1] = (half_t)x1;
        pk.h[2] = (half_t)x2; pk.h[3] = (half_t)x3;
        *(unsigned int*)(dst + q*8)     = pk.u[0];
        *(unsigned int*)(dst + q*8 + 4) = pk.u[1];
      }
    }
  };

  stage(0, 0);
  __syncthreads();
  for (int s = 0; s < BGSTEPS; s++){
    int buf = s & 1;
    if (s + 1 < BGSTEPS) stage(s+1, buf^1);
#pragma unroll
    for (int h = 0; h < 2; h++){
      half8 a8[4];
#pragma unroll
      for (int mb = 0; mb < 4; mb++)
        a8[mb] = *(const half8*)((const char*)(&As[buf][0]) +
                   swzA(((mw + mb*16 + c)*64 + h*32 + g*8)*2));
#pragma unroll
      for (int nb = 0; nb < 2; nb++){
        half8 b8;
        const half_t* wp = &Ws[buf][(h*32 + g*8)*66 + nw + nb*16 + c];
#pragma unroll
        for (int j = 0; j < 8; j++) b8[j] = wp[j*66];
#pragma unroll
        for (int mb = 0; mb < 4; mb++)
          acc[mb][nb] = __builtin_amdgcn_mfma_f32_16x16x32_f16(a8[mb], b8, acc[mb][nb], 0, 0, 0);
      }
    }
    __syncthreads();
  }
  // epilogue: D row = m (A-rows), col = n; lane: col = l&15, row = 4*(l>>4)+r
  float* pz = part + (size_t)z * 128 * NPART;
#pragma unroll
  for (int mb = 0; mb < 4; mb++)
#pragma unroll
    for (int nb = 0; nb < 2; nb++){
      int m = mw + mb*16 + g*4;
      int n = nb0 + nw + nb*16 + c;
#pragma unroll
      for (int r = 0; r < 4; r++)
        pz[(size_t)(m + r) * NPART + n] = acc[mb][nb][r];
    }
}

// ---------------- combine partials + bias, write preds + certainties ----------------
__global__ void k_output(const float* __restrict__ part, const float* __restrict__ outb,
                         float* __restrict__ dout, int t){
  const int b = blockIdx.x, tid = threadIdx.x;
  __shared__ float pred[NCLS];
  __shared__ float red[256];
  float lmax = -1e30f;
  for (int c = tid; c < NCLS; c += 256){
    float s = outb[c];
    const float* pp = part + (size_t)b*NPART + c;
#pragma unroll
    for (int z = 0; z < BGKS; z++) s += pp[(size_t)z*128*NPART];
    pred[c] = s;
    dout[((size_t)b*NCLS + c)*NITER + t] = s;
    lmax = fmaxf(lmax, s);
  }
  red[tid] = lmax; __syncthreads();
  for (int s2 = 128; s2 > 0; s2 >>= 1){ if (tid < s2) red[tid] = fmaxf(red[tid], red[tid+s2]); __syncthreads(); }
  float m = red[0]; __syncthreads();
  float se = 0.f;
  for (int c = tid; c < NCLS; c += 256) se += expf(pred[c]-m);
  float Z = bsum256(se, red);
  float logZ = m + logf(Z);
  float ent = 0.f;
  for (int c = tid; c < NCLS; c += 256){ float lp = pred[c]-logZ; ent += expf(lp)*lp; }
  float E = bsum256(ent, red);
  if (tid == 0){
    float ne = -E * (1.f/logf((float)NCLS));
    float* cp = dout + (size_t)BB*NCLS*NITER + (size_t)b*2*NITER + t;
    cp[0]     = ne;
    cp[NITER] = 1.f - ne;
  }
}

// ---------------- launch ----------------
extern "C" void kernel_launch(void* const* d_in, const int* in_sizes, int n_in,
                              void* d_out, int out_size, void* d_ws, size_t ws_size,
                              hipStream_t stream){
  const int*   x           = (const int*)  d_in[0];
  const float* emb         = (const float*)d_in[1];
  const float* kv_w        = (const float*)d_in[2];
  const float* kv_b        = (const float*)d_in[3];
  const float* kv_ln_g     = (const float*)d_in[4];
  const float* kv_ln_b     = (const float*)d_in[5];
  const float* q_w         = (const float*)d_in[6];
  const float* q_b         = (const float*)d_in[7];
  const float* in_proj_w   = (const float*)d_in[8];
  const float* in_proj_b   = (const float*)d_in[9];
  const float* out_proj_w  = (const float*)d_in[10];
  const float* out_proj_b  = (const float*)d_in[11];
  const float* syn_w       = (const float*)d_in[12];
  const float* syn_b       = (const float*)d_in[13];
  const float* syn_ln_g    = (const float*)d_in[14];
  const float* syn_ln_b    = (const float*)d_in[15];
  const float* tp1_w       = (const float*)d_in[16];
  const float* tp1_b       = (const float*)d_in[17];
  const float* tp2_w       = (const float*)d_in[18];
  const float* tp2_b       = (const float*)d_in[19];
  const float* start_act   = (const float*)d_in[20];
  const float* start_trace = (const float*)d_in[21];
  const float* decay_action= (const float*)d_in[22];
  const float* decay_out   = (const float*)d_in[23];
  const float* out_w       = (const float*)d_in[24];
  const float* out_b       = (const float*)d_in[25];
  float* dout = (float*)d_out;

  // ---- workspace layout (floats), with setup/iter aliasing ----
  float* w = (float*)d_ws;
  size_t off = 0;
  auto alloc = [&](size_t n){ n = (n + 3) & ~(size_t)3; float* p = w + off; off += n; return p; };
  float* region0 = alloc((size_t)BGKS*128*NPART);    // embx (setup) / bigemm partials (iter)
  float* region1 = alloc((size_t)ROWS*D_IN);         // kv (setup) / a_o (iter)
  float* Kmat    = alloc((size_t)ROWS*D_IN);
  float* Vmat    = alloc((size_t)ROWS*D_IN);
  float* trace   = alloc((size_t)BB*TRACE_SLOTS*D_MODEL);
  half_t* sync_oh= (half_t*)alloc((size_t)BB*SO_SZ/2);  // fp16 sync_o
  float* a_a     = alloc((size_t)BB*SA_SZ);
  float* sync_a  = alloc((size_t)BB*SA_SZ);
  float* act     = alloc((size_t)BB*D_MODEL);
  float* qbuf    = alloc((size_t)BB*D_IN);
  float* qhbuf   = alloc((size_t)BB*D_IN);
  float* obuf    = alloc((size_t)BB*D_IN);
  float* o2buf   = alloc((size_t)BB*D_IN);
  float* synbuf  = alloc((size_t)BB*2048);
  float* r_a     = alloc(SA_SZ);
  float* r_o     = alloc(SO_SZ);
  int2*  pairsA  = (int2*)alloc(2*SA_SZ);
  int2*  pairsO  = (int2*)alloc(2*SO_SZ);
  float* embx  = region0;
  float* part  = region0;
  float* kvbuf = region1;
  float* a_o   = region1;

  dim3 blk(256);

  // ---- setup ----
  k_embed<<<(ROWS*TED+255)/256, blk, 0, stream>>>(x, emb, embx);
  k_gemm<8,false><<<dim3(2, ROWS/8), blk, 0, stream>>>(embx, TED, kv_w, D_IN, 0, 0, kv_b, kvbuf, D_IN, D_IN, TED);
  k_ln<<<ROWS, blk, 0, stream>>>(kvbuf, kv_ln_g, kv_ln_b, kvbuf, D_IN);
  k_gemm<8,false><<<dim3(2, ROWS/8), blk, 0, stream>>>(kvbuf, D_IN, in_proj_w, 1536, 0, 512,  in_proj_b+512,  Kmat, D_IN, D_IN, D_IN);
  k_gemm<8,false><<<dim3(2, ROWS/8), blk, 0, stream>>>(kvbuf, D_IN, in_proj_w, 1536, 0, 1024, in_proj_b+1024, Vmat, D_IN, D_IN, D_IN);
  k_init_pairs<<<(SA_SZ+255)/256, blk, 0, stream>>>(N_SA, SA_SZ, decay_action, pairsA, r_a);
  k_init_pairs<<<(SO_SZ+255)/256, blk, 0, stream>>>(N_SO, SO_SZ, decay_out,    pairsO, r_o);
  k_init_act<<<(BB*D_MODEL+255)/256, blk, 0, stream>>>(start_act, act);
  k_zero<<<(BB*SA_SZ+255)/256, blk, 0, stream>>>(a_a, BB*SA_SZ);
  k_init_trace<<<(BB*MEMN*D_MODEL+255)/256, blk, 0, stream>>>(start_trace, trace);
  k_init_ao<<<dim3((SO_SZ+255)/256, BB), blk, 0, stream>>>(start_act, pairsO, a_o);

  // ---- 16 recurrent iterations ----
  for (int t = 0; t < NITER; t++){
    k_syncA<<<dim3((SA_SZ+255)/256, BB), blk, 0, stream>>>(act, r_a, pairsA, a_a, sync_a, t);
    k_gemm<4,false><<<dim3(2,32), blk, 0, stream>>>(sync_a, SA_SZ, q_w, D_IN, 0, 0, q_b, qbuf, D_IN, D_IN, SA_SZ);
    k_gemm<4,false><<<dim3(2,32), blk, 0, stream>>>(qbuf, D_IN, in_proj_w, 1536, 0, 0, in_proj_b, qhbuf, D_IN, D_IN, D_IN);
    k_attn<<<BB*HEADS, 128, 0, stream>>>(qhbuf, Kmat, Vmat, obuf);
    k_gemm<4,false><<<dim3(2,32), blk, 0, stream>>>(obuf, D_IN, out_proj_w, D_IN, 0, 0, out_proj_b, o2buf, D_IN, D_IN, D_IN);
    k_gemm<4,false><<<dim3(8,32), blk, 0, stream>>>(o2buf, D_IN, syn_w, 2048, 0, 0, syn_b, synbuf, 2048, 2048, D_IN);
    k_gemm<4,true ><<<dim3(8,32), blk, 0, stream>>>(act, D_MODEL, syn_w, 2048, 512, 0, nullptr, synbuf, 2048, 2048, D_MODEL);
    k_glu_ln<<<BB, blk, 0, stream>>>(synbuf, syn_ln_g, syn_ln_b, trace + (size_t)(MEMN+t)*D_MODEL);
    k_neuron<<<(BB*D_MODEL+255)/256, blk, 0, stream>>>(trace, tp1_w, tp1_b, tp2_w, tp2_b, act, t);
    k_syncO<<<dim3((SO_SZ+255)/256, BB), blk, 0, stream>>>(act, r_o, pairsO, a_o, sync_oh, t);
    k_bigemm2<<<dim3(31, BGKS), blk, 0, stream>>>(sync_oh, out_w, part);
    k_output<<<BB, blk, 0, stream>>>(part, out_b, dout, t);
  }
}

// Round 4
// 9063.747 us; speedup vs baseline: 3.9128x; 1.8177x over previous
//
#include <hip/hip_runtime.h>
#include <math.h>

#define BB 128
#define SS 72
#define NITER 16
#define D_IN 512
#define D_MODEL 1024
#define MEMN 25
#define HEADS 8
#define DHH 64
#define N_SO 256
#define N_SA 64
#define SA_SZ 2080
#define SO_SZ 32896
#define NCLS 1968
#define TED 128
#define ROWS (BB*SS)
#define TRACE_SLOTS (MEMN + NITER)   /* 41 */

/* big-GEMM (sync_o @ out_w) tiling */
#define BGN 64          /* cols per block */
#define BGKS 16         /* k splits */
#define BGKLEN 2056     /* 32896/16 */
#define BGSTEPS 33      /* ceil(2056/64); last step has 8 valid k */
#define NPART 1984      /* 31*64 padded col count */

typedef _Float16 half_t;
typedef _Float16 half8 __attribute__((ext_vector_type(8)));
typedef float f32x4v __attribute__((ext_vector_type(4)));

__device__ __forceinline__ float sigmoidf_(float x){ return 1.f/(1.f+expf(-x)); }

__device__ __forceinline__ float bsum256(float v, float* red){
  int tid = threadIdx.x; red[tid] = v; __syncthreads();
#pragma unroll
  for (int s = 128; s > 0; s >>= 1){ if (tid < s) red[tid] += red[tid+s]; __syncthreads(); }
  float r = red[0]; __syncthreads(); return r;
}

__device__ __forceinline__ long triu_off(int n, int i){
  return (long)i*n - ((long)i*(i-1))/2;
}

__device__ __forceinline__ int swzA(int b){ return b ^ (((b>>9)&1)<<5); }

// ---------------- setup kernels ----------------
__global__ void k_embed(const int* __restrict__ x, const float* __restrict__ emb,
                        float* __restrict__ out){
  int gid = blockIdx.x*256 + threadIdx.x;
  if (gid >= ROWS*TED) return;
  int row = gid >> 7, k = gid & 127;
  out[gid] = emb[x[row]*TED + k];
}

__global__ void k_init_pairs(int n, int npairs, const float* __restrict__ decay,
                             int2* __restrict__ pairs, float* __restrict__ rv){
  int p = blockIdx.x*256 + threadIdx.x;
  if (p >= npairs) return;
  double nn = (double)n;
  double disc = (2.0*nn+1.0)*(2.0*nn+1.0) - 8.0*(double)p;
  int i = (int)floor(((2.0*nn+1.0) - sqrt(disc))*0.5);
  if (i < 0) i = 0; if (i > n-1) i = n-1;
  while (i+1 < n && triu_off(n, i+1) <= (long)p) i++;
  while (i > 0 && triu_off(n, i) > (long)p) i--;
  int j = i + (int)((long)p - triu_off(n, i));
  pairs[p] = make_int2(i, j);
  float dc = decay[p]; dc = fminf(fmaxf(dc, 0.f), 15.f);
  rv[p] = expf(-dc);
}

__global__ void k_init_act(const float* __restrict__ sa, float* __restrict__ act){
  int gid = blockIdx.x*256 + threadIdx.x;
  if (gid >= BB*D_MODEL) return;
  act[gid] = sa[gid & 1023];
}

__global__ void k_zero(float* __restrict__ p, int n){
  int gid = blockIdx.x*256 + threadIdx.x;
  if (gid < n) p[gid] = 0.f;
}

__global__ void k_init_trace(const float* __restrict__ st, float* __restrict__ trace){
  int gid = blockIdx.x*256 + threadIdx.x;
  if (gid >= BB*MEMN*D_MODEL) return;
  int d = gid & 1023;
  int m = (gid >> 10) % MEMN;
  int b = (gid >> 10) / MEMN;
  trace[(size_t)b*TRACE_SLOTS*D_MODEL + (size_t)m*D_MODEL + d] = st[d*MEMN + m];
}

__global__ void k_init_ao(const float* __restrict__ sa, const int2* __restrict__ pairs,
                          float* __restrict__ ao){
  int p = blockIdx.x*256 + threadIdx.x;
  if (p >= SO_SZ) return;
  int b = blockIdx.y;
  int2 ij = pairs[p];
  ao[(size_t)b*SO_SZ + p] = sa[ij.x]*sa[ij.y];
}

// ---- generic fp32 GEMM:  C[M,N] = A[M,K] @ W[wrow0:,wcol0:] (+bias). REQUIRES K % 32 == 0 ----
template<int MB, bool ACCUM>
__global__ void k_gemm(const float* __restrict__ A, int lda,
                       const float* __restrict__ W, int ldw, int wrow0, int wcol0,
                       const float* __restrict__ bias,
                       float* __restrict__ C, int ldc, int N, int K){
  constexpr int KC = 32;
  const int tid = threadIdx.x;
  const int col = blockIdx.x*256 + tid;
  const int row0 = blockIdx.y*MB;
  __shared__ float As[MB][KC];
  float acc[MB];
#pragma unroll
  for (int r = 0; r < MB; r++) acc[r] = 0.f;
  for (int kk = 0; kk < K; kk += KC){
    __syncthreads();
    for (int idx = tid; idx < MB*KC; idx += 256){
      int r = idx / KC, k = idx % KC;
      As[r][k] = A[(size_t)(row0+r)*lda + kk + k];
    }
    __syncthreads();
#pragma unroll
    for (int k = 0; k < KC; k++){
      float w = W[(size_t)(wrow0+kk+k)*ldw + wcol0 + col];
#pragma unroll
      for (int r = 0; r < MB; r++) acc[r] = fmaf(As[r][k], w, acc[r]);
    }
  }
#pragma unroll
  for (int r = 0; r < MB; r++){
    size_t o = (size_t)(row0+r)*ldc + col;
    if (ACCUM) C[o] += acc[r];
    else       C[o] = acc[r] + bias[col];
  }
}

// ---------------- LayerNorm (block per row) ----------------
__global__ void k_ln(const float* __restrict__ X, const float* __restrict__ g,
                     const float* __restrict__ bta, float* __restrict__ Y, int D){
  const int row = blockIdx.x, tid = threadIdx.x;
  __shared__ float red[256];
  const float* xr = X + (size_t)row*D;
  float s = 0.f;
  for (int c = tid; c < D; c += 256) s += xr[c];
  float mean = bsum256(s, red) / (float)D;
  float s2 = 0.f;
  for (int c = tid; c < D; c += 256){ float d = xr[c]-mean; s2 += d*d; }
  float var = bsum256(s2, red) / (float)D;
  float inv = 1.f / sqrtf(var + 1e-5f);
  float* yr = Y + (size_t)row*D;
  for (int c = tid; c < D; c += 256) yr[c] = (xr[c]-mean)*inv*g[c] + bta[c];
}

// ---------------- GLU + LN -> write state into trace slot ----------------
__global__ void k_glu_ln(const float* __restrict__ syn, const float* __restrict__ g,
                         const float* __restrict__ bta, float* __restrict__ traceSlot){
  const int b = blockIdx.x, tid = threadIdx.x;
  __shared__ float vals[D_MODEL];
  __shared__ float red[256];
  const float* sr = syn + (size_t)b*2048;
  for (int c = tid; c < 1024; c += 256){
    float a = sr[c], gg = sr[c+1024];
    vals[c] = a * sigmoidf_(gg);
  }
  __syncthreads();
  float s = 0.f;
  for (int c = tid; c < 1024; c += 256) s += vals[c];
  float mean = bsum256(s, red) * (1.f/1024.f);
  float s2 = 0.f;
  for (int c = tid; c < 1024; c += 256){ float d = vals[c]-mean; s2 += d*d; }
  float var = bsum256(s2, red) * (1.f/1024.f);
  float inv = 1.f / sqrtf(var + 1e-5f);
  float* out = traceSlot + (size_t)b*(TRACE_SLOTS*D_MODEL);
  for (int c = tid; c < 1024; c += 256) out[c] = (vals[c]-mean)*inv*g[c] + bta[c];
}

// ---------------- attention: block per (b,h), 128 threads ----------------
__global__ void k_attn(const float* __restrict__ qh, const float* __restrict__ Km,
                       const float* __restrict__ Vm, float* __restrict__ o){
  const int bh = blockIdx.x, b = bh >> 3, h = bh & 7;
  const int tid = threadIdx.x;
  __shared__ float qs[DHH];
  __shared__ float attn[SS];
  __shared__ float red[128];
  if (tid < DHH) qs[tid] = qh[(size_t)b*D_IN + h*DHH + tid];
  __syncthreads();
  float sc = -1e30f;
  if (tid < SS){
    const float* kp = Km + ((size_t)(b*SS+tid)*HEADS + h)*DHH;
    float d = 0.f;
#pragma unroll
    for (int i = 0; i < DHH; i++) d = fmaf(qs[i], kp[i], d);
    sc = d * 0.125f;
  }
  red[tid] = sc; __syncthreads();
  for (int s2 = 64; s2 > 0; s2 >>= 1){ if (tid < s2) red[tid] = fmaxf(red[tid], red[tid+s2]); __syncthreads(); }
  float m = red[0]; __syncthreads();
  float e = (tid < SS) ? expf(sc - m) : 0.f;
  red[tid] = e; __syncthreads();
  for (int s2 = 64; s2 > 0; s2 >>= 1){ if (tid < s2) red[tid] += red[tid+s2]; __syncthreads(); }
  float inv = 1.f / red[0]; __syncthreads();
  if (tid < SS) attn[tid] = e * inv;
  __syncthreads();
  if (tid < DHH){
    const float* vp = Vm + ((size_t)(b*SS)*HEADS + h)*DHH + tid;
    float acc = 0.f;
    for (int s2 = 0; s2 < SS; s2++) acc = fmaf(attn[s2], vp[(size_t)s2*D_IN], acc);
    o[(size_t)b*D_IN + h*DHH + tid] = acc;
  }
}

// ---- neuron update (trace->tp1->GLU->tp2->GLU), register-lean: 2 live h at a time ----
__global__ void k_neuron(const float* __restrict__ trace,
                         const float* __restrict__ tp1w, const float* __restrict__ tp1b,
                         const float* __restrict__ tp2w, const float* __restrict__ tp2b,
                         float* __restrict__ act, int t){
  int gid = blockIdx.x*256 + threadIdx.x;
  if (gid >= BB*D_MODEL) return;
  int b = gid >> 10, d = gid & 1023;
  const float* tr = trace + (size_t)b*(TRACE_SLOTS*D_MODEL) + (size_t)(t+1)*D_MODEL + d;
  float trv[MEMN];
#pragma unroll
  for (int m = 0; m < MEMN; m++) trv[m] = tr[(size_t)m*D_MODEL];
  float o0 = tp2b[d*2+0], o1 = tp2b[d*2+1];
#pragma unroll
  for (int j = 0; j < 16; j++){
    const float* wpj = tp1w + (size_t)j*1024 + d;        // feeds h[j]
    const float* wpg = tp1w + (size_t)(j+16)*1024 + d;   // feeds h[j+16]
    float hj = tp1b[d*32 + j];
    float hg = tp1b[d*32 + j + 16];
#pragma unroll
    for (int m = 0; m < MEMN; m++){
      float tv = trv[m];
      hj = fmaf(tv, wpj[(size_t)m*32*1024], hj);
      hg = fmaf(tv, wpg[(size_t)m*32*1024], hg);
    }
    float hgv = hj * sigmoidf_(hg);
    o0 = fmaf(hgv, tp2w[(size_t)(j*2+0)*1024 + d], o0);
    o1 = fmaf(hgv, tp2w[(size_t)(j*2+1)*1024 + d], o1);
  }
  act[gid] = o0 * sigmoidf_(o1);
}

// ---------------- sync accumulators ----------------
__global__ void k_syncA(const float* __restrict__ act, const float* __restrict__ rv,
                        const int2* __restrict__ pairs, float* __restrict__ aa,
                        float* __restrict__ syncv, int t){
  int p = blockIdx.x*256 + threadIdx.x;
  if (p >= SA_SZ) return;
  int b = blockIdx.y;
  int2 ij = pairs[p];
  const float* ab = act + (size_t)b*D_MODEL + (D_MODEL - N_SA);
  float r = rv[p];
  size_t idx = (size_t)b*SA_SZ + p;
  float a = fmaf(r, aa[idx], ab[ij.x]*ab[ij.y]);
  aa[idx] = a;
  float bb = 0.f;
  for (int i = 0; i <= t; i++) bb = fmaf(r, bb, 1.f);
  syncv[idx] = a / sqrtf(bb);
}

__global__ void k_syncO(const float* __restrict__ act, const float* __restrict__ rv,
                        const int2* __restrict__ pairs, float* __restrict__ ao,
                        half_t* __restrict__ syncv, int t){
  int p = blockIdx.x*256 + threadIdx.x;
  if (p >= SO_SZ) return;
  int b = blockIdx.y;
  int2 ij = pairs[p];
  const float* ab = act + (size_t)b*D_MODEL;
  float r = rv[p];
  size_t idx = (size_t)b*SO_SZ + p;
  float a = fmaf(r, ao[idx], ab[ij.x]*ab[ij.y]);
  ao[idx] = a;
  float bb = 1.f;
  for (int i = 0; i <= t; i++) bb = fmaf(r, bb, 1.f);
  syncv[idx] = (half_t)(a / sqrtf(bb));
}

// ---------------- big GEMM via fp16 MFMA: part[z][m][n] = sync_o @ out_w (k-chunk z) ----------------
__global__ __launch_bounds__(256)
void k_bigemm2(const half_t* __restrict__ Ah, const float* __restrict__ W,
               float* __restrict__ part){
  __shared__ half_t As[2][128*64];   // 128 rows x 64 k-halfs, st_16x32 XOR-swizzled
  __shared__ half_t Ws[2][64*66];    // 64 k-rows x 66 halfs (64 cols + pad)
  const int tid = threadIdx.x;
  const int z = blockIdx.y;
  const int nb0 = blockIdx.x * BGN;
  const int l = tid & 63, wv = tid >> 6;
  const int mw = (wv >> 1) * 64, nw = (wv & 1) * 32;
  const int c = l & 15, g = l >> 4;
  const int k0 = z * BGKLEN;

  f32x4v acc[4][2];
#pragma unroll
  for (int i = 0; i < 4; i++)
#pragma unroll
    for (int j2 = 0; j2 < 2; j2++)
#pragma unroll
      for (int r = 0; r < 4; r++) acc[i][j2][r] = 0.f;

  auto stage = [&](int s, int buf){
    const int kv = min(64, BGKLEN - s*64);   // 64 or 8 (tail)
    // ---- A tile: 128m x 64k halfs, as 1024 16B chunks (8 chunks/row), swizzled linear ----
#pragma unroll
    for (int it = 0; it < 4; it++){
      int ch = tid + it*256;
      int m = ch >> 3, kg = ch & 7, kl = kg*8;
      half8 v;
      if (kl < kv) v = *(const half8*)(Ah + (size_t)m*SO_SZ + k0 + s*64 + kl);
      else { 
#pragma unroll
        for (int j = 0; j < 8; j++) v[j] = (half_t)0.f; 
      }
      *(half8*)((char*)(&As[buf][0]) + swzA(ch*16)) = v;
    }
    // ---- W tile: 64k x 64n fp32 -> fp16, rows padded to 66 halfs ----
    {
      int k = tid >> 2, cs = (tid & 3) * 16;
      const float* wr = W + (size_t)(k0 + s*64 + k) * NCLS + nb0 + cs;
      char* dst = (char*)(&Ws[buf][0]) + (size_t)(k*66 + cs) * 2;
      bool kvalid = (k < kv);
#pragma unroll
      for (int q = 0; q < 4; q++){
        float x0 = 0.f, x1 = 0.f, x2 = 0.f, x3 = 0.f;
        int col = nb0 + cs + q*4;
        if (kvalid && col < NCLS){
          float4 wvv = *(const float4*)(wr + q*4);
          x0 = wvv.x; x1 = wvv.y; x2 = wvv.z; x3 = wvv.w;
        }
        union { half_t h[4]; unsigned int u[2]; } pk;
        pk.h[0] = (half_t)x0; pk.h[1] = (half_t)x1;
        pk.h[2] = (half_t)x2; pk.h[3] = (half_t)x3;
        *(unsigned int*)(dst + q*8)     = pk.u[0];
        *(unsigned int*)(dst + q*8 + 4) = pk.u[1];
      }
    }
  };

  stage(0, 0);
  __syncthreads();
  for (int s = 0; s < BGSTEPS; s++){
    int buf = s & 1;
    if (s + 1 < BGSTEPS) stage(s+1, buf^1);
#pragma unroll
    for (int h = 0; h < 2; h++){
      half8 a8[4];
#pragma unroll
      for (int mb = 0; mb < 4; mb++)
        a8[mb] = *(const half8*)((const char*)(&As[buf][0]) +
                   swzA(((mw + mb*16 + c)*64 + h*32 + g*8)*2));
#pragma unroll
      for (int nb = 0; nb < 2; nb++){
        half8 b8;
        const half_t* wp = &Ws[buf][(h*32 + g*8)*66 + nw + nb*16 + c];
#pragma unroll
        for (int j = 0; j < 8; j++) b8[j] = wp[j*66];
#pragma unroll
        for (int mb = 0; mb < 4; mb++)
          acc[mb][nb] = __builtin_amdgcn_mfma_f32_16x16x32_f16(a8[mb], b8, acc[mb][nb], 0, 0, 0);
      }
    }
    __syncthreads();
  }
  // epilogue: D row = m (A-rows), col = n; lane: col = l&15, row = 4*(l>>4)+r
  float* pz = part + (size_t)z * 128 * NPART;
#pragma unroll
  for (int mb = 0; mb < 4; mb++)
#pragma unroll
    for (int nb = 0; nb < 2; nb++){
      int m = mw + mb*16 + g*4;
      int n = nb0 + nw + nb*16 + c;
#pragma unroll
      for (int r = 0; r < 4; r++)
        pz[(size_t)(m + r) * NPART + n] = acc[mb][nb][r];
    }
}

// ---------------- combine partials + bias, write preds + certainties ----------------
__global__ void k_output(const float* __restrict__ part, const float* __restrict__ outb,
                         float* __restrict__ dout, int t){
  const int b = blockIdx.x, tid = threadIdx.x;
  __shared__ float pred[NCLS];
  __shared__ float red[256];
  float lmax = -1e30f;
  for (int c = tid; c < NCLS; c += 256){
    float s = outb[c];
    const float* pp = part + (size_t)b*NPART + c;
#pragma unroll
    for (int z = 0; z < BGKS; z++) s += pp[(size_t)z*128*NPART];
    pred[c] = s;
    dout[((size_t)b*NCLS + c)*NITER + t] = s;
    lmax = fmaxf(lmax, s);
  }
  red[tid] = lmax; __syncthreads();
  for (int s2 = 128; s2 > 0; s2 >>= 1){ if (tid < s2) red[tid] = fmaxf(red[tid], red[tid+s2]); __syncthreads(); }
  float m = red[0]; __syncthreads();
  float se = 0.f;
  for (int c = tid; c < NCLS; c += 256) se += expf(pred[c]-m);
  float Z = bsum256(se, red);
  float logZ = m + logf(Z);
  float ent = 0.f;
  for (int c = tid; c < NCLS; c += 256){ float lp = pred[c]-logZ; ent += expf(lp)*lp; }
  float E = bsum256(ent, red);
  if (tid == 0){
    float ne = -E * (1.f/logf((float)NCLS));
    float* cp = dout + (size_t)BB*NCLS*NITER + (size_t)b*2*NITER + t;
    cp[0]     = ne;
    cp[NITER] = 1.f - ne;
  }
}

// ---------------- launch ----------------
extern "C" void kernel_launch(void* const* d_in, const int* in_sizes, int n_in,
                              void* d_out, int out_size, void* d_ws, size_t ws_size,
                              hipStream_t stream){
  const int*   x           = (const int*)  d_in[0];
  const float* emb         = (const float*)d_in[1];
  const float* kv_w        = (const float*)d_in[2];
  const float* kv_b        = (const float*)d_in[3];
  const float* kv_ln_g     = (const float*)d_in[4];
  const float* kv_ln_b     = (const float*)d_in[5];
  const float* q_w         = (const float*)d_in[6];
  const float* q_b         = (const float*)d_in[7];
  const float* in_proj_w   = (const float*)d_in[8];
  const float* in_proj_b   = (const float*)d_in[9];
  const float* out_proj_w  = (const float*)d_in[10];
  const float* out_proj_b  = (const float*)d_in[11];
  const float* syn_w       = (const float*)d_in[12];
  const float* syn_b       = (const float*)d_in[13];
  const float* syn_ln_g    = (const float*)d_in[14];
  const float* syn_ln_b    = (const float*)d_in[15];
  const float* tp1_w       = (const float*)d_in[16];
  const float* tp1_b       = (const float*)d_in[17];
  const float* tp2_w       = (const float*)d_in[18];
  const float* tp2_b       = (const float*)d_in[19];
  const float* start_act   = (const float*)d_in[20];
  const float* start_trace = (const float*)d_in[21];
  const float* decay_action= (const float*)d_in[22];
  const float* decay_out   = (const float*)d_in[23];
  const float* out_w       = (const float*)d_in[24];
  const float* out_b       = (const float*)d_in[25];
  float* dout = (float*)d_out;

  // ---- workspace layout (floats), with setup/iter aliasing ----
  float* w = (float*)d_ws;
  size_t off = 0;
  auto alloc = [&](size_t n){ n = (n + 3) & ~(size_t)3; float* p = w + off; off += n; return p; };
  float* region0 = alloc((size_t)BGKS*128*NPART);    // embx (setup) / bigemm partials (iter)
  float* region1 = alloc((size_t)ROWS*D_IN);         // kv (setup) / a_o (iter)
  float* Kmat    = alloc((size_t)ROWS*D_IN);
  float* Vmat    = alloc((size_t)ROWS*D_IN);
  float* trace   = alloc((size_t)BB*TRACE_SLOTS*D_MODEL);
  half_t* sync_oh= (half_t*)alloc((size_t)BB*SO_SZ/2);  // fp16 sync_o
  float* a_a     = alloc((size_t)BB*SA_SZ);
  float* sync_a  = alloc((size_t)BB*SA_SZ);
  float* act     = alloc((size_t)BB*D_MODEL);
  float* qbuf    = alloc((size_t)BB*D_IN);
  float* qhbuf   = alloc((size_t)BB*D_IN);
  float* obuf    = alloc((size_t)BB*D_IN);
  float* o2buf   = alloc((size_t)BB*D_IN);
  float* synbuf  = alloc((size_t)BB*2048);
  float* r_a     = alloc(SA_SZ);
  float* r_o     = alloc(SO_SZ);
  int2*  pairsA  = (int2*)alloc(2*SA_SZ);
  int2*  pairsO  = (int2*)alloc(2*SO_SZ);
  float* embx  = region0;
  float* part  = region0;
  float* kvbuf = region1;
  float* a_o   = region1;

  dim3 blk(256);

  // ---- setup ----
  k_embed<<<(ROWS*TED+255)/256, blk, 0, stream>>>(x, emb, embx);
  k_gemm<8,false><<<dim3(2, ROWS/8), blk, 0, stream>>>(embx, TED, kv_w, D_IN, 0, 0, kv_b, kvbuf, D_IN, D_IN, TED);
  k_ln<<<ROWS, blk, 0, stream>>>(kvbuf, kv_ln_g, kv_ln_b, kvbuf, D_IN);
  k_gemm<8,false><<<dim3(2, ROWS/8), blk, 0, stream>>>(kvbuf, D_IN, in_proj_w, 1536, 0, 512,  in_proj_b+512,  Kmat, D_IN, D_IN, D_IN);
  k_gemm<8,false><<<dim3(2, ROWS/8), blk, 0, stream>>>(kvbuf, D_IN, in_proj_w, 1536, 0, 1024, in_proj_b+1024, Vmat, D_IN, D_IN, D_IN);
  k_init_pairs<<<(SA_SZ+255)/256, blk, 0, stream>>>(N_SA, SA_SZ, decay_action, pairsA, r_a);
  k_init_pairs<<<(SO_SZ+255)/256, blk, 0, stream>>>(N_SO, SO_SZ, decay_out,    pairsO, r_o);
  k_init_act<<<(BB*D_MODEL+255)/256, blk, 0, stream>>>(start_act, act);
  k_zero<<<(BB*SA_SZ+255)/256, blk, 0, stream>>>(a_a, BB*SA_SZ);
  k_init_trace<<<(BB*MEMN*D_MODEL+255)/256, blk, 0, stream>>>(start_trace, trace);
  k_init_ao<<<dim3((SO_SZ+255)/256, BB), blk, 0, stream>>>(start_act, pairsO, a_o);

  // ---- 16 recurrent iterations ----
  for (int t = 0; t < NITER; t++){
    k_syncA<<<dim3((SA_SZ+255)/256, BB), blk, 0, stream>>>(act, r_a, pairsA, a_a, sync_a, t);
    k_gemm<4,false><<<dim3(2,32), blk, 0, stream>>>(sync_a, SA_SZ, q_w, D_IN, 0, 0, q_b, qbuf, D_IN, D_IN, SA_SZ);
    k_gemm<4,false><<<dim3(2,32), blk, 0, stream>>>(qbuf, D_IN, in_proj_w, 1536, 0, 0, in_proj_b, qhbuf, D_IN, D_IN, D_IN);
    k_attn<<<BB*HEADS, 128, 0, stream>>>(qhbuf, Kmat, Vmat, obuf);
    k_gemm<4,false><<<dim3(2,32), blk, 0, stream>>>(obuf, D_IN, out_proj_w, D_IN, 0, 0, out_proj_b, o2buf, D_IN, D_IN, D_IN);
    k_gemm<4,false><<<dim3(8,32), blk, 0, stream>>>(o2buf, D_IN, syn_w, 2048, 0, 0, syn_b, synbuf, 2048, 2048, D_IN);
    k_gemm<4,true ><<<dim3(8,32), blk, 0, stream>>>(act, D_MODEL, syn_w, 2048, 512, 0, nullptr, synbuf, 2048, 2048, D_MODEL);
    k_glu_ln<<<BB, blk, 0, stream>>>(synbuf, syn_ln_g, syn_ln_b, trace + (size_t)(MEMN+t)*D_MODEL);
    k_neuron<<<(BB*D_MODEL+255)/256, blk, 0, stream>>>(trace, tp1_w, tp1_b, tp2_w, tp2_b, act, t);
    k_syncO<<<dim3((SO_SZ+255)/256, BB), blk, 0, stream>>>(act, r_o, pairsO, a_o, sync_oh, t);
    k_bigemm2<<<dim3(31, BGKS), blk, 0, stream>>>(sync_oh, out_w, part);
    k_output<<<BB, blk, 0, stream>>>(part, out_b, dout, t);
  }
}

// Round 5
// 7251.624 us; speedup vs baseline: 4.8906x; 1.2499x over previous
//
#include <hip/hip_runtime.h>
#include <math.h>

#define BB 128
#define SS 72
#define NITER 16
#define D_IN 512
#define D_MODEL 1024
#define MEMN 25
#define HEADS 8
#define DHH 64
#define N_SO 256
#define N_SA 64
#define SA_SZ 2080
#define SO_SZ 32896
#define NCLS 1968
#define TED 128
#define ROWS (BB*SS)
#define TRACE_SLOTS (MEMN + NITER)   /* 41 */

/* big-GEMM (sync_o @ out_w) tiling */
#define BGN 64          /* cols per block */
#define BGKS 16         /* k splits */
#define BGKLEN 2056     /* 32896/16 */
#define BGSTEPS 33      /* ceil(2056/64); last step has 8 valid k */
#define NPART 1984      /* 31*64 padded col count */
#define WHLD 1984       /* fp16 out_w padded row length */

typedef _Float16 half_t;
typedef _Float16 half8 __attribute__((ext_vector_type(8)));
typedef float f32x4v __attribute__((ext_vector_type(4)));

__device__ __forceinline__ float sigmoidf_(float x){ return 1.f/(1.f+expf(-x)); }

__device__ __forceinline__ float bsum256(float v, float* red){
  int tid = threadIdx.x; red[tid] = v; __syncthreads();
#pragma unroll
  for (int s = 128; s > 0; s >>= 1){ if (tid < s) red[tid] += red[tid+s]; __syncthreads(); }
  float r = red[0]; __syncthreads(); return r;
}

__device__ __forceinline__ long triu_off(int n, int i){
  return (long)i*n - ((long)i*(i-1))/2;
}

__device__ __forceinline__ int swzA(int b){ return b ^ (((b>>9)&1)<<5); }

// ---------------- setup kernels ----------------
__global__ void k_embed(const int* __restrict__ x, const float* __restrict__ emb,
                        float* __restrict__ out){
  int gid = blockIdx.x*256 + threadIdx.x;
  if (gid >= ROWS*TED) return;
  int row = gid >> 7, k = gid & 127;
  out[gid] = emb[x[row]*TED + k];
}

__global__ void k_init_pairs(int n, int npairs, const float* __restrict__ decay,
                             int2* __restrict__ pairs, float* __restrict__ rv){
  int p = blockIdx.x*256 + threadIdx.x;
  if (p >= npairs) return;
  double nn = (double)n;
  double disc = (2.0*nn+1.0)*(2.0*nn+1.0) - 8.0*(double)p;
  int i = (int)floor(((2.0*nn+1.0) - sqrt(disc))*0.5);
  if (i < 0) i = 0; if (i > n-1) i = n-1;
  while (i+1 < n && triu_off(n, i+1) <= (long)p) i++;
  while (i > 0 && triu_off(n, i) > (long)p) i--;
  int j = i + (int)((long)p - triu_off(n, i));
  pairs[p] = make_int2(i, j);
  float dc = decay[p]; dc = fminf(fmaxf(dc, 0.f), 15.f);
  rv[p] = expf(-dc);
}

__global__ void k_init_act(const float* __restrict__ sa, float* __restrict__ act){
  int gid = blockIdx.x*256 + threadIdx.x;
  if (gid >= BB*D_MODEL) return;
  act[gid] = sa[gid & 1023];
}

__global__ void k_zero(float* __restrict__ p, int n){
  int gid = blockIdx.x*256 + threadIdx.x;
  if (gid < n) p[gid] = 0.f;
}

__global__ void k_init_trace(const float* __restrict__ st, float* __restrict__ trace){
  int gid = blockIdx.x*256 + threadIdx.x;
  if (gid >= BB*MEMN*D_MODEL) return;
  int d = gid & 1023;
  int m = (gid >> 10) % MEMN;
  int b = (gid >> 10) / MEMN;
  trace[(size_t)b*TRACE_SLOTS*D_MODEL + (size_t)m*D_MODEL + d] = st[d*MEMN + m];
}

__global__ void k_init_ao(const float* __restrict__ sa, const int2* __restrict__ pairs,
                          float* __restrict__ ao){
  int p = blockIdx.x*256 + threadIdx.x;
  if (p >= SO_SZ) return;
  int b = blockIdx.y;
  int2 ij = pairs[p];
  ao[(size_t)b*SO_SZ + p] = sa[ij.x]*sa[ij.y];
}

// out_w (fp32, [32896][1968]) -> Wh (fp16, [32896][1984], zero-padded cols)
__global__ void k_convw(const float* __restrict__ W, half_t* __restrict__ Wh){
  int gid = blockIdx.x*256 + threadIdx.x;            // one half8 chunk
  if (gid >= SO_SZ*(WHLD/8)) return;
  int row = gid / (WHLD/8), c0 = (gid % (WHLD/8))*8;
  half8 v;
#pragma unroll
  for (int j = 0; j < 8; j++){
    int c = c0 + j;
    v[j] = (c < NCLS) ? (half_t)W[(size_t)row*NCLS + c] : (half_t)0.f;
  }
  *(half8*)(Wh + (size_t)row*WHLD + c0) = v;
}

// out[col] = sum_k vec[k]*W[k*ldw+col] + (addb?addb[col]:0)
__global__ void k_colsum(const float* __restrict__ vec, const float* __restrict__ W,
                         int ldw, const float* __restrict__ addb,
                         float* __restrict__ out, int N, int K){
  int col = blockIdx.x*256 + threadIdx.x;
  if (col >= N) return;
  float s = addb ? addb[col] : 0.f;
  for (int k = 0; k < K; k++) s = fmaf(vec[k], W[(size_t)k*ldw + col], s);
  out[col] = s;
}

// ---- generic fp32 GEMM:  C[M,N] = A[M,K] @ W[wrow0:,wcol0:] (+bias). REQUIRES K % 32 == 0 ----
template<int MB>
__global__ void k_gemm(const float* __restrict__ A, int lda,
                       const float* __restrict__ W, int ldw, int wrow0, int wcol0,
                       const float* __restrict__ bias,
                       float* __restrict__ C, int ldc, int N, int K){
  constexpr int KC = 32;
  const int tid = threadIdx.x;
  const int col = blockIdx.x*256 + tid;
  const int row0 = blockIdx.y*MB;
  __shared__ float As[MB][KC];
  float acc[MB];
#pragma unroll
  for (int r = 0; r < MB; r++) acc[r] = 0.f;
  for (int kk = 0; kk < K; kk += KC){
    __syncthreads();
    for (int idx = tid; idx < MB*KC; idx += 256){
      int r = idx / KC, k = idx % KC;
      As[r][k] = A[(size_t)(row0+r)*lda + kk + k];
    }
    __syncthreads();
#pragma unroll
    for (int k = 0; k < KC; k++){
      float w = W[(size_t)(wrow0+kk+k)*ldw + wcol0 + col];
#pragma unroll
      for (int r = 0; r < MB; r++) acc[r] = fmaf(As[r][k], w, acc[r]);
    }
  }
#pragma unroll
  for (int r = 0; r < MB; r++){
    size_t o = (size_t)(row0+r)*ldc + col;
    C[o] = acc[r] + (bias ? bias[col] : 0.f);
  }
}

// ---- q-fused GEMM, 4-way K-split: qpart[z] = sync_a @ qfw (k-range z) ----
__global__ void k_gemmq(const float* __restrict__ A, const float* __restrict__ W,
                        float* __restrict__ qpart){
  constexpr int KC = 32;
  const int tid = threadIdx.x;
  const int col = blockIdx.x*256 + tid;        // N=512, grid.x=2
  const int row0 = blockIdx.y*4;               // M=128, grid.y=32
  const int z = blockIdx.z;                    // 4 splits
  const int kstart = z*544;
  const int kend = min(SA_SZ, kstart + 544);   // 544,544,544,448 (all %32==0)
  __shared__ float As[4][KC];
  float acc[4] = {0.f,0.f,0.f,0.f};
  for (int kk = kstart; kk < kend; kk += KC){
    __syncthreads();
    for (int idx = tid; idx < 4*KC; idx += 256){
      int r = idx / KC, k = idx % KC;
      As[r][k] = A[(size_t)(row0+r)*SA_SZ + kk + k];
    }
    __syncthreads();
#pragma unroll
    for (int k = 0; k < KC; k++){
      float w = W[(size_t)(kk+k)*D_IN + col];
#pragma unroll
      for (int r = 0; r < 4; r++) acc[r] = fmaf(As[r][k], w, acc[r]);
    }
  }
#pragma unroll
  for (int r = 0; r < 4; r++)
    qpart[(size_t)z*BB*D_IN + (size_t)(row0+r)*D_IN + col] = acc[r];
}

// ---- fused syn GEMM: synbuf = obuf@Wf2 + act@syn_w[512:] + bias2 ----
__global__ void k_gemm2src(const float* __restrict__ A1, const float* __restrict__ A2,
                           const float* __restrict__ W1, const float* __restrict__ W2,
                           const float* __restrict__ bias2, float* __restrict__ Cout){
  constexpr int MB = 8, KC = 32;
  const int tid = threadIdx.x;
  const int col = blockIdx.x*256 + tid;        // N=2048, grid.x=8
  const int row0 = blockIdx.y*MB;              // M=128, grid.y=16
  __shared__ float As[MB][KC];
  float acc[MB];
#pragma unroll
  for (int r = 0; r < MB; r++) acc[r] = 0.f;
  for (int kk = 0; kk < 1536; kk += KC){
    __syncthreads();
    for (int idx = tid; idx < MB*KC; idx += 256){
      int r = idx / KC, k = idx % KC;
      int kg = kk + k;
      As[r][k] = (kg < D_IN) ? A1[(size_t)(row0+r)*D_IN + kg]
                             : A2[(size_t)(row0+r)*D_MODEL + kg - D_IN];
    }
    __syncthreads();
    const float* Wp = (kk < D_IN) ? W1 : W2;   // phase fully on one side (512%32==0)
#pragma unroll
    for (int k = 0; k < KC; k++){
      float w = Wp[(size_t)(kk+k)*2048 + col];
#pragma unroll
      for (int r = 0; r < MB; r++) acc[r] = fmaf(As[r][k], w, acc[r]);
    }
  }
#pragma unroll
  for (int r = 0; r < MB; r++)
    Cout[(size_t)(row0+r)*2048 + col] = acc[r] + bias2[col];
}

// ---------------- LayerNorm (block per row) ----------------
__global__ void k_ln(const float* __restrict__ X, const float* __restrict__ g,
                     const float* __restrict__ bta, float* __restrict__ Y, int D){
  const int row = blockIdx.x, tid = threadIdx.x;
  __shared__ float red[256];
  const float* xr = X + (size_t)row*D;
  float s = 0.f;
  for (int c = tid; c < D; c += 256) s += xr[c];
  float mean = bsum256(s, red) / (float)D;
  float s2 = 0.f;
  for (int c = tid; c < D; c += 256){ float d = xr[c]-mean; s2 += d*d; }
  float var = bsum256(s2, red) / (float)D;
  float inv = 1.f / sqrtf(var + 1e-5f);
  float* yr = Y + (size_t)row*D;
  for (int c = tid; c < D; c += 256) yr[c] = (xr[c]-mean)*inv*g[c] + bta[c];
}

// ---------------- GLU + LN -> write state into trace slot ----------------
__global__ void k_glu_ln(const float* __restrict__ syn, const float* __restrict__ g,
                         const float* __restrict__ bta, float* __restrict__ traceSlot){
  const int b = blockIdx.x, tid = threadIdx.x;
  __shared__ float vals[D_MODEL];
  __shared__ float red[256];
  const float* sr = syn + (size_t)b*2048;
  for (int c = tid; c < 1024; c += 256){
    float a = sr[c], gg = sr[c+1024];
    vals[c] = a * sigmoidf_(gg);
  }
  __syncthreads();
  float s = 0.f;
  for (int c = tid; c < 1024; c += 256) s += vals[c];
  float mean = bsum256(s, red) * (1.f/1024.f);
  float s2 = 0.f;
  for (int c = tid; c < 1024; c += 256){ float d = vals[c]-mean; s2 += d*d; }
  float var = bsum256(s2, red) * (1.f/1024.f);
  float inv = 1.f / sqrtf(var + 1e-5f);
  float* out = traceSlot + (size_t)b*(TRACE_SLOTS*D_MODEL);
  for (int c = tid; c < 1024; c += 256) out[c] = (vals[c]-mean)*inv*g[c] + bta[c];
}

// ---------------- attention: block per (b,h); q = sum of 4 qpart + bqf ----------------
__global__ void k_attn(const float* __restrict__ qpart, const float* __restrict__ bqf,
                       const float* __restrict__ Km, const float* __restrict__ Vm,
                       float* __restrict__ o){
  const int bh = blockIdx.x, b = bh >> 3, h = bh & 7;
  const int tid = threadIdx.x;
  __shared__ float qs[DHH];
  __shared__ float attn[SS];
  __shared__ float red[128];
  if (tid < DHH){
    int d = h*DHH + tid;
    float qv = bqf[d];
#pragma unroll
    for (int z = 0; z < 4; z++) qv += qpart[(size_t)z*BB*D_IN + (size_t)b*D_IN + d];
    qs[tid] = qv;
  }
  __syncthreads();
  float sc = -1e30f;
  if (tid < SS){
    const float* kp = Km + ((size_t)(b*SS+tid)*HEADS + h)*DHH;
    float d = 0.f;
#pragma unroll
    for (int i = 0; i < DHH; i++) d = fmaf(qs[i], kp[i], d);
    sc = d * 0.125f;
  }
  red[tid] = sc; __syncthreads();
  for (int s2 = 64; s2 > 0; s2 >>= 1){ if (tid < s2) red[tid] = fmaxf(red[tid], red[tid+s2]); __syncthreads(); }
  float m = red[0]; __syncthreads();
  float e = (tid < SS) ? expf(sc - m) : 0.f;
  red[tid] = e; __syncthreads();
  for (int s2 = 64; s2 > 0; s2 >>= 1){ if (tid < s2) red[tid] += red[tid+s2]; __syncthreads(); }
  float inv = 1.f / red[0]; __syncthreads();
  if (tid < SS) attn[tid] = e * inv;
  __syncthreads();
  if (tid < DHH){
    const float* vp = Vm + ((size_t)(b*SS)*HEADS + h)*DHH + tid;
    float acc = 0.f;
    for (int s2 = 0; s2 < SS; s2++) acc = fmaf(attn[s2], vp[(size_t)s2*D_IN], acc);
    o[(size_t)b*D_IN + h*DHH + tid] = acc;
  }
}

// ---- neuron update (trace->tp1->GLU->tp2->GLU), register-lean: 2 live h at a time ----
__global__ void k_neuron(const float* __restrict__ trace,
                         const float* __restrict__ tp1w, const float* __restrict__ tp1b,
                         const float* __restrict__ tp2w, const float* __restrict__ tp2b,
                         float* __restrict__ act, int t){
  int gid = blockIdx.x*256 + threadIdx.x;
  if (gid >= BB*D_MODEL) return;
  int b = gid >> 10, d = gid & 1023;
  const float* tr = trace + (size_t)b*(TRACE_SLOTS*D_MODEL) + (size_t)(t+1)*D_MODEL + d;
  float trv[MEMN];
#pragma unroll
  for (int m = 0; m < MEMN; m++) trv[m] = tr[(size_t)m*D_MODEL];
  float o0 = tp2b[d*2+0], o1 = tp2b[d*2+1];
#pragma unroll
  for (int j = 0; j < 16; j++){
    const float* wpj = tp1w + (size_t)j*1024 + d;
    const float* wpg = tp1w + (size_t)(j+16)*1024 + d;
    float hj = tp1b[d*32 + j];
    float hg = tp1b[d*32 + j + 16];
#pragma unroll
    for (int m = 0; m < MEMN; m++){
      float tv = trv[m];
      hj = fmaf(tv, wpj[(size_t)m*32*1024], hj);
      hg = fmaf(tv, wpg[(size_t)m*32*1024], hg);
    }
    float hgv = hj * sigmoidf_(hg);
    o0 = fmaf(hgv, tp2w[(size_t)(j*2+0)*1024 + d], o0);
    o1 = fmaf(hgv, tp2w[(size_t)(j*2+1)*1024 + d], o1);
  }
  act[gid] = o0 * sigmoidf_(o1);
}

// ---------------- sync accumulators ----------------
__global__ void k_syncA(const float* __restrict__ act, const float* __restrict__ rv,
                        const int2* __restrict__ pairs, float* __restrict__ aa,
                        float* __restrict__ syncv, int t){
  int p = blockIdx.x*256 + threadIdx.x;
  if (p >= SA_SZ) return;
  int b = blockIdx.y;
  int2 ij = pairs[p];
  const float* ab = act + (size_t)b*D_MODEL + (D_MODEL - N_SA);
  float r = rv[p];
  size_t idx = (size_t)b*SA_SZ + p;
  float a = fmaf(r, aa[idx], ab[ij.x]*ab[ij.y]);
  aa[idx] = a;
  float bb = 0.f;
  for (int i = 0; i <= t; i++) bb = fmaf(r, bb, 1.f);
  syncv[idx] = a / sqrtf(bb);
}

__global__ void k_syncO(const float* __restrict__ act, const float* __restrict__ rv,
                        const int2* __restrict__ pairs, float* __restrict__ ao,
                        half_t* __restrict__ syncv, int t){
  int p = blockIdx.x*256 + threadIdx.x;
  if (p >= SO_SZ) return;
  int b = blockIdx.y;
  int2 ij = pairs[p];
  const float* ab = act + (size_t)b*D_MODEL;
  float r = rv[p];
  size_t idx = (size_t)b*SO_SZ + p;
  float a = fmaf(r, ao[idx], ab[ij.x]*ab[ij.y]);
  ao[idx] = a;
  float bb = 1.f;
  for (int i = 0; i <= t; i++) bb = fmaf(r, bb, 1.f);
  syncv[idx] = (half_t)(a / sqrtf(bb));
}

// ---------------- big GEMM via fp16 MFMA (fp32-W fallback path) ----------------
__global__ __launch_bounds__(256)
void k_bigemm2(const half_t* __restrict__ Ah, const float* __restrict__ W,
               float* __restrict__ part){
  __shared__ half_t As[2][128*64];
  __shared__ half_t Ws[2][64*66];
  const int tid = threadIdx.x;
  const int z = blockIdx.y;
  const int nb0 = blockIdx.x * BGN;
  const int l = tid & 63, wv = tid >> 6;
  const int mw = (wv >> 1) * 64, nw = (wv & 1) * 32;
  const int c = l & 15, g = l >> 4;
  const int k0 = z * BGKLEN;

  f32x4v acc[4][2];
#pragma unroll
  for (int i = 0; i < 4; i++)
#pragma unroll
    for (int j2 = 0; j2 < 2; j2++)
#pragma unroll
      for (int r = 0; r < 4; r++) acc[i][j2][r] = 0.f;

  auto stage = [&](int s, int buf){
    const int kv = min(64, BGKLEN - s*64);
#pragma unroll
    for (int it = 0; it < 4; it++){
      int ch = tid + it*256;
      int m = ch >> 3, kg = ch & 7, kl = kg*8;
      half8 v;
      if (kl < kv) v = *(const half8*)(Ah + (size_t)m*SO_SZ + k0 + s*64 + kl);
      else {
#pragma unroll
        for (int j = 0; j < 8; j++) v[j] = (half_t)0.f;
      }
      *(half8*)((char*)(&As[buf][0]) + swzA(ch*16)) = v;
    }
    {
      int k = tid >> 2, cs = (tid & 3) * 16;
      const float* wr = W + (size_t)(k0 + s*64 + k) * NCLS + nb0 + cs;
      char* dst = (char*)(&Ws[buf][0]) + (size_t)(k*66 + cs) * 2;
      bool kvalid = (k < kv);
#pragma unroll
      for (int q = 0; q < 4; q++){
        float x0 = 0.f, x1 = 0.f, x2 = 0.f, x3 = 0.f;
        int col = nb0 + cs + q*4;
        if (kvalid && col < NCLS){
          float4 wvv = *(const float4*)(wr + q*4);
          x0 = wvv.x; x1 = wvv.y; x2 = wvv.z; x3 = wvv.w;
        }
        union { half_t h[4]; unsigned int u[2]; } pk;
        pk.h[0] = (half_t)x0; pk.h[1] = (half_t)x1;
        pk.h[2] = (half_t)x2; pk.h[3] = (half_t)x3;
        *(unsigned int*)(dst + q*8)     = pk.u[0];
        *(unsigned int*)(dst + q*8 + 4) = pk.u[1];
      }
    }
  };

  stage(0, 0);
  __syncthreads();
  for (int s = 0; s < BGSTEPS; s++){
    int buf = s & 1;
    if (s + 1 < BGSTEPS) stage(s+1, buf^1);
#pragma unroll
    for (int h = 0; h < 2; h++){
      half8 a8[4];
#pragma unroll
      for (int mb = 0; mb < 4; mb++)
        a8[mb] = *(const half8*)((const char*)(&As[buf][0]) +
                   swzA(((mw + mb*16 + c)*64 + h*32 + g*8)*2));
#pragma unroll
      for (int nb = 0; nb < 2; nb++){
        half8 b8;
        const half_t* wp = &Ws[buf][(h*32 + g*8)*66 + nw + nb*16 + c];
#pragma unroll
        for (int j = 0; j < 8; j++) b8[j] = wp[j*66];
#pragma unroll
        for (int mb = 0; mb < 4; mb++)
          acc[mb][nb] = __builtin_amdgcn_mfma_f32_16x16x32_f16(a8[mb], b8, acc[mb][nb], 0, 0, 0);
      }
    }
    __syncthreads();
  }
  float* pz = part + (size_t)z * 128 * NPART;
#pragma unroll
  for (int mb = 0; mb < 4; mb++)
#pragma unroll
    for (int nb = 0; nb < 2; nb++){
      int m = mw + mb*16 + g*4;
      int n = nb0 + nw + nb*16 + c;
#pragma unroll
      for (int r = 0; r < 4; r++)
        pz[(size_t)(m + r) * NPART + n] = acc[mb][nb][r];
    }
}

// ---------------- big GEMM, fp16-W path (Wh pre-converted, padded [32896][1984]) ----------------
__global__ __launch_bounds__(256)
void k_bigemm2h(const half_t* __restrict__ Ah, const half_t* __restrict__ Wh,
                float* __restrict__ part){
  __shared__ half_t As[2][128*64];
  __shared__ half_t Ws[2][64*66];
  const int tid = threadIdx.x;
  const int z = blockIdx.y;
  const int nb0 = blockIdx.x * BGN;
  const int l = tid & 63, wv = tid >> 6;
  const int mw = (wv >> 1) * 64, nw = (wv & 1) * 32;
  const int c = l & 15, g = l >> 4;
  const int k0 = z * BGKLEN;

  f32x4v acc[4][2];
#pragma unroll
  for (int i = 0; i < 4; i++)
#pragma unroll
    for (int j2 = 0; j2 < 2; j2++)
#pragma unroll
      for (int r = 0; r < 4; r++) acc[i][j2][r] = 0.f;

  auto stage = [&](int s, int buf){
    const int kv = min(64, BGKLEN - s*64);
#pragma unroll
    for (int it = 0; it < 4; it++){
      int ch = tid + it*256;
      int m = ch >> 3, kg = ch & 7, kl = kg*8;
      half8 v;
      if (kl < kv) v = *(const half8*)(Ah + (size_t)m*SO_SZ + k0 + s*64 + kl);
      else {
#pragma unroll
        for (int j = 0; j < 8; j++) v[j] = (half_t)0.f;
      }
      *(half8*)((char*)(&As[buf][0]) + swzA(ch*16)) = v;
    }
    {
      int k = tid >> 2, cs = (tid & 3) * 16;
      const half_t* wr = Wh + (size_t)(k0 + s*64 + k) * WHLD + nb0 + cs;
      char* dst = (char*)(&Ws[buf][0]) + (size_t)(k*66 + cs) * 2;
      union { half8 v; unsigned int u[4]; } p0, p1;
      if (k < kv){ p0.v = *(const half8*)wr; p1.v = *(const half8*)(wr + 8); }
      else {
#pragma unroll
        for (int j = 0; j < 8; j++){ p0.v[j] = (half_t)0.f; p1.v[j] = (half_t)0.f; }
      }
#pragma unroll
      for (int q = 0; q < 4; q++){
        ((unsigned int*)dst)[q]        = p0.u[q];
        ((unsigned int*)(dst + 16))[q] = p1.u[q];
      }
    }
  };

  stage(0, 0);
  __syncthreads();
  for (int s = 0; s < BGSTEPS; s++){
    int buf = s & 1;
    if (s + 1 < BGSTEPS) stage(s+1, buf^1);
#pragma unroll
    for (int h = 0; h < 2; h++){
      half8 a8[4];
#pragma unroll
      for (int mb = 0; mb < 4; mb++)
        a8[mb] = *(const half8*)((const char*)(&As[buf][0]) +
                   swzA(((mw + mb*16 + c)*64 + h*32 + g*8)*2));
#pragma unroll
      for (int nb = 0; nb < 2; nb++){
        half8 b8;
        const half_t* wp = &Ws[buf][(h*32 + g*8)*66 + nw + nb*16 + c];
#pragma unroll
        for (int j = 0; j < 8; j++) b8[j] = wp[j*66];
#pragma unroll
        for (int mb = 0; mb < 4; mb++)
          acc[mb][nb] = __builtin_amdgcn_mfma_f32_16x16x32_f16(a8[mb], b8, acc[mb][nb], 0, 0, 0);
      }
    }
    __syncthreads();
  }
  float* pz = part + (size_t)z * 128 * NPART;
#pragma unroll
  for (int mb = 0; mb < 4; mb++)
#pragma unroll
    for (int nb = 0; nb < 2; nb++){
      int m = mw + mb*16 + g*4;
      int n = nb0 + nw + nb*16 + c;
#pragma unroll
      for (int r = 0; r < 4; r++)
        pz[(size_t)(m + r) * NPART + n] = acc[mb][nb][r];
    }
}

// ---------------- combine partials + bias, write preds + certainties ----------------
__global__ void k_output(const float* __restrict__ part, const float* __restrict__ outb,
                         float* __restrict__ dout, int t){
  const int b = blockIdx.x, tid = threadIdx.x;
  __shared__ float pred[NCLS];
  __shared__ float red[256];
  float lmax = -1e30f;
  for (int c = tid; c < NCLS; c += 256){
    float s = outb[c];
    const float* pp = part + (size_t)b*NPART + c;
#pragma unroll
    for (int z = 0; z < BGKS; z++) s += pp[(size_t)z*128*NPART];
    pred[c] = s;
    dout[((size_t)b*NCLS + c)*NITER + t] = s;
    lmax = fmaxf(lmax, s);
  }
  red[tid] = lmax; __syncthreads();
  for (int s2 = 128; s2 > 0; s2 >>= 1){ if (tid < s2) red[tid] = fmaxf(red[tid], red[tid+s2]); __syncthreads(); }
  float m = red[0]; __syncthreads();
  float se = 0.f;
  for (int c = tid; c < NCLS; c += 256) se += expf(pred[c]-m);
  float Z = bsum256(se, red);
  float logZ = m + logf(Z);
  float ent = 0.f;
  for (int c = tid; c < NCLS; c += 256){ float lp = pred[c]-logZ; ent += expf(lp)*lp; }
  float E = bsum256(ent, red);
  if (tid == 0){
    float ne = -E * (1.f/logf((float)NCLS));
    float* cp = dout + (size_t)BB*NCLS*NITER + (size_t)b*2*NITER + t;
    cp[0]     = ne;
    cp[NITER] = 1.f - ne;
  }
}

// ---------------- launch ----------------
extern "C" void kernel_launch(void* const* d_in, const int* in_sizes, int n_in,
                              void* d_out, int out_size, void* d_ws, size_t ws_size,
                              hipStream_t stream){
  const int*   x           = (const int*)  d_in[0];
  const float* emb         = (const float*)d_in[1];
  const float* kv_w        = (const float*)d_in[2];
  const float* kv_b        = (const float*)d_in[3];
  const float* kv_ln_g     = (const float*)d_in[4];
  const float* kv_ln_b     = (const float*)d_in[5];
  const float* q_w         = (const float*)d_in[6];
  const float* q_b         = (const float*)d_in[7];
  const float* in_proj_w   = (const float*)d_in[8];
  const float* in_proj_b   = (const float*)d_in[9];
  const float* out_proj_w  = (const float*)d_in[10];
  const float* out_proj_b  = (const float*)d_in[11];
  const float* syn_w       = (const float*)d_in[12];
  const float* syn_b       = (const float*)d_in[13];
  const float* syn_ln_g    = (const float*)d_in[14];
  const float* syn_ln_b    = (const float*)d_in[15];
  const float* tp1_w       = (const float*)d_in[16];
  const float* tp1_b       = (const float*)d_in[17];
  const float* tp2_w       = (const float*)d_in[18];
  const float* tp2_b       = (const float*)d_in[19];
  const float* start_act   = (const float*)d_in[20];
  const float* start_trace = (const float*)d_in[21];
  const float* decay_action= (const float*)d_in[22];
  const float* decay_out   = (const float*)d_in[23];
  const float* out_w       = (const float*)d_in[24];
  const float* out_b       = (const float*)d_in[25];
  float* dout = (float*)d_out;

  // ---- workspace layout (float units, 16B-aligned allocs) ----
  float* w = (float*)d_ws;
  size_t off = 0;
  auto alloc = [&](size_t n){ n = (n + 3) & ~(size_t)3; float* p = w + off; off += n; return p; };
  float* region0 = alloc((size_t)BGKS*128*NPART);    // embx (setup) / bigemm partials (iter)
  float* region1 = alloc((size_t)ROWS*D_IN);         // kv (setup) / a_o (iter)
  float* Kmat    = alloc((size_t)ROWS*D_IN);
  float* Vmat    = alloc((size_t)ROWS*D_IN);
  float* trace   = alloc((size_t)BB*TRACE_SLOTS*D_MODEL);
  half_t* sync_oh= (half_t*)alloc((size_t)BB*SO_SZ/2);
  float* a_a     = alloc((size_t)BB*SA_SZ);
  float* sync_a  = alloc((size_t)BB*SA_SZ);
  float* act     = alloc((size_t)BB*D_MODEL);
  float* qpart   = alloc((size_t)4*BB*D_IN);
  float* obuf    = alloc((size_t)BB*D_IN);
  float* synbuf  = alloc((size_t)BB*2048);
  float* qfw     = alloc((size_t)SA_SZ*D_IN);        // q_w @ Wq  (2080x512)
  float* Wf2     = alloc((size_t)D_IN*2048);         // out_proj @ syn_w_top (512x2048)
  float* bqf     = alloc(D_IN);
  float* bias2   = alloc(2048);
  float* r_a     = alloc(SA_SZ);
  float* r_o     = alloc(SO_SZ);
  int2*  pairsA  = (int2*)alloc(2*SA_SZ);
  int2*  pairsO  = (int2*)alloc(2*SO_SZ);
  half_t* Wh     = (half_t*)alloc(((size_t)SO_SZ*WHLD)/2);   // optional fp16 out_w
  const bool use_fp16w = (off * sizeof(float) <= ws_size);

  float* embx  = region0;
  float* part  = region0;
  float* kvbuf = region1;
  float* a_o   = region1;

  dim3 blk(256);

  // ---- setup ----
  k_embed<<<(ROWS*TED+255)/256, blk, 0, stream>>>(x, emb, embx);
  k_gemm<16><<<dim3(2, ROWS/16), blk, 0, stream>>>(embx, TED, kv_w, D_IN, 0, 0, kv_b, kvbuf, D_IN, D_IN, TED);
  k_ln<<<ROWS, blk, 0, stream>>>(kvbuf, kv_ln_g, kv_ln_b, kvbuf, D_IN);
  k_gemm<16><<<dim3(2, ROWS/16), blk, 0, stream>>>(kvbuf, D_IN, in_proj_w, 1536, 0, 512,  in_proj_b+512,  Kmat, D_IN, D_IN, D_IN);
  k_gemm<16><<<dim3(2, ROWS/16), blk, 0, stream>>>(kvbuf, D_IN, in_proj_w, 1536, 0, 1024, in_proj_b+1024, Vmat, D_IN, D_IN, D_IN);
  // fused weights: qfw = q_w @ Wq ; Wf2 = out_proj_w @ syn_w[:512]
  k_gemm<16><<<dim3(2, SA_SZ/16), blk, 0, stream>>>(q_w, D_IN, in_proj_w, 1536, 0, 0, nullptr, qfw, D_IN, D_IN, D_IN);
  k_gemm<16><<<dim3(8, D_IN/16), blk, 0, stream>>>(out_proj_w, D_IN, syn_w, 2048, 0, 0, nullptr, Wf2, 2048, 2048, D_IN);
  k_colsum<<<2, blk, 0, stream>>>(q_b, in_proj_w, 1536, in_proj_b, bqf, D_IN, D_IN);
  k_colsum<<<8, blk, 0, stream>>>(out_proj_b, syn_w, 2048, syn_b, bias2, 2048, D_IN);
  if (use_fp16w)
    k_convw<<<(SO_SZ*(WHLD/8)+255)/256, blk, 0, stream>>>(out_w, Wh);
  k_init_pairs<<<(SA_SZ+255)/256, blk, 0, stream>>>(N_SA, SA_SZ, decay_action, pairsA, r_a);
  k_init_pairs<<<(SO_SZ+255)/256, blk, 0, stream>>>(N_SO, SO_SZ, decay_out,    pairsO, r_o);
  k_init_act<<<(BB*D_MODEL+255)/256, blk, 0, stream>>>(start_act, act);
  k_zero<<<(BB*SA_SZ+255)/256, blk, 0, stream>>>(a_a, BB*SA_SZ);
  k_init_trace<<<(BB*MEMN*D_MODEL+255)/256, blk, 0, stream>>>(start_trace, trace);
  k_init_ao<<<dim3((SO_SZ+255)/256, BB), blk, 0, stream>>>(start_act, pairsO, a_o);

  // ---- 16 recurrent iterations ----
  for (int t = 0; t < NITER; t++){
    k_syncA<<<dim3((SA_SZ+255)/256, BB), blk, 0, stream>>>(act, r_a, pairsA, a_a, sync_a, t);
    k_gemmq<<<dim3(2, 32, 4), blk, 0, stream>>>(sync_a, qfw, qpart);
    k_attn<<<BB*HEADS, 128, 0, stream>>>(qpart, bqf, Kmat, Vmat, obuf);
    k_gemm2src<<<dim3(8, 16), blk, 0, stream>>>(obuf, act, Wf2, syn_w, bias2, synbuf);
    k_glu_ln<<<BB, blk, 0, stream>>>(synbuf, syn_ln_g, syn_ln_b, trace + (size_t)(MEMN+t)*D_MODEL);
    k_neuron<<<(BB*D_MODEL+255)/256, blk, 0, stream>>>(trace, tp1_w, tp1_b, tp2_w, tp2_b, act, t);
    k_syncO<<<dim3((SO_SZ+255)/256, BB), blk, 0, stream>>>(act, r_o, pairsO, a_o, sync_oh, t);
    if (use_fp16w)
      k_bigemm2h<<<dim3(31, BGKS), blk, 0, stream>>>(sync_oh, Wh, part);
    else
      k_bigemm2<<<dim3(31, BGKS), blk, 0, stream>>>(sync_oh, out_w, part);
    k_output<<<BB, blk, 0, stream>>>(part, out_b, dout, t);
  }
}

// Round 6
// 3825.084 us; speedup vs baseline: 9.2716x; 1.8958x over previous
//
#include <hip/hip_runtime.h>
#include <math.h>

#define BB 128
#define SS 72
#define NITER 16
#define D_IN 512
#define D_MODEL 1024
#define MEMN 25
#define HEADS 8
#define DHH 64
#define N_SO 256
#define N_SA 64
#define SA_SZ 2080
#define SO_SZ 32896
#define NCLS 1968
#define TED 128
#define ROWS (BB*SS)
#define TRACE_SLOTS (MEMN + NITER)   /* 41 */

/* big-GEMM (sync_o @ out_w) tiling */
#define BGN 64          /* cols per block */
#define BGKS 16         /* k splits */
#define BGKLEN 2056     /* 32896/16 */
#define BGSTEPS 33      /* ceil(2056/64); last step has 8 valid k */
#define NPART 1984      /* 31*64 padded col count */
#define WHLD 1984       /* fp16 out_w padded row length */
#define SYNZ 6          /* K-splits for syn GEMM (1536/256) */

typedef _Float16 half_t;
typedef _Float16 half8 __attribute__((ext_vector_type(8)));
typedef float f32x4v __attribute__((ext_vector_type(4)));

__device__ __forceinline__ float sigmoidf_(float x){ return 1.f/(1.f+expf(-x)); }

__device__ __forceinline__ float bsum256(float v, float* red){
  int tid = threadIdx.x; red[tid] = v; __syncthreads();
#pragma unroll
  for (int s = 128; s > 0; s >>= 1){ if (tid < s) red[tid] += red[tid+s]; __syncthreads(); }
  float r = red[0]; __syncthreads(); return r;
}

__device__ __forceinline__ long triu_off(int n, int i){
  return (long)i*n - ((long)i*(i-1))/2;
}

__device__ __forceinline__ int swzA(int b){ return b ^ (((b>>9)&1)<<5); }

// ---------------- setup kernels ----------------
__global__ void k_embed(const int* __restrict__ x, const float* __restrict__ emb,
                        float* __restrict__ out){
  int gid = blockIdx.x*256 + threadIdx.x;
  if (gid >= ROWS*TED) return;
  int row = gid >> 7, k = gid & 127;
  out[gid] = emb[x[row]*TED + k];
}

__global__ void k_init_pairs(int n, int npairs, const float* __restrict__ decay,
                             int2* __restrict__ pairs, float* __restrict__ rv){
  int p = blockIdx.x*256 + threadIdx.x;
  if (p >= npairs) return;
  double nn = (double)n;
  double disc = (2.0*nn+1.0)*(2.0*nn+1.0) - 8.0*(double)p;
  int i = (int)floor(((2.0*nn+1.0) - sqrt(disc))*0.5);
  if (i < 0) i = 0; if (i > n-1) i = n-1;
  while (i+1 < n && triu_off(n, i+1) <= (long)p) i++;
  while (i > 0 && triu_off(n, i) > (long)p) i--;
  int j = i + (int)((long)p - triu_off(n, i));
  pairs[p] = make_int2(i, j);
  float dc = decay[p]; dc = fminf(fmaxf(dc, 0.f), 15.f);
  rv[p] = expf(-dc);
}

__global__ void k_init_act(const float* __restrict__ sa, float* __restrict__ act){
  int gid = blockIdx.x*256 + threadIdx.x;
  if (gid >= BB*D_MODEL) return;
  act[gid] = sa[gid & 1023];
}

__global__ void k_zero(float* __restrict__ p, int n){
  int gid = blockIdx.x*256 + threadIdx.x;
  if (gid < n) p[gid] = 0.f;
}

__global__ void k_init_trace(const float* __restrict__ st, float* __restrict__ trace){
  int gid = blockIdx.x*256 + threadIdx.x;
  if (gid >= BB*MEMN*D_MODEL) return;
  int d = gid & 1023;
  int m = (gid >> 10) % MEMN;
  int b = (gid >> 10) / MEMN;
  trace[(size_t)b*TRACE_SLOTS*D_MODEL + (size_t)m*D_MODEL + d] = st[d*MEMN + m];
}

__global__ void k_init_ao(const float* __restrict__ sa, const int2* __restrict__ pairs,
                          float* __restrict__ ao){
  int p = blockIdx.x*256 + threadIdx.x;
  if (p >= SO_SZ) return;
  int b = blockIdx.y;
  int2 ij = pairs[p];
  ao[(size_t)b*SO_SZ + p] = sa[ij.x]*sa[ij.y];
}

// out_w (fp32, [32896][1968]) -> Wh (fp16, [32896][1984], zero-padded cols)
__global__ void k_convw(const float* __restrict__ W, half_t* __restrict__ Wh){
  int gid = blockIdx.x*256 + threadIdx.x;            // one half8 chunk
  if (gid >= SO_SZ*(WHLD/8)) return;
  int row = gid / (WHLD/8), c0 = (gid % (WHLD/8))*8;
  half8 v;
#pragma unroll
  for (int j = 0; j < 8; j++){
    int c = c0 + j;
    v[j] = (c < NCLS) ? (half_t)W[(size_t)row*NCLS + c] : (half_t)0.f;
  }
  *(half8*)(Wh + (size_t)row*WHLD + c0) = v;
}

// out[col] = sum_k vec[k]*W[k*ldw+col] + (addb?addb[col]:0)
__global__ void k_colsum(const float* __restrict__ vec, const float* __restrict__ W,
                         int ldw, const float* __restrict__ addb,
                         float* __restrict__ out, int N, int K){
  int col = blockIdx.x*256 + threadIdx.x;
  if (col >= N) return;
  float s = addb ? addb[col] : 0.f;
  for (int k = 0; k < K; k++) s = fmaf(vec[k], W[(size_t)k*ldw + col], s);
  out[col] = s;
}

// ---- generic fp32 GEMM:  C[M,N] = A[M,K] @ W[wrow0:,wcol0:] (+bias). REQUIRES K % 32 == 0 ----
// MB=8: latency-bound streamer; block count is the controlling variable (R5 lesson).
template<int MB>
__global__ void k_gemm(const float* __restrict__ A, int lda,
                       const float* __restrict__ W, int ldw, int wrow0, int wcol0,
                       const float* __restrict__ bias,
                       float* __restrict__ C, int ldc, int N, int K){
  constexpr int KC = 32;
  const int tid = threadIdx.x;
  const int col = blockIdx.x*256 + tid;
  const int row0 = blockIdx.y*MB;
  __shared__ float As[MB][KC];
  float acc[MB];
#pragma unroll
  for (int r = 0; r < MB; r++) acc[r] = 0.f;
  for (int kk = 0; kk < K; kk += KC){
    __syncthreads();
    for (int idx = tid; idx < MB*KC; idx += 256){
      int r = idx / KC, k = idx % KC;
      As[r][k] = A[(size_t)(row0+r)*lda + kk + k];
    }
    __syncthreads();
#pragma unroll
    for (int k = 0; k < KC; k++){
      float w = W[(size_t)(wrow0+kk+k)*ldw + wcol0 + col];
#pragma unroll
      for (int r = 0; r < MB; r++) acc[r] = fmaf(As[r][k], w, acc[r]);
    }
  }
#pragma unroll
  for (int r = 0; r < MB; r++){
    size_t o = (size_t)(row0+r)*ldc + col;
    C[o] = acc[r] + (bias ? bias[col] : 0.f);
  }
}

// ---- q-fused GEMM, 4-way K-split: qpart[z] = sync_a @ qfw (k-range z) ----
__global__ void k_gemmq(const float* __restrict__ A, const float* __restrict__ W,
                        float* __restrict__ qpart){
  constexpr int KC = 32;
  const int tid = threadIdx.x;
  const int col = blockIdx.x*256 + tid;        // N=512, grid.x=2
  const int row0 = blockIdx.y*4;               // M=128, grid.y=32
  const int z = blockIdx.z;                    // 4 splits
  const int kstart = z*544;
  const int kend = min(SA_SZ, kstart + 544);   // 544,544,544,448 (all %32==0)
  __shared__ float As[4][KC];
  float acc[4] = {0.f,0.f,0.f,0.f};
  for (int kk = kstart; kk < kend; kk += KC){
    __syncthreads();
    for (int idx = tid; idx < 4*KC; idx += 256){
      int r = idx / KC, k = idx % KC;
      As[r][k] = A[(size_t)(row0+r)*SA_SZ + kk + k];
    }
    __syncthreads();
#pragma unroll
    for (int k = 0; k < KC; k++){
      float w = W[(size_t)(kk+k)*D_IN + col];
#pragma unroll
      for (int r = 0; r < 4; r++) acc[r] = fmaf(As[r][k], w, acc[r]);
    }
  }
#pragma unroll
  for (int r = 0; r < 4; r++)
    qpart[(size_t)z*BB*D_IN + (size_t)(row0+r)*D_IN + col] = acc[r];
}

// ---- fused syn GEMM, 6-way K-split: synpart[z] = [obuf|act] @ [Wf2|syn_w] (k-chunk z of 256) ----
__global__ void k_gemm2srcZ(const float* __restrict__ A1, const float* __restrict__ A2,
                            const float* __restrict__ W1, const float* __restrict__ W2,
                            float* __restrict__ outp){
  constexpr int MB = 8, KC = 32;
  const int tid = threadIdx.x;
  const int col = blockIdx.x*256 + tid;        // N=2048, grid.x=8
  const int row0 = blockIdx.y*MB;              // M=128, grid.y=16
  const int z = blockIdx.z;                    // 6 chunks of 256 (512 boundary = 2*256, never crossed)
  __shared__ float As[MB][KC];
  float acc[MB];
#pragma unroll
  for (int r = 0; r < MB; r++) acc[r] = 0.f;
  for (int kk = z*256; kk < z*256 + 256; kk += KC){
    __syncthreads();
    for (int idx = tid; idx < MB*KC; idx += 256){
      int r = idx / KC, k = idx % KC;
      int kg = kk + k;
      As[r][k] = (kg < D_IN) ? A1[(size_t)(row0+r)*D_IN + kg]
                             : A2[(size_t)(row0+r)*D_MODEL + kg - D_IN];
    }
    __syncthreads();
    const float* Wp = (kk < D_IN) ? W1 : W2;   // W2 indexed by absolute row (syn_w rows 512..1535)
#pragma unroll
    for (int k = 0; k < KC; k++){
      float w = Wp[(size_t)(kk+k)*2048 + col];
#pragma unroll
      for (int r = 0; r < MB; r++) acc[r] = fmaf(As[r][k], w, acc[r]);
    }
  }
#pragma unroll
  for (int r = 0; r < MB; r++)
    outp[(size_t)z*BB*2048 + (size_t)(row0+r)*2048 + col] = acc[r];
}

// ---------------- LayerNorm (block per row) ----------------
__global__ void k_ln(const float* __restrict__ X, const float* __restrict__ g,
                     const float* __restrict__ bta, float* __restrict__ Y, int D){
  const int row = blockIdx.x, tid = threadIdx.x;
  __shared__ float red[256];
  const float* xr = X + (size_t)row*D;
  float s = 0.f;
  for (int c = tid; c < D; c += 256) s += xr[c];
  float mean = bsum256(s, red) / (float)D;
  float s2 = 0.f;
  for (int c = tid; c < D; c += 256){ float d = xr[c]-mean; s2 += d*d; }
  float var = bsum256(s2, red) / (float)D;
  float inv = 1.f / sqrtf(var + 1e-5f);
  float* yr = Y + (size_t)row*D;
  for (int c = tid; c < D; c += 256) yr[c] = (xr[c]-mean)*inv*g[c] + bta[c];
}

// ---- sum 6 synpart + bias2 -> GLU -> LN -> trace slot ----
__global__ void k_glu_ln(const float* __restrict__ synpart, const float* __restrict__ bias2,
                         const float* __restrict__ g, const float* __restrict__ bta,
                         float* __restrict__ traceSlot){
  const int b = blockIdx.x, tid = threadIdx.x;
  __shared__ float vals[D_MODEL];
  __shared__ float red[256];
  for (int c = tid; c < 1024; c += 256){
    float a = bias2[c], gg = bias2[c+1024];
#pragma unroll
    for (int z = 0; z < SYNZ; z++){
      const float* sp = synpart + (size_t)z*BB*2048 + (size_t)b*2048;
      a  += sp[c];
      gg += sp[c+1024];
    }
    vals[c] = a * sigmoidf_(gg);
  }
  __syncthreads();
  float s = 0.f;
  for (int c = tid; c < 1024; c += 256) s += vals[c];
  float mean = bsum256(s, red) * (1.f/1024.f);
  float s2 = 0.f;
  for (int c = tid; c < 1024; c += 256){ float d = vals[c]-mean; s2 += d*d; }
  float var = bsum256(s2, red) * (1.f/1024.f);
  float inv = 1.f / sqrtf(var + 1e-5f);
  float* out = traceSlot + (size_t)b*(TRACE_SLOTS*D_MODEL);
  for (int c = tid; c < 1024; c += 256) out[c] = (vals[c]-mean)*inv*g[c] + bta[c];
}

// ---------------- attention: block per (b,h); q = sum of 4 qpart + bqf ----------------
__global__ void k_attn(const float* __restrict__ qpart, const float* __restrict__ bqf,
                       const float* __restrict__ Km, const float* __restrict__ Vm,
                       float* __restrict__ o){
  const int bh = blockIdx.x, b = bh >> 3, h = bh & 7;
  const int tid = threadIdx.x;
  __shared__ float qs[DHH];
  __shared__ float attn[SS];
  __shared__ float red[128];
  if (tid < DHH){
    int d = h*DHH + tid;
    float qv = bqf[d];
#pragma unroll
    for (int z = 0; z < 4; z++) qv += qpart[(size_t)z*BB*D_IN + (size_t)b*D_IN + d];
    qs[tid] = qv;
  }
  __syncthreads();
  float sc = -1e30f;
  if (tid < SS){
    const float* kp = Km + ((size_t)(b*SS+tid)*HEADS + h)*DHH;
    float d = 0.f;
#pragma unroll
    for (int i = 0; i < DHH; i++) d = fmaf(qs[i], kp[i], d);
    sc = d * 0.125f;
  }
  red[tid] = sc; __syncthreads();
  for (int s2 = 64; s2 > 0; s2 >>= 1){ if (tid < s2) red[tid] = fmaxf(red[tid], red[tid+s2]); __syncthreads(); }
  float m = red[0]; __syncthreads();
  float e = (tid < SS) ? expf(sc - m) : 0.f;
  red[tid] = e; __syncthreads();
  for (int s2 = 64; s2 > 0; s2 >>= 1){ if (tid < s2) red[tid] += red[tid+s2]; __syncthreads(); }
  float inv = 1.f / red[0]; __syncthreads();
  if (tid < SS) attn[tid] = e * inv;
  __syncthreads();
  if (tid < DHH){
    const float* vp = Vm + ((size_t)(b*SS)*HEADS + h)*DHH + tid;
    float acc = 0.f;
    for (int s2 = 0; s2 < SS; s2++) acc = fmaf(attn[s2], vp[(size_t)s2*D_IN], acc);
    o[(size_t)b*D_IN + h*DHH + tid] = acc;
  }
}

// ---- neuron update (trace->tp1->GLU->tp2->GLU), register-lean: 2 live h at a time ----
__global__ void k_neuron(const float* __restrict__ trace,
                         const float* __restrict__ tp1w, const float* __restrict__ tp1b,
                         const float* __restrict__ tp2w, const float* __restrict__ tp2b,
                         float* __restrict__ act, int t){
  int gid = blockIdx.x*256 + threadIdx.x;
  if (gid >= BB*D_MODEL) return;
  int b = gid >> 10, d = gid & 1023;
  const float* tr = trace + (size_t)b*(TRACE_SLOTS*D_MODEL) + (size_t)(t+1)*D_MODEL + d;
  float trv[MEMN];
#pragma unroll
  for (int m = 0; m < MEMN; m++) trv[m] = tr[(size_t)m*D_MODEL];
  float o0 = tp2b[d*2+0], o1 = tp2b[d*2+1];
#pragma unroll
  for (int j = 0; j < 16; j++){
    const float* wpj = tp1w + (size_t)j*1024 + d;
    const float* wpg = tp1w + (size_t)(j+16)*1024 + d;
    float hj = tp1b[d*32 + j];
    float hg = tp1b[d*32 + j + 16];
#pragma unroll
    for (int m = 0; m < MEMN; m++){
      float tv = trv[m];
      hj = fmaf(tv, wpj[(size_t)m*32*1024], hj);
      hg = fmaf(tv, wpg[(size_t)m*32*1024], hg);
    }
    float hgv = hj * sigmoidf_(hg);
    o0 = fmaf(hgv, tp2w[(size_t)(j*2+0)*1024 + d], o0);
    o1 = fmaf(hgv, tp2w[(size_t)(j*2+1)*1024 + d], o1);
  }
  act[gid] = o0 * sigmoidf_(o1);
}

// ---------------- sync accumulators ----------------
__global__ void k_syncA(const float* __restrict__ act, const float* __restrict__ rv,
                        const int2* __restrict__ pairs, float* __restrict__ aa,
                        float* __restrict__ syncv, int t){
  int p = blockIdx.x*256 + threadIdx.x;
  if (p >= SA_SZ) return;
  int b = blockIdx.y;
  int2 ij = pairs[p];
  const float* ab = act + (size_t)b*D_MODEL + (D_MODEL - N_SA);
  float r = rv[p];
  size_t idx = (size_t)b*SA_SZ + p;
  float a = fmaf(r, aa[idx], ab[ij.x]*ab[ij.y]);
  aa[idx] = a;
  float bb = 0.f;
  for (int i = 0; i <= t; i++) bb = fmaf(r, bb, 1.f);
  syncv[idx] = a / sqrtf(bb);
}

__global__ void k_syncO(const float* __restrict__ act, const float* __restrict__ rv,
                        const int2* __restrict__ pairs, float* __restrict__ ao,
                        half_t* __restrict__ syncv, int t){
  int p = blockIdx.x*256 + threadIdx.x;
  if (p >= SO_SZ) return;
  int b = blockIdx.y;
  int2 ij = pairs[p];
  const float* ab = act + (size_t)b*D_MODEL;
  float r = rv[p];
  size_t idx = (size_t)b*SO_SZ + p;
  float a = fmaf(r, ao[idx], ab[ij.x]*ab[ij.y]);
  ao[idx] = a;
  float bb = 1.f;
  for (int i = 0; i <= t; i++) bb = fmaf(r, bb, 1.f);
  syncv[idx] = (half_t)(a / sqrtf(bb));
}

// ---------------- big GEMM via fp16 MFMA (fp32-W fallback path) ----------------
__global__ __launch_bounds__(256)
void k_bigemm2(const half_t* __restrict__ Ah, const float* __restrict__ W,
               float* __restrict__ part){
  __shared__ half_t As[2][128*64];
  __shared__ half_t Ws[2][64*66];
  const int tid = threadIdx.x;
  const int z = blockIdx.y;
  const int nb0 = blockIdx.x * BGN;
  const int l = tid & 63, wv = tid >> 6;
  const int mw = (wv >> 1) * 64, nw = (wv & 1) * 32;
  const int c = l & 15, g = l >> 4;
  const int k0 = z * BGKLEN;

  f32x4v acc[4][2];
#pragma unroll
  for (int i = 0; i < 4; i++)
#pragma unroll
    for (int j2 = 0; j2 < 2; j2++)
#pragma unroll
      for (int r = 0; r < 4; r++) acc[i][j2][r] = 0.f;

  auto stage = [&](int s, int buf){
    const int kv = min(64, BGKLEN - s*64);
#pragma unroll
    for (int it = 0; it < 4; it++){
      int ch = tid + it*256;
      int m = ch >> 3, kg = ch & 7, kl = kg*8;
      half8 v;
      if (kl < kv) v = *(const half8*)(Ah + (size_t)m*SO_SZ + k0 + s*64 + kl);
      else {
#pragma unroll
        for (int j = 0; j < 8; j++) v[j] = (half_t)0.f;
      }
      *(half8*)((char*)(&As[buf][0]) + swzA(ch*16)) = v;
    }
    {
      int k = tid >> 2, cs = (tid & 3) * 16;
      const float* wr = W + (size_t)(k0 + s*64 + k) * NCLS + nb0 + cs;
      char* dst = (char*)(&Ws[buf][0]) + (size_t)(k*66 + cs) * 2;
      bool kvalid = (k < kv);
#pragma unroll
      for (int q = 0; q < 4; q++){
        float x0 = 0.f, x1 = 0.f, x2 = 0.f, x3 = 0.f;
        int col = nb0 + cs + q*4;
        if (kvalid && col < NCLS){
          float4 wvv = *(const float4*)(wr + q*4);
          x0 = wvv.x; x1 = wvv.y; x2 = wvv.z; x3 = wvv.w;
        }
        union { half_t h[4]; unsigned int u[2]; } pk;
        pk.h[0] = (half_t)x0; pk.h[1] = (half_t)x1;
        pk.h[2] = (half_t)x2; pk.h[3] = (half_t)x3;
        *(unsigned int*)(dst + q*8)     = pk.u[0];
        *(unsigned int*)(dst + q*8 + 4) = pk.u[1];
      }
    }
  };

  stage(0, 0);
  __syncthreads();
  for (int s = 0; s < BGSTEPS; s++){
    int buf = s & 1;
    if (s + 1 < BGSTEPS) stage(s+1, buf^1);
#pragma unroll
    for (int h = 0; h < 2; h++){
      half8 a8[4];
#pragma unroll
      for (int mb = 0; mb < 4; mb++)
        a8[mb] = *(const half8*)((const char*)(&As[buf][0]) +
                   swzA(((mw + mb*16 + c)*64 + h*32 + g*8)*2));
#pragma unroll
      for (int nb = 0; nb < 2; nb++){
        half8 b8;
        const half_t* wp = &Ws[buf][(h*32 + g*8)*66 + nw + nb*16 + c];
#pragma unroll
        for (int j = 0; j < 8; j++) b8[j] = wp[j*66];
#pragma unroll
        for (int mb = 0; mb < 4; mb++)
          acc[mb][nb] = __builtin_amdgcn_mfma_f32_16x16x32_f16(a8[mb], b8, acc[mb][nb], 0, 0, 0);
      }
    }
    __syncthreads();
  }
  float* pz = part + (size_t)z * 128 * NPART;
#pragma unroll
  for (int mb = 0; mb < 4; mb++)
#pragma unroll
    for (int nb = 0; nb < 2; nb++){
      int m = mw + mb*16 + g*4;
      int n = nb0 + nw + nb*16 + c;
#pragma unroll
      for (int r = 0; r < 4; r++)
        pz[(size_t)(m + r) * NPART + n] = acc[mb][nb][r];
    }
}

// ---------------- big GEMM, fp16-W path (Wh pre-converted, padded [32896][1984]) ----------------
__global__ __launch_bounds__(256)
void k_bigemm2h(const half_t* __restrict__ Ah, const half_t* __restrict__ Wh,
                float* __restrict__ part){
  __shared__ half_t As[2][128*64];
  __shared__ half_t Ws[2][64*66];
  const int tid = threadIdx.x;
  const int z = blockIdx.y;
  const int nb0 = blockIdx.x * BGN;
  const int l = tid & 63, wv = tid >> 6;
  const int mw = (wv >> 1) * 64, nw = (wv & 1) * 32;
  const int c = l & 15, g = l >> 4;
  const int k0 = z * BGKLEN;

  f32x4v acc[4][2];
#pragma unroll
  for (int i = 0; i < 4; i++)
#pragma unroll
    for (int j2 = 0; j2 < 2; j2++)
#pragma unroll
      for (int r = 0; r < 4; r++) acc[i][j2][r] = 0.f;

  auto stage = [&](int s, int buf){
    const int kv = min(64, BGKLEN - s*64);
#pragma unroll
    for (int it = 0; it < 4; it++){
      int ch = tid + it*256;
      int m = ch >> 3, kg = ch & 7, kl = kg*8;
      half8 v;
      if (kl < kv) v = *(const half8*)(Ah + (size_t)m*SO_SZ + k0 + s*64 + kl);
      else {
#pragma unroll
        for (int j = 0; j < 8; j++) v[j] = (half_t)0.f;
      }
      *(half8*)((char*)(&As[buf][0]) + swzA(ch*16)) = v;
    }
    {
      int k = tid >> 2, cs = (tid & 3) * 16;
      const half_t* wr = Wh + (size_t)(k0 + s*64 + k) * WHLD + nb0 + cs;
      char* dst = (char*)(&Ws[buf][0]) + (size_t)(k*66 + cs) * 2;
      union { half8 v; unsigned int u[4]; } p0, p1;
      if (k < kv){ p0.v = *(const half8*)wr; p1.v = *(const half8*)(wr + 8); }
      else {
#pragma unroll
        for (int j = 0; j < 8; j++){ p0.v[j] = (half_t)0.f; p1.v[j] = (half_t)0.f; }
      }
#pragma unroll
      for (int q = 0; q < 4; q++){
        ((unsigned int*)dst)[q]        = p0.u[q];
        ((unsigned int*)(dst + 16))[q] = p1.u[q];
      }
    }
  };

  stage(0, 0);
  __syncthreads();
  for (int s = 0; s < BGSTEPS; s++){
    int buf = s & 1;
    if (s + 1 < BGSTEPS) stage(s+1, buf^1);
#pragma unroll
    for (int h = 0; h < 2; h++){
      half8 a8[4];
#pragma unroll
      for (int mb = 0; mb < 4; mb++)
        a8[mb] = *(const half8*)((const char*)(&As[buf][0]) +
                   swzA(((mw + mb*16 + c)*64 + h*32 + g*8)*2));
#pragma unroll
      for (int nb = 0; nb < 2; nb++){
        half8 b8;
        const half_t* wp = &Ws[buf][(h*32 + g*8)*66 + nw + nb*16 + c];
#pragma unroll
        for (int j = 0; j < 8; j++) b8[j] = wp[j*66];
#pragma unroll
        for (int mb = 0; mb < 4; mb++)
          acc[mb][nb] = __builtin_amdgcn_mfma_f32_16x16x32_f16(a8[mb], b8, acc[mb][nb], 0, 0, 0);
      }
    }
    __syncthreads();
  }
  float* pz = part + (size_t)z * 128 * NPART;
#pragma unroll
  for (int mb = 0; mb < 4; mb++)
#pragma unroll
    for (int nb = 0; nb < 2; nb++){
      int m = mw + mb*16 + g*4;
      int n = nb0 + nw + nb*16 + c;
#pragma unroll
      for (int r = 0; r < 4; r++)
        pz[(size_t)(m + r) * NPART + n] = acc[mb][nb][r];
    }
}

// ---------------- combine partials + bias, write preds + certainties ----------------
__global__ void k_output(const float* __restrict__ part, const float* __restrict__ outb,
                         float* __restrict__ dout, int t){
  const int b = blockIdx.x, tid = threadIdx.x;
  __shared__ float pred[NCLS];
  __shared__ float red[256];
  float lmax = -1e30f;
  for (int c = tid; c < NCLS; c += 256){
    float s = outb[c];
    const float* pp = part + (size_t)b*NPART + c;
#pragma unroll
    for (int z = 0; z < BGKS; z++) s += pp[(size_t)z*128*NPART];
    pred[c] = s;
    dout[((size_t)b*NCLS + c)*NITER + t] = s;
    lmax = fmaxf(lmax, s);
  }
  red[tid] = lmax; __syncthreads();
  for (int s2 = 128; s2 > 0; s2 >>= 1){ if (tid < s2) red[tid] = fmaxf(red[tid], red[tid+s2]); __syncthreads(); }
  float m = red[0]; __syncthreads();
  float se = 0.f;
  for (int c = tid; c < NCLS; c += 256) se += expf(pred[c]-m);
  float Z = bsum256(se, red);
  float logZ = m + logf(Z);
  float ent = 0.f;
  for (int c = tid; c < NCLS; c += 256){ float lp = pred[c]-logZ; ent += expf(lp)*lp; }
  float E = bsum256(ent, red);
  if (tid == 0){
    float ne = -E * (1.f/logf((float)NCLS));
    float* cp = dout + (size_t)BB*NCLS*NITER + (size_t)b*2*NITER + t;
    cp[0]     = ne;
    cp[NITER] = 1.f - ne;
  }
}

// ---------------- launch ----------------
extern "C" void kernel_launch(void* const* d_in, const int* in_sizes, int n_in,
                              void* d_out, int out_size, void* d_ws, size_t ws_size,
                              hipStream_t stream){
  const int*   x           = (const int*)  d_in[0];
  const float* emb         = (const float*)d_in[1];
  const float* kv_w        = (const float*)d_in[2];
  const float* kv_b        = (const float*)d_in[3];
  const float* kv_ln_g     = (const float*)d_in[4];
  const float* kv_ln_b     = (const float*)d_in[5];
  const float* q_w         = (const float*)d_in[6];
  const float* q_b         = (const float*)d_in[7];
  const float* in_proj_w   = (const float*)d_in[8];
  const float* in_proj_b   = (const float*)d_in[9];
  const float* out_proj_w  = (const float*)d_in[10];
  const float* out_proj_b  = (const float*)d_in[11];
  const float* syn_w       = (const float*)d_in[12];
  const float* syn_b       = (const float*)d_in[13];
  const float* syn_ln_g    = (const float*)d_in[14];
  const float* syn_ln_b    = (const float*)d_in[15];
  const float* tp1_w       = (const float*)d_in[16];
  const float* tp1_b       = (const float*)d_in[17];
  const float* tp2_w       = (const float*)d_in[18];
  const float* tp2_b       = (const float*)d_in[19];
  const float* start_act   = (const float*)d_in[20];
  const float* start_trace = (const float*)d_in[21];
  const float* decay_action= (const float*)d_in[22];
  const float* decay_out   = (const float*)d_in[23];
  const float* out_w       = (const float*)d_in[24];
  const float* out_b       = (const float*)d_in[25];
  float* dout = (float*)d_out;

  // ---- workspace layout (float units, 16B-aligned allocs) ----
  float* w = (float*)d_ws;
  size_t off = 0;
  auto alloc = [&](size_t n){ n = (n + 3) & ~(size_t)3; float* p = w + off; off += n; return p; };
  float* region0 = alloc((size_t)BGKS*128*NPART);    // embx (setup) / synpart+bigemm partials (iter, disjoint lifetimes)
  float* region1 = alloc((size_t)ROWS*D_IN);         // kv (setup) / a_o (iter)
  float* Kmat    = alloc((size_t)ROWS*D_IN);
  float* Vmat    = alloc((size_t)ROWS*D_IN);
  float* trace   = alloc((size_t)BB*TRACE_SLOTS*D_MODEL);
  half_t* sync_oh= (half_t*)alloc((size_t)BB*SO_SZ/2);
  float* a_a     = alloc((size_t)BB*SA_SZ);
  float* sync_a  = alloc((size_t)BB*SA_SZ);
  float* act     = alloc((size_t)BB*D_MODEL);
  float* qpart   = alloc((size_t)4*BB*D_IN);
  float* obuf    = alloc((size_t)BB*D_IN);
  float* qfw     = alloc((size_t)SA_SZ*D_IN);        // q_w @ Wq  (2080x512)
  float* Wf2     = alloc((size_t)D_IN*2048);         // out_proj @ syn_w_top (512x2048)
  float* bqf     = alloc(D_IN);
  float* bias2   = alloc(2048);
  float* r_a     = alloc(SA_SZ);
  float* r_o     = alloc(SO_SZ);
  int2*  pairsA  = (int2*)alloc(2*SA_SZ);
  int2*  pairsO  = (int2*)alloc(2*SO_SZ);
  half_t* Wh     = (half_t*)alloc(((size_t)SO_SZ*WHLD)/2);   // optional fp16 out_w
  const bool use_fp16w = (off * sizeof(float) <= ws_size);

  float* embx    = region0;
  float* part    = region0;   // bigemm partials: live bigemm->output
  float* synpart = region0;   // syn partials: live gemm2srcZ->glu_ln (disjoint from part within an iter)
  float* kvbuf = region1;
  float* a_o   = region1;

  dim3 blk(256);

  // ---- setup ----
  k_embed<<<(ROWS*TED+255)/256, blk, 0, stream>>>(x, emb, embx);
  k_gemm<8><<<dim3(2, ROWS/8), blk, 0, stream>>>(embx, TED, kv_w, D_IN, 0, 0, kv_b, kvbuf, D_IN, D_IN, TED);
  k_ln<<<ROWS, blk, 0, stream>>>(kvbuf, kv_ln_g, kv_ln_b, kvbuf, D_IN);
  k_gemm<8><<<dim3(2, ROWS/8), blk, 0, stream>>>(kvbuf, D_IN, in_proj_w, 1536, 0, 512,  in_proj_b+512,  Kmat, D_IN, D_IN, D_IN);
  k_gemm<8><<<dim3(2, ROWS/8), blk, 0, stream>>>(kvbuf, D_IN, in_proj_w, 1536, 0, 1024, in_proj_b+1024, Vmat, D_IN, D_IN, D_IN);
  // fused weights: qfw = q_w @ Wq ; Wf2 = out_proj_w @ syn_w[:512]
  k_gemm<8><<<dim3(2, SA_SZ/8), blk, 0, stream>>>(q_w, D_IN, in_proj_w, 1536, 0, 0, nullptr, qfw, D_IN, D_IN, D_IN);
  k_gemm<8><<<dim3(8, D_IN/8), blk, 0, stream>>>(out_proj_w, D_IN, syn_w, 2048, 0, 0, nullptr, Wf2, 2048, 2048, D_IN);
  k_colsum<<<2, blk, 0, stream>>>(q_b, in_proj_w, 1536, in_proj_b, bqf, D_IN, D_IN);
  k_colsum<<<8, blk, 0, stream>>>(out_proj_b, syn_w, 2048, syn_b, bias2, 2048, D_IN);
  if (use_fp16w)
    k_convw<<<(SO_SZ*(WHLD/8)+255)/256, blk, 0, stream>>>(out_w, Wh);
  k_init_pairs<<<(SA_SZ+255)/256, blk, 0, stream>>>(N_SA, SA_SZ, decay_action, pairsA, r_a);
  k_init_pairs<<<(SO_SZ+255)/256, blk, 0, stream>>>(N_SO, SO_SZ, decay_out,    pairsO, r_o);
  k_init_act<<<(BB*D_MODEL+255)/256, blk, 0, stream>>>(start_act, act);
  k_zero<<<(BB*SA_SZ+255)/256, blk, 0, stream>>>(a_a, BB*SA_SZ);
  k_init_trace<<<(BB*MEMN*D_MODEL+255)/256, blk, 0, stream>>>(start_trace, trace);
  k_init_ao<<<dim3((SO_SZ+255)/256, BB), blk, 0, stream>>>(start_act, pairsO, a_o);

  // ---- 16 recurrent iterations ----
  for (int t = 0; t < NITER; t++){
    k_syncA<<<dim3((SA_SZ+255)/256, BB), blk, 0, stream>>>(act, r_a, pairsA, a_a, sync_a, t);
    k_gemmq<<<dim3(2, 32, 4), blk, 0, stream>>>(sync_a, qfw, qpart);
    k_attn<<<BB*HEADS, 128, 0, stream>>>(qpart, bqf, Kmat, Vmat, obuf);
    k_gemm2srcZ<<<dim3(8, 16, SYNZ), blk, 0, stream>>>(obuf, act, Wf2, syn_w, synpart);
    k_glu_ln<<<BB, blk, 0, stream>>>(synpart, bias2, syn_ln_g, syn_ln_b, trace + (size_t)(MEMN+t)*D_MODEL);
    k_neuron<<<(BB*D_MODEL+255)/256, blk, 0, stream>>>(trace, tp1_w, tp1_b, tp2_w, tp2_b, act, t);
    k_syncO<<<dim3((SO_SZ+255)/256, BB), blk, 0, stream>>>(act, r_o, pairsO, a_o, sync_oh, t);
    if (use_fp16w)
      k_bigemm2h<<<dim3(31, BGKS), blk, 0, stream>>>(sync_oh, Wh, part);
    else
      k_bigemm2<<<dim3(31, BGKS), blk, 0, stream>>>(sync_oh, out_w, part);
    k_output<<<BB, blk, 0, stream>>>(part, out_b, dout, t);
  }
}

// Round 7
// 3578.299 us; speedup vs baseline: 9.9111x; 1.0690x over previous
//
#include <hip/hip_runtime.h>
#include <math.h>

#define BB 128
#define SS 72
#define NITER 16
#define D_IN 512
#define D_MODEL 1024
#define MEMN 25
#define HEADS 8
#define DHH 64
#define N_SO 256
#define N_SA 64
#define SA_SZ 2080
#define SO_SZ 32896
#define NCLS 1968
#define TED 128
#define VOCAB 32
#define ROWS (BB*SS)
#define TRACE_SLOTS (MEMN + NITER)   /* 41 */

/* big-GEMM (sync_o @ out_w) tiling */
#define BGN 64          /* cols per block */
#define BGKS 16         /* k splits */
#define BGKLEN 2056     /* 32896/16 */
#define BGSTEPS 33      /* ceil(2056/64); last step has 8 valid k */
#define NPART 1984      /* 31*64 padded col count */
#define WHLD 1984       /* fp16 out_w padded row length */
#define SYNZ 6          /* K-splits for syn GEMM (1536/256) */

typedef _Float16 half_t;
typedef _Float16 half8 __attribute__((ext_vector_type(8)));
typedef float f32x4v __attribute__((ext_vector_type(4)));

__device__ __forceinline__ float sigmoidf_(float x){ return 1.f/(1.f+expf(-x)); }

__device__ __forceinline__ float bsum256(float v, float* red){
  int tid = threadIdx.x; red[tid] = v; __syncthreads();
#pragma unroll
  for (int s = 128; s > 0; s >>= 1){ if (tid < s) red[tid] += red[tid+s]; __syncthreads(); }
  float r = red[0]; __syncthreads(); return r;
}

__device__ __forceinline__ long triu_off(int n, int i){
  return (long)i*n - ((long)i*(i-1))/2;
}

__device__ __forceinline__ int swzA(int b){ return b ^ (((b>>9)&1)<<5); }

// ---------------- setup kernels ----------------
__global__ void k_conv(const float* __restrict__ src, half_t* __restrict__ dst, int n){
  int gid = blockIdx.x*256 + threadIdx.x;
  if (gid < n) dst[gid] = (half_t)src[gid];
}

// dst[r][c] = src[r*ldsrc + col0 + c]  (fp32 -> fp16)
__global__ void k_convslice(const float* __restrict__ src, int ldsrc, int col0,
                            half_t* __restrict__ dst, int rows, int cols){
  int gid = blockIdx.x*256 + threadIdx.x;
  if (gid >= rows*cols) return;
  int r = gid / cols, c = gid % cols;
  dst[gid] = (half_t)src[(size_t)r*ldsrc + col0 + c];
}

__global__ void k_embed_h(const int* __restrict__ x, const half_t* __restrict__ embh,
                          half_t* __restrict__ out){
  int gid = blockIdx.x*256 + threadIdx.x;           // half8 chunks: 9216*16
  if (gid >= ROWS*(TED/8)) return;
  int row = gid >> 4, c0 = (gid & 15)*8;
  *(half8*)(out + (size_t)row*TED + c0) = *(const half8*)(embh + (size_t)x[row]*TED + c0);
}

__global__ void k_init_pairs(int n, int npairs, const float* __restrict__ decay,
                             int2* __restrict__ pairs, float* __restrict__ rv){
  int p = blockIdx.x*256 + threadIdx.x;
  if (p >= npairs) return;
  double nn = (double)n;
  double disc = (2.0*nn+1.0)*(2.0*nn+1.0) - 8.0*(double)p;
  int i = (int)floor(((2.0*nn+1.0) - sqrt(disc))*0.5);
  if (i < 0) i = 0; if (i > n-1) i = n-1;
  while (i+1 < n && triu_off(n, i+1) <= (long)p) i++;
  while (i > 0 && triu_off(n, i) > (long)p) i--;
  int j = i + (int)((long)p - triu_off(n, i));
  pairs[p] = make_int2(i, j);
  float dc = decay[p]; dc = fminf(fmaxf(dc, 0.f), 15.f);
  rv[p] = expf(-dc);
}

__global__ void k_init_act(const float* __restrict__ sa, float* __restrict__ act){
  int gid = blockIdx.x*256 + threadIdx.x;
  if (gid >= BB*D_MODEL) return;
  act[gid] = sa[gid & 1023];
}

__global__ void k_zero(float* __restrict__ p, int n){
  int gid = blockIdx.x*256 + threadIdx.x;
  if (gid < n) p[gid] = 0.f;
}

__global__ void k_init_trace(const float* __restrict__ st, float* __restrict__ trace){
  int gid = blockIdx.x*256 + threadIdx.x;
  if (gid >= BB*MEMN*D_MODEL) return;
  int d = gid & 1023;
  int m = (gid >> 10) % MEMN;
  int b = (gid >> 10) / MEMN;
  trace[(size_t)b*TRACE_SLOTS*D_MODEL + (size_t)m*D_MODEL + d] = st[d*MEMN + m];
}

__global__ void k_init_ao(const float* __restrict__ sa, const int2* __restrict__ pairs,
                          float* __restrict__ ao){
  int p = blockIdx.x*256 + threadIdx.x;
  if (p >= SO_SZ) return;
  int b = blockIdx.y;
  int2 ij = pairs[p];
  ao[(size_t)b*SO_SZ + p] = sa[ij.x]*sa[ij.y];
}

// out_w (fp32, [32896][1968]) -> Wh (fp16, [32896][1984], zero-padded cols)
__global__ void k_convw(const float* __restrict__ W, half_t* __restrict__ Wh){
  int gid = blockIdx.x*256 + threadIdx.x;            // one half8 chunk
  if (gid >= SO_SZ*(WHLD/8)) return;
  int row = gid / (WHLD/8), c0 = (gid % (WHLD/8))*8;
  half8 v;
#pragma unroll
  for (int j = 0; j < 8; j++){
    int c = c0 + j;
    v[j] = (c < NCLS) ? (half_t)W[(size_t)row*NCLS + c] : (half_t)0.f;
  }
  *(half8*)(Wh + (size_t)row*WHLD + c0) = v;
}

// out[col] = sum_k vec[k]*W[k*ldw+col] + (addb?addb[col]:0)
__global__ void k_colsum(const float* __restrict__ vec, const float* __restrict__ W,
                         int ldw, const float* __restrict__ addb,
                         float* __restrict__ out, int N, int K){
  int col = blockIdx.x*256 + threadIdx.x;
  if (col >= N) return;
  float s = addb ? addb[col] : 0.f;
  for (int k = 0; k < K; k++) s = fmaf(vec[k], W[(size_t)k*ldw + col], s);
  out[col] = s;
}

// ---- generic fp32 GEMM:  C[M,N] = A[M,K] @ W[wrow0:,wcol0:] (+bias). REQUIRES K % 32 == 0 ----
template<int MB>
__global__ void k_gemm(const float* __restrict__ A, int lda,
                       const float* __restrict__ W, int ldw, int wrow0, int wcol0,
                       const float* __restrict__ bias,
                       float* __restrict__ C, int ldc, int N, int K){
  constexpr int KC = 32;
  const int tid = threadIdx.x;
  const int col = blockIdx.x*256 + tid;
  const int row0 = blockIdx.y*MB;
  __shared__ float As[MB][KC];
  float acc[MB];
#pragma unroll
  for (int r = 0; r < MB; r++) acc[r] = 0.f;
  for (int kk = 0; kk < K; kk += KC){
    __syncthreads();
    for (int idx = tid; idx < MB*KC; idx += 256){
      int r = idx / KC, k = idx % KC;
      As[r][k] = A[(size_t)(row0+r)*lda + kk + k];
    }
    __syncthreads();
#pragma unroll
    for (int k = 0; k < KC; k++){
      float w = W[(size_t)(wrow0+kk+k)*ldw + wcol0 + col];
#pragma unroll
      for (int r = 0; r < MB; r++) acc[r] = fmaf(As[r][k], w, acc[r]);
    }
  }
#pragma unroll
  for (int r = 0; r < MB; r++){
    size_t o = (size_t)(row0+r)*ldc + col;
    C[o] = acc[r] + (bias ? bias[col] : 0.f);
  }
}

// ---- fp16 MFMA projection GEMM: C[M,512] = Ah[M][ldah] @ Wh16[ldah][512] + bias ----
// 128x64 tiles, ksteps = ldah/64 (no tail). Clone of k_bigemm2h's verified structure.
__global__ __launch_bounds__(256)
void k_pgemm(const half_t* __restrict__ Ah, int ldah,
             const half_t* __restrict__ Wh16, const float* __restrict__ bias,
             float* __restrict__ C, int ksteps){
  __shared__ half_t As[2][128*64];
  __shared__ half_t Ws[2][64*66];
  const int tid = threadIdx.x;
  const int nb0 = blockIdx.x * 64;
  const int row0 = blockIdx.y * 128;
  const int l = tid & 63, wv = tid >> 6;
  const int mw = (wv >> 1) * 64, nw = (wv & 1) * 32;
  const int c = l & 15, g = l >> 4;

  f32x4v acc[4][2];
#pragma unroll
  for (int i = 0; i < 4; i++)
#pragma unroll
    for (int j2 = 0; j2 < 2; j2++)
#pragma unroll
      for (int r = 0; r < 4; r++) acc[i][j2][r] = 0.f;

  auto stage = [&](int s, int buf){
#pragma unroll
    for (int it = 0; it < 4; it++){
      int ch = tid + it*256;
      int m = ch >> 3, kl = (ch & 7)*8;
      half8 v = *(const half8*)(Ah + (size_t)(row0+m)*ldah + s*64 + kl);
      *(half8*)((char*)(&As[buf][0]) + swzA(ch*16)) = v;
    }
    {
      int k = tid >> 2, cs = (tid & 3) * 16;
      const half_t* wr = Wh16 + (size_t)(s*64 + k) * D_IN + nb0 + cs;
      char* dst = (char*)(&Ws[buf][0]) + (size_t)(k*66 + cs) * 2;
      union { half8 v; unsigned int u[4]; } p0, p1;
      p0.v = *(const half8*)wr; p1.v = *(const half8*)(wr + 8);
#pragma unroll
      for (int q = 0; q < 4; q++){
        ((unsigned int*)dst)[q]        = p0.u[q];
        ((unsigned int*)(dst + 16))[q] = p1.u[q];
      }
    }
  };

  stage(0, 0);
  __syncthreads();
  for (int s = 0; s < ksteps; s++){
    int buf = s & 1;
    if (s + 1 < ksteps) stage(s+1, buf^1);
#pragma unroll
    for (int h = 0; h < 2; h++){
      half8 a8[4];
#pragma unroll
      for (int mb = 0; mb < 4; mb++)
        a8[mb] = *(const half8*)((const char*)(&As[buf][0]) +
                   swzA(((mw + mb*16 + c)*64 + h*32 + g*8)*2));
#pragma unroll
      for (int nb = 0; nb < 2; nb++){
        half8 b8;
        const half_t* wp = &Ws[buf][(h*32 + g*8)*66 + nw + nb*16 + c];
#pragma unroll
        for (int j = 0; j < 8; j++) b8[j] = wp[j*66];
#pragma unroll
        for (int mb = 0; mb < 4; mb++)
          acc[mb][nb] = __builtin_amdgcn_mfma_f32_16x16x32_f16(a8[mb], b8, acc[mb][nb], 0, 0, 0);
      }
    }
    __syncthreads();
  }
#pragma unroll
  for (int mb = 0; mb < 4; mb++)
#pragma unroll
    for (int nb = 0; nb < 2; nb++){
      int m = mw + mb*16 + g*4;
      int n = nb0 + nw + nb*16 + c;
      float bv = bias[n];
#pragma unroll
      for (int r = 0; r < 4; r++)
        C[(size_t)(row0 + m + r) * D_IN + n] = acc[mb][nb][r] + bv;
    }
}

// ---- q-fused GEMM, 4-way K-split: qpart[z] = sync_a @ qfw (k-range z) ----
__global__ void k_gemmq(const float* __restrict__ A, const float* __restrict__ W,
                        float* __restrict__ qpart){
  constexpr int KC = 32;
  const int tid = threadIdx.x;
  const int col = blockIdx.x*256 + tid;        // N=512, grid.x=2
  const int row0 = blockIdx.y*4;               // M=128, grid.y=32
  const int z = blockIdx.z;                    // 4 splits
  const int kstart = z*544;
  const int kend = min(SA_SZ, kstart + 544);   // 544,544,544,448 (all %32==0)
  __shared__ float As[4][KC];
  float acc[4] = {0.f,0.f,0.f,0.f};
  for (int kk = kstart; kk < kend; kk += KC){
    __syncthreads();
    for (int idx = tid; idx < 4*KC; idx += 256){
      int r = idx / KC, k = idx % KC;
      As[r][k] = A[(size_t)(row0+r)*SA_SZ + kk + k];
    }
    __syncthreads();
#pragma unroll
    for (int k = 0; k < KC; k++){
      float w = W[(size_t)(kk+k)*D_IN + col];
#pragma unroll
      for (int r = 0; r < 4; r++) acc[r] = fmaf(As[r][k], w, acc[r]);
    }
  }
#pragma unroll
  for (int r = 0; r < 4; r++)
    qpart[(size_t)z*BB*D_IN + (size_t)(row0+r)*D_IN + col] = acc[r];
}

// ---- fused syn GEMM, 6-way K-split: synpart[z] = [obuf|act] @ [Wf2|syn_w] (k-chunk z of 256) ----
__global__ void k_gemm2srcZ(const float* __restrict__ A1, const float* __restrict__ A2,
                            const float* __restrict__ W1, const float* __restrict__ W2,
                            float* __restrict__ outp){
  constexpr int MB = 8, KC = 32;
  const int tid = threadIdx.x;
  const int col = blockIdx.x*256 + tid;        // N=2048, grid.x=8
  const int row0 = blockIdx.y*MB;              // M=128, grid.y=16
  const int z = blockIdx.z;                    // 6 chunks of 256
  __shared__ float As[MB][KC];
  float acc[MB];
#pragma unroll
  for (int r = 0; r < MB; r++) acc[r] = 0.f;
  for (int kk = z*256; kk < z*256 + 256; kk += KC){
    __syncthreads();
    for (int idx = tid; idx < MB*KC; idx += 256){
      int r = idx / KC, k = idx % KC;
      int kg = kk + k;
      As[r][k] = (kg < D_IN) ? A1[(size_t)(row0+r)*D_IN + kg]
                             : A2[(size_t)(row0+r)*D_MODEL + kg - D_IN];
    }
    __syncthreads();
    const float* Wp = (kk < D_IN) ? W1 : W2;
#pragma unroll
    for (int k = 0; k < KC; k++){
      float w = Wp[(size_t)(kk+k)*2048 + col];
#pragma unroll
      for (int r = 0; r < MB; r++) acc[r] = fmaf(As[r][k], w, acc[r]);
    }
  }
#pragma unroll
  for (int r = 0; r < MB; r++)
    outp[(size_t)z*BB*2048 + (size_t)(row0+r)*2048 + col] = acc[r];
}

// ---------------- LayerNorm (block per row), fp32 in -> fp16 out ----------------
__global__ void k_ln_h(const float* __restrict__ X, const float* __restrict__ g,
                       const float* __restrict__ bta, half_t* __restrict__ Y, int D){
  const int row = blockIdx.x, tid = threadIdx.x;
  __shared__ float red[256];
  const float* xr = X + (size_t)row*D;
  float s = 0.f;
  for (int c = tid; c < D; c += 256) s += xr[c];
  float mean = bsum256(s, red) / (float)D;
  float s2 = 0.f;
  for (int c = tid; c < D; c += 256){ float d = xr[c]-mean; s2 += d*d; }
  float var = bsum256(s2, red) / (float)D;
  float inv = 1.f / sqrtf(var + 1e-5f);
  half_t* yr = Y + (size_t)row*D;
  for (int c = tid; c < D; c += 256) yr[c] = (half_t)((xr[c]-mean)*inv*g[c] + bta[c]);
}

// ---- sum 6 synpart + bias2 -> GLU -> LN -> trace slot ----
__global__ void k_glu_ln(const float* __restrict__ synpart, const float* __restrict__ bias2,
                         const float* __restrict__ g, const float* __restrict__ bta,
                         float* __restrict__ traceSlot){
  const int b = blockIdx.x, tid = threadIdx.x;
  __shared__ float vals[D_MODEL];
  __shared__ float red[256];
  for (int c = tid; c < 1024; c += 256){
    float a = bias2[c], gg = bias2[c+1024];
#pragma unroll
    for (int z = 0; z < SYNZ; z++){
      const float* sp = synpart + (size_t)z*BB*2048 + (size_t)b*2048;
      a  += sp[c];
      gg += sp[c+1024];
    }
    vals[c] = a * sigmoidf_(gg);
  }
  __syncthreads();
  float s = 0.f;
  for (int c = tid; c < 1024; c += 256) s += vals[c];
  float mean = bsum256(s, red) * (1.f/1024.f);
  float s2 = 0.f;
  for (int c = tid; c < 1024; c += 256){ float d = vals[c]-mean; s2 += d*d; }
  float var = bsum256(s2, red) * (1.f/1024.f);
  float inv = 1.f / sqrtf(var + 1e-5f);
  float* out = traceSlot + (size_t)b*(TRACE_SLOTS*D_MODEL);
  for (int c = tid; c < 1024; c += 256) out[c] = (vals[c]-mean)*inv*g[c] + bta[c];
}

// ---------------- attention: block per (b,h); q = sum of 4 qpart + bqf ----------------
__global__ void k_attn(const float* __restrict__ qpart, const float* __restrict__ bqf,
                       const float* __restrict__ Km, const float* __restrict__ Vm,
                       float* __restrict__ o){
  const int bh = blockIdx.x, b = bh >> 3, h = bh & 7;
  const int tid = threadIdx.x;
  __shared__ float qs[DHH];
  __shared__ float attn[SS];
  __shared__ float red[128];
  if (tid < DHH){
    int d = h*DHH + tid;
    float qv = bqf[d];
#pragma unroll
    for (int z = 0; z < 4; z++) qv += qpart[(size_t)z*BB*D_IN + (size_t)b*D_IN + d];
    qs[tid] = qv;
  }
  __syncthreads();
  float sc = -1e30f;
  if (tid < SS){
    const float* kp = Km + ((size_t)(b*SS+tid)*HEADS + h)*DHH;
    float d = 0.f;
#pragma unroll
    for (int i = 0; i < DHH; i++) d = fmaf(qs[i], kp[i], d);
    sc = d * 0.125f;
  }
  red[tid] = sc; __syncthreads();
  for (int s2 = 64; s2 > 0; s2 >>= 1){ if (tid < s2) red[tid] = fmaxf(red[tid], red[tid+s2]); __syncthreads(); }
  float m = red[0]; __syncthreads();
  float e = (tid < SS) ? expf(sc - m) : 0.f;
  red[tid] = e; __syncthreads();
  for (int s2 = 64; s2 > 0; s2 >>= 1){ if (tid < s2) red[tid] += red[tid+s2]; __syncthreads(); }
  float inv = 1.f / red[0]; __syncthreads();
  if (tid < SS) attn[tid] = e * inv;
  __syncthreads();
  if (tid < DHH){
    const float* vp = Vm + ((size_t)(b*SS)*HEADS + h)*DHH + tid;
    float acc = 0.f;
    for (int s2 = 0; s2 < SS; s2++) acc = fmaf(attn[s2], vp[(size_t)s2*D_IN], acc);
    o[(size_t)b*D_IN + h*DHH + tid] = acc;
  }
}

// ---- neuron update (trace->tp1->GLU->tp2->GLU), register-lean: 2 live h at a time ----
__global__ void k_neuron(const float* __restrict__ trace,
                         const float* __restrict__ tp1w, const float* __restrict__ tp1b,
                         const float* __restrict__ tp2w, const float* __restrict__ tp2b,
                         float* __restrict__ act, int t){
  int gid = blockIdx.x*256 + threadIdx.x;
  if (gid >= BB*D_MODEL) return;
  int b = gid >> 10, d = gid & 1023;
  const float* tr = trace + (size_t)b*(TRACE_SLOTS*D_MODEL) + (size_t)(t+1)*D_MODEL + d;
  float trv[MEMN];
#pragma unroll
  for (int m = 0; m < MEMN; m++) trv[m] = tr[(size_t)m*D_MODEL];
  float o0 = tp2b[d*2+0], o1 = tp2b[d*2+1];
#pragma unroll
  for (int j = 0; j < 16; j++){
    const float* wpj = tp1w + (size_t)j*1024 + d;
    const float* wpg = tp1w + (size_t)(j+16)*1024 + d;
    float hj = tp1b[d*32 + j];
    float hg = tp1b[d*32 + j + 16];
#pragma unroll
    for (int m = 0; m < MEMN; m++){
      float tv = trv[m];
      hj = fmaf(tv, wpj[(size_t)m*32*1024], hj);
      hg = fmaf(tv, wpg[(size_t)m*32*1024], hg);
    }
    float hgv = hj * sigmoidf_(hg);
    o0 = fmaf(hgv, tp2w[(size_t)(j*2+0)*1024 + d], o0);
    o1 = fmaf(hgv, tp2w[(size_t)(j*2+1)*1024 + d], o1);
  }
  act[gid] = o0 * sigmoidf_(o1);
}

// ---------------- sync accumulators ----------------
__global__ void k_syncA(const float* __restrict__ act, const float* __restrict__ rv,
                        const int2* __restrict__ pairs, float* __restrict__ aa,
                        float* __restrict__ syncv, int t){
  int p = blockIdx.x*256 + threadIdx.x;
  if (p >= SA_SZ) return;
  int b = blockIdx.y;
  int2 ij = pairs[p];
  const float* ab = act + (size_t)b*D_MODEL + (D_MODEL - N_SA);
  float r = rv[p];
  size_t idx = (size_t)b*SA_SZ + p;
  float a = fmaf(r, aa[idx], ab[ij.x]*ab[ij.y]);
  aa[idx] = a;
  float bb = 0.f;
  for (int i = 0; i <= t; i++) bb = fmaf(r, bb, 1.f);
  syncv[idx] = a / sqrtf(bb);
}

__global__ void k_syncO(const float* __restrict__ act, const float* __restrict__ rv,
                        const int2* __restrict__ pairs, float* __restrict__ ao,
                        half_t* __restrict__ syncv, int t){
  int p = blockIdx.x*256 + threadIdx.x;
  if (p >= SO_SZ) return;
  int b = blockIdx.y;
  int2 ij = pairs[p];
  const float* ab = act + (size_t)b*D_MODEL;
  float r = rv[p];
  size_t idx = (size_t)b*SO_SZ + p;
  float a = fmaf(r, ao[idx], ab[ij.x]*ab[ij.y]);
  ao[idx] = a;
  float bb = 1.f;
  for (int i = 0; i <= t; i++) bb = fmaf(r, bb, 1.f);
  syncv[idx] = (half_t)(a / sqrtf(bb));
}

// ---------------- big GEMM, fp16-W path (Wh pre-converted, padded [32896][1984]) ----------------
__global__ __launch_bounds__(256)
void k_bigemm2h(const half_t* __restrict__ Ah, const half_t* __restrict__ Wh,
                float* __restrict__ part){
  __shared__ half_t As[2][128*64];
  __shared__ half_t Ws[2][64*66];
  const int tid = threadIdx.x;
  const int z = blockIdx.y;
  const int nb0 = blockIdx.x * BGN;
  const int l = tid & 63, wv = tid >> 6;
  const int mw = (wv >> 1) * 64, nw = (wv & 1) * 32;
  const int c = l & 15, g = l >> 4;
  const int k0 = z * BGKLEN;

  f32x4v acc[4][2];
#pragma unroll
  for (int i = 0; i < 4; i++)
#pragma unroll
    for (int j2 = 0; j2 < 2; j2++)
#pragma unroll
      for (int r = 0; r < 4; r++) acc[i][j2][r] = 0.f;

  auto stage = [&](int s, int buf){
    const int kv = min(64, BGKLEN - s*64);
#pragma unroll
    for (int it = 0; it < 4; it++){
      int ch = tid + it*256;
      int m = ch >> 3, kg = ch & 7, kl = kg*8;
      half8 v;
      if (kl < kv) v = *(const half8*)(Ah + (size_t)m*SO_SZ + k0 + s*64 + kl);
      else {
#pragma unroll
        for (int j = 0; j < 8; j++) v[j] = (half_t)0.f;
      }
      *(half8*)((char*)(&As[buf][0]) + swzA(ch*16)) = v;
    }
    {
      int k = tid >> 2, cs = (tid & 3) * 16;
      const half_t* wr = Wh + (size_t)(k0 + s*64 + k) * WHLD + nb0 + cs;
      char* dst = (char*)(&Ws[buf][0]) + (size_t)(k*66 + cs) * 2;
      union { half8 v; unsigned int u[4]; } p0, p1;
      if (k < kv){ p0.v = *(const half8*)wr; p1.v = *(const half8*)(wr + 8); }
      else {
#pragma unroll
        for (int j = 0; j < 8; j++){ p0.v[j] = (half_t)0.f; p1.v[j] = (half_t)0.f; }
      }
#pragma unroll
      for (int q = 0; q < 4; q++){
        ((unsigned int*)dst)[q]        = p0.u[q];
        ((unsigned int*)(dst + 16))[q] = p1.u[q];
      }
    }
  };

  stage(0, 0);
  __syncthreads();
  for (int s = 0; s < BGSTEPS; s++){
    int buf = s & 1;
    if (s + 1 < BGSTEPS) stage(s+1, buf^1);
#pragma unroll
    for (int h = 0; h < 2; h++){
      half8 a8[4];
#pragma unroll
      for (int mb = 0; mb < 4; mb++)
        a8[mb] = *(const half8*)((const char*)(&As[buf][0]) +
                   swzA(((mw + mb*16 + c)*64 + h*32 + g*8)*2));
#pragma unroll
      for (int nb = 0; nb < 2; nb++){
        half8 b8;
        const half_t* wp = &Ws[buf][(h*32 + g*8)*66 + nw + nb*16 + c];
#pragma unroll
        for (int j = 0; j < 8; j++) b8[j] = wp[j*66];
#pragma unroll
        for (int mb = 0; mb < 4; mb++)
          acc[mb][nb] = __builtin_amdgcn_mfma_f32_16x16x32_f16(a8[mb], b8, acc[mb][nb], 0, 0, 0);
      }
    }
    __syncthreads();
  }
  float* pz = part + (size_t)z * 128 * NPART;
#pragma unroll
  for (int mb = 0; mb < 4; mb++)
#pragma unroll
    for (int nb = 0; nb < 2; nb++){
      int m = mw + mb*16 + g*4;
      int n = nb0 + nw + nb*16 + c;
#pragma unroll
      for (int r = 0; r < 4; r++)
        pz[(size_t)(m + r) * NPART + n] = acc[mb][nb][r];
    }
}

// ---------------- combine partials + bias, write preds + certainties ----------------
__global__ void k_output(const float* __restrict__ part, const float* __restrict__ outb,
                         float* __restrict__ dout, int t){
  const int b = blockIdx.x, tid = threadIdx.x;
  __shared__ float pred[NCLS];
  __shared__ float red[256];
  float lmax = -1e30f;
  for (int c = tid; c < NCLS; c += 256){
    float s = outb[c];
    const float* pp = part + (size_t)b*NPART + c;
#pragma unroll
    for (int z = 0; z < BGKS; z++) s += pp[(size_t)z*128*NPART];
    pred[c] = s;
    dout[((size_t)b*NCLS + c)*NITER + t] = s;
    lmax = fmaxf(lmax, s);
  }
  red[tid] = lmax; __syncthreads();
  for (int s2 = 128; s2 > 0; s2 >>= 1){ if (tid < s2) red[tid] = fmaxf(red[tid], red[tid+s2]); __syncthreads(); }
  float m = red[0]; __syncthreads();
  float se = 0.f;
  for (int c = tid; c < NCLS; c += 256) se += expf(pred[c]-m);
  float Z = bsum256(se, red);
  float logZ = m + logf(Z);
  float ent = 0.f;
  for (int c = tid; c < NCLS; c += 256){ float lp = pred[c]-logZ; ent += expf(lp)*lp; }
  float E = bsum256(ent, red);
  if (tid == 0){
    float ne = -E * (1.f/logf((float)NCLS));
    float* cp = dout + (size_t)BB*NCLS*NITER + (size_t)b*2*NITER + t;
    cp[0]     = ne;
    cp[NITER] = 1.f - ne;
  }
}

// ---------------- launch ----------------
extern "C" void kernel_launch(void* const* d_in, const int* in_sizes, int n_in,
                              void* d_out, int out_size, void* d_ws, size_t ws_size,
                              hipStream_t stream){
  const int*   x           = (const int*)  d_in[0];
  const float* emb         = (const float*)d_in[1];
  const float* kv_w        = (const float*)d_in[2];
  const float* kv_b        = (const float*)d_in[3];
  const float* kv_ln_g     = (const float*)d_in[4];
  const float* kv_ln_b     = (const float*)d_in[5];
  const float* q_w         = (const float*)d_in[6];
  const float* q_b         = (const float*)d_in[7];
  const float* in_proj_w   = (const float*)d_in[8];
  const float* in_proj_b   = (const float*)d_in[9];
  const float* out_proj_w  = (const float*)d_in[10];
  const float* out_proj_b  = (const float*)d_in[11];
  const float* syn_w       = (const float*)d_in[12];
  const float* syn_b       = (const float*)d_in[13];
  const float* syn_ln_g    = (const float*)d_in[14];
  const float* syn_ln_b    = (const float*)d_in[15];
  const float* tp1_w       = (const float*)d_in[16];
  const float* tp1_b       = (const float*)d_in[17];
  const float* tp2_w       = (const float*)d_in[18];
  const float* tp2_b       = (const float*)d_in[19];
  const float* start_act   = (const float*)d_in[20];
  const float* start_trace = (const float*)d_in[21];
  const float* decay_action= (const float*)d_in[22];
  const float* decay_out   = (const float*)d_in[23];
  const float* out_w       = (const float*)d_in[24];
  const float* out_b       = (const float*)d_in[25];
  float* dout = (float*)d_out;

  // ---- workspace layout (float units, 16B-aligned allocs) ----
  float* w = (float*)d_ws;
  size_t off = 0;
  auto alloc = [&](size_t n){ n = (n + 3) & ~(size_t)3; float* p = w + off; off += n; return p; };
  float* region0 = alloc((size_t)BGKS*128*NPART);    // embx_h/kvh (setup) / synpart+bigemm partials (iter)
  float* region1 = alloc((size_t)ROWS*D_IN);         // kvbuf fp32 (setup) / a_o (iter)
  float* Kmat    = alloc((size_t)ROWS*D_IN);
  float* Vmat    = alloc((size_t)ROWS*D_IN);
  float* trace   = alloc((size_t)BB*TRACE_SLOTS*D_MODEL);
  half_t* sync_oh= (half_t*)alloc((size_t)BB*SO_SZ/2);
  float* a_a     = alloc((size_t)BB*SA_SZ);
  float* sync_a  = alloc((size_t)BB*SA_SZ);
  float* act     = alloc((size_t)BB*D_MODEL);
  float* qpart   = alloc((size_t)4*BB*D_IN);
  float* obuf    = alloc((size_t)BB*D_IN);
  float* qfw     = alloc((size_t)SA_SZ*D_IN);        // q_w @ Wq  (2080x512)
  float* Wf2     = alloc((size_t)D_IN*2048);         // out_proj @ syn_w_top (512x2048)
  float* bqf     = alloc(D_IN);
  float* bias2   = alloc(2048);
  float* r_a     = alloc(SA_SZ);
  float* r_o     = alloc(SO_SZ);
  int2*  pairsA  = (int2*)alloc(2*SA_SZ);
  int2*  pairsO  = (int2*)alloc(2*SO_SZ);
  half_t* embh   = (half_t*)alloc((size_t)VOCAB*TED/2);      // emb fp16
  half_t* kvwh   = (half_t*)alloc((size_t)TED*D_IN/2);       // kv_w fp16
  half_t* Wkh    = (half_t*)alloc((size_t)D_IN*D_IN/2);      // Wk fp16
  half_t* Wvh    = (half_t*)alloc((size_t)D_IN*D_IN/2);      // Wv fp16
  half_t* Wh     = (half_t*)alloc(((size_t)SO_SZ*WHLD)/2);   // fp16 out_w

  half_t* embx_h = (half_t*)region0;   // setup: 9216x128 fp16
  half_t* kvh    = (half_t*)region0;   // setup: 9216x512 fp16 (embx_h dead by then)
  float* part    = region0;            // iter: bigemm partials
  float* synpart = region0;            // iter: syn partials (disjoint lifetime vs part)
  float* kvbuf = region1;
  float* a_o   = region1;

  dim3 blk(256);

  // ---- setup ----
  k_conv<<<(VOCAB*TED+255)/256, blk, 0, stream>>>(emb, embh, VOCAB*TED);
  k_convslice<<<(TED*D_IN+255)/256, blk, 0, stream>>>(kv_w, D_IN, 0, kvwh, TED, D_IN);
  k_convslice<<<(D_IN*D_IN+255)/256, blk, 0, stream>>>(in_proj_w, 1536, 512,  Wkh, D_IN, D_IN);
  k_convslice<<<(D_IN*D_IN+255)/256, blk, 0, stream>>>(in_proj_w, 1536, 1024, Wvh, D_IN, D_IN);
  k_embed_h<<<(ROWS*(TED/8)+255)/256, blk, 0, stream>>>(x, embh, embx_h);
  k_pgemm<<<dim3(8, ROWS/128), blk, 0, stream>>>(embx_h, TED, kvwh, kv_b, kvbuf, TED/64);
  k_ln_h<<<ROWS, blk, 0, stream>>>(kvbuf, kv_ln_g, kv_ln_b, kvh, D_IN);
  k_pgemm<<<dim3(8, ROWS/128), blk, 0, stream>>>(kvh, D_IN, Wkh, in_proj_b+512,  Kmat, D_IN/64);
  k_pgemm<<<dim3(8, ROWS/128), blk, 0, stream>>>(kvh, D_IN, Wvh, in_proj_b+1024, Vmat, D_IN/64);
  // fused weights: qfw = q_w @ Wq ; Wf2 = out_proj_w @ syn_w[:512]  (kept fp32-exact)
  k_gemm<8><<<dim3(2, SA_SZ/8), blk, 0, stream>>>(q_w, D_IN, in_proj_w, 1536, 0, 0, nullptr, qfw, D_IN, D_IN, D_IN);
  k_gemm<8><<<dim3(8, D_IN/8), blk, 0, stream>>>(out_proj_w, D_IN, syn_w, 2048, 0, 0, nullptr, Wf2, 2048, 2048, D_IN);
  k_colsum<<<2, blk, 0, stream>>>(q_b, in_proj_w, 1536, in_proj_b, bqf, D_IN, D_IN);
  k_colsum<<<8, blk, 0, stream>>>(out_proj_b, syn_w, 2048, syn_b, bias2, 2048, D_IN);
  k_convw<<<(SO_SZ*(WHLD/8)+255)/256, blk, 0, stream>>>(out_w, Wh);
  k_init_pairs<<<(SA_SZ+255)/256, blk, 0, stream>>>(N_SA, SA_SZ, decay_action, pairsA, r_a);
  k_init_pairs<<<(SO_SZ+255)/256, blk, 0, stream>>>(N_SO, SO_SZ, decay_out,    pairsO, r_o);
  k_init_act<<<(BB*D_MODEL+255)/256, blk, 0, stream>>>(start_act, act);
  k_zero<<<(BB*SA_SZ+255)/256, blk, 0, stream>>>(a_a, BB*SA_SZ);
  k_init_trace<<<(BB*MEMN*D_MODEL+255)/256, blk, 0, stream>>>(start_trace, trace);
  k_init_ao<<<dim3((SO_SZ+255)/256, BB), blk, 0, stream>>>(start_act, pairsO, a_o);

  // ---- 16 recurrent iterations ----
  for (int t = 0; t < NITER; t++){
    k_syncA<<<dim3((SA_SZ+255)/256, BB), blk, 0, stream>>>(act, r_a, pairsA, a_a, sync_a, t);
    k_gemmq<<<dim3(2, 32, 4), blk, 0, stream>>>(sync_a, qfw, qpart);
    k_attn<<<BB*HEADS, 128, 0, stream>>>(qpart, bqf, Kmat, Vmat, obuf);
    k_gemm2srcZ<<<dim3(8, 16, SYNZ), blk, 0, stream>>>(obuf, act, Wf2, syn_w, synpart);
    k_glu_ln<<<BB, blk, 0, stream>>>(synpart, bias2, syn_ln_g, syn_ln_b, trace + (size_t)(MEMN+t)*D_MODEL);
    k_neuron<<<(BB*D_MODEL+255)/256, blk, 0, stream>>>(trace, tp1_w, tp1_b, tp2_w, tp2_b, act, t);
    k_syncO<<<dim3((SO_SZ+255)/256, BB), blk, 0, stream>>>(act, r_o, pairsO, a_o, sync_oh, t);
    k_bigemm2h<<<dim3(31, BGKS), blk, 0, stream>>>(sync_oh, Wh, part);
    k_output<<<BB, blk, 0, stream>>>(part, out_b, dout, t);
  }
}

// Round 8
// 3041.434 us; speedup vs baseline: 11.6605x; 1.1765x over previous
//
#include <hip/hip_runtime.h>
#include <math.h>

#define BB 128
#define SS 72
#define NITER 16
#define D_IN 512
#define D_MODEL 1024
#define MEMN 25
#define HEADS 8
#define DHH 64
#define N_SO 256
#define N_SA 64
#define SA_SZ 2080
#define SO_SZ 32896
#define NCLS 1968
#define TED 128
#define VOCAB 32
#define ROWS (BB*SS)
#define TRACE_SLOTS (MEMN + NITER)   /* 41 */

/* big-GEMM (sync_o @ out_w) tiling */
#define BGN 64          /* cols per block */
#define BGKS 16         /* k splits */
#define BGKLEN 2056     /* 32896/16 */
#define BGSTEPS 33      /* ceil(2056/64); last step has 8 valid k */
#define NPART 1984      /* 31*64 padded col count */
#define WHLD 1984       /* fp16 out_w padded row length */
#define WCHUNKS 124     /* WHLD/16 */
#define SYNZ 6          /* K-splits for syn GEMM (1536/256) */

typedef _Float16 half_t;
typedef _Float16 half8 __attribute__((ext_vector_type(8)));
typedef float f32x4v __attribute__((ext_vector_type(4)));

__device__ __forceinline__ float sigmoidf_(float x){ return 1.f/(1.f+expf(-x)); }

__device__ __forceinline__ float bsum256(float v, float* red){
  int tid = threadIdx.x; red[tid] = v; __syncthreads();
#pragma unroll
  for (int s = 128; s > 0; s >>= 1){ if (tid < s) red[tid] += red[tid+s]; __syncthreads(); }
  float r = red[0]; __syncthreads(); return r;
}

__device__ __forceinline__ long triu_off(int n, int i){
  return (long)i*n - ((long)i*(i-1))/2;
}

__device__ __forceinline__ int swzA(int b){ return b ^ (((b>>9)&1)<<5); }

// ---------------- setup kernels ----------------
__global__ void k_conv(const float* __restrict__ src, half_t* __restrict__ dst, int n){
  int gid = blockIdx.x*256 + threadIdx.x;
  if (gid < n) dst[gid] = (half_t)src[gid];
}

// dst[r][c] = src[r*ldsrc + col0 + c]  (fp32 -> fp16)
__global__ void k_convslice(const float* __restrict__ src, int ldsrc, int col0,
                            half_t* __restrict__ dst, int rows, int cols){
  int gid = blockIdx.x*256 + threadIdx.x;
  if (gid >= rows*cols) return;
  int r = gid / cols, c = gid % cols;
  dst[gid] = (half_t)src[(size_t)r*ldsrc + col0 + c];
}

__global__ void k_embed_h(const int* __restrict__ x, const half_t* __restrict__ embh,
                          half_t* __restrict__ out){
  int gid = blockIdx.x*256 + threadIdx.x;           // half8 chunks: 9216*16
  if (gid >= ROWS*(TED/8)) return;
  int row = gid >> 4, c0 = (gid & 15)*8;
  *(half8*)(out + (size_t)row*TED + c0) = *(const half8*)(embh + (size_t)x[row]*TED + c0);
}

__global__ void k_init_pairs(int n, int npairs, const float* __restrict__ decay,
                             int2* __restrict__ pairs, float* __restrict__ rv){
  int p = blockIdx.x*256 + threadIdx.x;
  if (p >= npairs) return;
  double nn = (double)n;
  double disc = (2.0*nn+1.0)*(2.0*nn+1.0) - 8.0*(double)p;
  int i = (int)floor(((2.0*nn+1.0) - sqrt(disc))*0.5);
  if (i < 0) i = 0; if (i > n-1) i = n-1;
  while (i+1 < n && triu_off(n, i+1) <= (long)p) i++;
  while (i > 0 && triu_off(n, i) > (long)p) i--;
  int j = i + (int)((long)p - triu_off(n, i));
  pairs[p] = make_int2(i, j);
  float dc = decay[p]; dc = fminf(fmaxf(dc, 0.f), 15.f);
  rv[p] = expf(-dc);
}

__global__ void k_init_act(const float* __restrict__ sa, float* __restrict__ act){
  int gid = blockIdx.x*256 + threadIdx.x;
  if (gid >= BB*D_MODEL) return;
  act[gid] = sa[gid & 1023];
}

__global__ void k_zero(float* __restrict__ p, int n){
  int gid = blockIdx.x*256 + threadIdx.x;
  if (gid < n) p[gid] = 0.f;
}

__global__ void k_init_trace(const float* __restrict__ st, float* __restrict__ trace){
  int gid = blockIdx.x*256 + threadIdx.x;
  if (gid >= BB*MEMN*D_MODEL) return;
  int d = gid & 1023;
  int m = (gid >> 10) % MEMN;
  int b = (gid >> 10) / MEMN;
  trace[(size_t)b*TRACE_SLOTS*D_MODEL + (size_t)m*D_MODEL + d] = st[d*MEMN + m];
}

__global__ void k_init_ao(const float* __restrict__ sa, const int2* __restrict__ pairs,
                          float* __restrict__ ao){
  int p = blockIdx.x*256 + threadIdx.x;
  if (p >= SO_SZ) return;
  int b = blockIdx.y;
  int2 ij = pairs[p];
  ao[(size_t)b*SO_SZ + p] = sa[ij.x]*sa[ij.y];
}

// out_w (fp32 [32896][1968]) -> Wh (fp16 [32896][1984], zero-padded). One thread = 16 halfs.
// 1968 = 123*16, so chunks 0..122 are branch-free; chunk 123 is pure padding.
__global__ void k_convw(const float* __restrict__ W, half_t* __restrict__ Wh){
  int gid = blockIdx.x*256 + threadIdx.x;
  if (gid >= SO_SZ*WCHUNKS) return;
  int row = gid / WCHUNKS, ch = gid - row*WCHUNKS;
  int c0 = ch*16;
  half_t* dst = Wh + (size_t)row*WHLD + c0;
  if (ch < 123){
    const float4* src = (const float4*)(W + (size_t)row*NCLS + c0);
    float4 f0 = src[0], f1 = src[1], f2 = src[2], f3 = src[3];
    half8 h0, h1;
    h0[0]=(half_t)f0.x; h0[1]=(half_t)f0.y; h0[2]=(half_t)f0.z; h0[3]=(half_t)f0.w;
    h0[4]=(half_t)f1.x; h0[5]=(half_t)f1.y; h0[6]=(half_t)f1.z; h0[7]=(half_t)f1.w;
    h1[0]=(half_t)f2.x; h1[1]=(half_t)f2.y; h1[2]=(half_t)f2.z; h1[3]=(half_t)f2.w;
    h1[4]=(half_t)f3.x; h1[5]=(half_t)f3.y; h1[6]=(half_t)f3.z; h1[7]=(half_t)f3.w;
    *(half8*)dst = h0; *(half8*)(dst+8) = h1;
  } else {
    half8 zz;
#pragma unroll
    for (int j = 0; j < 8; j++) zz[j] = (half_t)0.f;
    *(half8*)dst = zz; *(half8*)(dst+8) = zz;
  }
}

// out[col] = sum_k vec[k]*W[k*ldw+col] + (addb?addb[col]:0)
__global__ void k_colsum(const float* __restrict__ vec, const float* __restrict__ W,
                         int ldw, const float* __restrict__ addb,
                         float* __restrict__ out, int N, int K){
  int col = blockIdx.x*256 + threadIdx.x;
  if (col >= N) return;
  float s = addb ? addb[col] : 0.f;
  for (int k = 0; k < K; k++) s = fmaf(vec[k], W[(size_t)k*ldw + col], s);
  out[col] = s;
}

// ---- generic fp32 GEMM:  C[M,N] = A[M,K] @ W[wrow0:,wcol0:] (+bias). REQUIRES K % 32 == 0 ----
template<int MB>
__global__ void k_gemm(const float* __restrict__ A, int lda,
                       const float* __restrict__ W, int ldw, int wrow0, int wcol0,
                       const float* __restrict__ bias,
                       float* __restrict__ C, int ldc, int N, int K){
  constexpr int KC = 32;
  const int tid = threadIdx.x;
  const int col = blockIdx.x*256 + tid;
  const int row0 = blockIdx.y*MB;
  __shared__ float As[MB][KC];
  float acc[MB];
#pragma unroll
  for (int r = 0; r < MB; r++) acc[r] = 0.f;
  for (int kk = 0; kk < K; kk += KC){
    __syncthreads();
    for (int idx = tid; idx < MB*KC; idx += 256){
      int r = idx / KC, k = idx % KC;
      As[r][k] = A[(size_t)(row0+r)*lda + kk + k];
    }
    __syncthreads();
#pragma unroll
    for (int k = 0; k < KC; k++){
      float w = W[(size_t)(wrow0+kk+k)*ldw + wcol0 + col];
#pragma unroll
      for (int r = 0; r < MB; r++) acc[r] = fmaf(As[r][k], w, acc[r]);
    }
  }
#pragma unroll
  for (int r = 0; r < MB; r++){
    size_t o = (size_t)(row0+r)*ldc + col;
    C[o] = acc[r] + (bias ? bias[col] : 0.f);
  }
}

// ---- fp16 MFMA projection GEMM: C[M,512] = Ah[M][ldah] @ Wh16[ldah][512] + bias ----
__global__ __launch_bounds__(256)
void k_pgemm(const half_t* __restrict__ Ah, int ldah,
             const half_t* __restrict__ Wh16, const float* __restrict__ bias,
             float* __restrict__ C, int ksteps){
  __shared__ half_t As[2][128*64];
  __shared__ half_t Ws[2][64*66];
  const int tid = threadIdx.x;
  const int nb0 = blockIdx.x * 64;
  const int row0 = blockIdx.y * 128;
  const int l = tid & 63, wv = tid >> 6;
  const int mw = (wv >> 1) * 64, nw = (wv & 1) * 32;
  const int c = l & 15, g = l >> 4;

  f32x4v acc[4][2];
#pragma unroll
  for (int i = 0; i < 4; i++)
#pragma unroll
    for (int j2 = 0; j2 < 2; j2++)
#pragma unroll
      for (int r = 0; r < 4; r++) acc[i][j2][r] = 0.f;

  auto stage = [&](int s, int buf){
#pragma unroll
    for (int it = 0; it < 4; it++){
      int ch = tid + it*256;
      int m = ch >> 3, kl = (ch & 7)*8;
      half8 v = *(const half8*)(Ah + (size_t)(row0+m)*ldah + s*64 + kl);
      *(half8*)((char*)(&As[buf][0]) + swzA(ch*16)) = v;
    }
    {
      int k = tid >> 2, cs = (tid & 3) * 16;
      const half_t* wr = Wh16 + (size_t)(s*64 + k) * D_IN + nb0 + cs;
      char* dst = (char*)(&Ws[buf][0]) + (size_t)(k*66 + cs) * 2;
      union { half8 v; unsigned int u[4]; } p0, p1;
      p0.v = *(const half8*)wr; p1.v = *(const half8*)(wr + 8);
#pragma unroll
      for (int q = 0; q < 4; q++){
        ((unsigned int*)dst)[q]        = p0.u[q];
        ((unsigned int*)(dst + 16))[q] = p1.u[q];
      }
    }
  };

  stage(0, 0);
  __syncthreads();
  for (int s = 0; s < ksteps; s++){
    int buf = s & 1;
    if (s + 1 < ksteps) stage(s+1, buf^1);
#pragma unroll
    for (int h = 0; h < 2; h++){
      half8 a8[4];
#pragma unroll
      for (int mb = 0; mb < 4; mb++)
        a8[mb] = *(const half8*)((const char*)(&As[buf][0]) +
                   swzA(((mw + mb*16 + c)*64 + h*32 + g*8)*2));
#pragma unroll
      for (int nb = 0; nb < 2; nb++){
        half8 b8;
        const half_t* wp = &Ws[buf][(h*32 + g*8)*66 + nw + nb*16 + c];
#pragma unroll
        for (int j = 0; j < 8; j++) b8[j] = wp[j*66];
#pragma unroll
        for (int mb = 0; mb < 4; mb++)
          acc[mb][nb] = __builtin_amdgcn_mfma_f32_16x16x32_f16(a8[mb], b8, acc[mb][nb], 0, 0, 0);
      }
    }
    __syncthreads();
  }
#pragma unroll
  for (int mb = 0; mb < 4; mb++)
#pragma unroll
    for (int nb = 0; nb < 2; nb++){
      int m = mw + mb*16 + g*4;
      int n = nb0 + nw + nb*16 + c;
      float bv = bias[n];
#pragma unroll
      for (int r = 0; r < 4; r++)
        C[(size_t)(row0 + m + r) * D_IN + n] = acc[mb][nb][r] + bv;
    }
}

// ---- syn fp16 MFMA GEMM: synpart[z][128][2048] = Ah16[:, z*256:+256] @ Wsynh[z*256:+256, :] ----
__global__ __launch_bounds__(256)
void k_syn16(const half_t* __restrict__ Ah, const half_t* __restrict__ Wh16,
             float* __restrict__ outp){
  __shared__ half_t As[2][128*64];
  __shared__ half_t Ws[2][64*66];
  const int tid = threadIdx.x;
  const int nb0 = blockIdx.x * 64;     // N=2048, grid.x=32
  const int z = blockIdx.y;            // 6 k-chunks of 256
  const int l = tid & 63, wv = tid >> 6;
  const int mw = (wv >> 1) * 64, nw = (wv & 1) * 32;
  const int c = l & 15, g = l >> 4;
  const int kbase = z * 256;

  f32x4v acc[4][2];
#pragma unroll
  for (int i = 0; i < 4; i++)
#pragma unroll
    for (int j2 = 0; j2 < 2; j2++)
#pragma unroll
      for (int r = 0; r < 4; r++) acc[i][j2][r] = 0.f;

  auto stage = [&](int s, int buf){
#pragma unroll
    for (int it = 0; it < 4; it++){
      int ch = tid + it*256;
      int m = ch >> 3, kl = (ch & 7)*8;
      half8 v = *(const half8*)(Ah + (size_t)m*1536 + kbase + s*64 + kl);
      *(half8*)((char*)(&As[buf][0]) + swzA(ch*16)) = v;
    }
    {
      int k = tid >> 2, cs = (tid & 3) * 16;
      const half_t* wr = Wh16 + (size_t)(kbase + s*64 + k) * 2048 + nb0 + cs;
      char* dst = (char*)(&Ws[buf][0]) + (size_t)(k*66 + cs) * 2;
      union { half8 v; unsigned int u[4]; } p0, p1;
      p0.v = *(const half8*)wr; p1.v = *(const half8*)(wr + 8);
#pragma unroll
      for (int q = 0; q < 4; q++){
        ((unsigned int*)dst)[q]        = p0.u[q];
        ((unsigned int*)(dst + 16))[q] = p1.u[q];
      }
    }
  };

  stage(0, 0);
  __syncthreads();
  for (int s = 0; s < 4; s++){
    int buf = s & 1;
    if (s + 1 < 4) stage(s+1, buf^1);
#pragma unroll
    for (int h = 0; h < 2; h++){
      half8 a8[4];
#pragma unroll
      for (int mb = 0; mb < 4; mb++)
        a8[mb] = *(const half8*)((const char*)(&As[buf][0]) +
                   swzA(((mw + mb*16 + c)*64 + h*32 + g*8)*2));
#pragma unroll
      for (int nb = 0; nb < 2; nb++){
        half8 b8;
        const half_t* wp = &Ws[buf][(h*32 + g*8)*66 + nw + nb*16 + c];
#pragma unroll
        for (int j = 0; j < 8; j++) b8[j] = wp[j*66];
#pragma unroll
        for (int mb = 0; mb < 4; mb++)
          acc[mb][nb] = __builtin_amdgcn_mfma_f32_16x16x32_f16(a8[mb], b8, acc[mb][nb], 0, 0, 0);
      }
    }
    __syncthreads();
  }
  float* pz = outp + (size_t)z * BB * 2048;
#pragma unroll
  for (int mb = 0; mb < 4; mb++)
#pragma unroll
    for (int nb = 0; nb < 2; nb++){
      int m = mw + mb*16 + g*4;
      int n = nb0 + nw + nb*16 + c;
#pragma unroll
      for (int r = 0; r < 4; r++)
        pz[(size_t)(m + r) * 2048 + n] = acc[mb][nb][r];
    }
}

// ---- pack [obuf | act] -> fp16 Ah16[128][1536] ----
__global__ void k_cat16(const float* __restrict__ obuf, const float* __restrict__ act,
                        half_t* __restrict__ Ah){
  int gid = blockIdx.x*256 + threadIdx.x;   // 8-half chunks: 128*192
  if (gid >= BB*192) return;
  int row = gid / 192, c = (gid - row*192)*8;
  const float* src = (c < D_IN) ? (obuf + (size_t)row*D_IN + c)
                                : (act + (size_t)row*D_MODEL + (c - D_IN));
  float4 f0 = *(const float4*)src, f1 = *(const float4*)(src + 4);
  half8 h;
  h[0]=(half_t)f0.x; h[1]=(half_t)f0.y; h[2]=(half_t)f0.z; h[3]=(half_t)f0.w;
  h[4]=(half_t)f1.x; h[5]=(half_t)f1.y; h[6]=(half_t)f1.z; h[7]=(half_t)f1.w;
  *(half8*)(Ah + (size_t)row*1536 + c) = h;
}

// ---- q-fused GEMM, 4-way K-split: qpart[z] = sync_a @ qfw (k-range z) ----
__global__ void k_gemmq(const float* __restrict__ A, const float* __restrict__ W,
                        float* __restrict__ qpart){
  constexpr int KC = 32;
  const int tid = threadIdx.x;
  const int col = blockIdx.x*256 + tid;
  const int row0 = blockIdx.y*4;
  const int z = blockIdx.z;
  const int kstart = z*544;
  const int kend = min(SA_SZ, kstart + 544);
  __shared__ float As[4][KC];
  float acc[4] = {0.f,0.f,0.f,0.f};
  for (int kk = kstart; kk < kend; kk += KC){
    __syncthreads();
    for (int idx = tid; idx < 4*KC; idx += 256){
      int r = idx / KC, k = idx % KC;
      As[r][k] = A[(size_t)(row0+r)*SA_SZ + kk + k];
    }
    __syncthreads();
#pragma unroll
    for (int k = 0; k < KC; k++){
      float w = W[(size_t)(kk+k)*D_IN + col];
#pragma unroll
      for (int r = 0; r < 4; r++) acc[r] = fmaf(As[r][k], w, acc[r]);
    }
  }
#pragma unroll
  for (int r = 0; r < 4; r++)
    qpart[(size_t)z*BB*D_IN + (size_t)(row0+r)*D_IN + col] = acc[r];
}

// ---- fused syn GEMM fp32 fallback, 6-way K-split ----
__global__ void k_gemm2srcZ(const float* __restrict__ A1, const float* __restrict__ A2,
                            const float* __restrict__ W1, const float* __restrict__ W2,
                            float* __restrict__ outp){
  constexpr int MB = 8, KC = 32;
  const int tid = threadIdx.x;
  const int col = blockIdx.x*256 + tid;
  const int row0 = blockIdx.y*MB;
  const int z = blockIdx.z;
  __shared__ float As[MB][KC];
  float acc[MB];
#pragma unroll
  for (int r = 0; r < MB; r++) acc[r] = 0.f;
  for (int kk = z*256; kk < z*256 + 256; kk += KC){
    __syncthreads();
    for (int idx = tid; idx < MB*KC; idx += 256){
      int r = idx / KC, k = idx % KC;
      int kg = kk + k;
      As[r][k] = (kg < D_IN) ? A1[(size_t)(row0+r)*D_IN + kg]
                             : A2[(size_t)(row0+r)*D_MODEL + kg - D_IN];
    }
    __syncthreads();
    const float* Wp = (kk < D_IN) ? W1 : W2;
#pragma unroll
    for (int k = 0; k < KC; k++){
      float w = Wp[(size_t)(kk+k)*2048 + col];
#pragma unroll
      for (int r = 0; r < MB; r++) acc[r] = fmaf(As[r][k], w, acc[r]);
    }
  }
#pragma unroll
  for (int r = 0; r < MB; r++)
    outp[(size_t)z*BB*2048 + (size_t)(row0+r)*2048 + col] = acc[r];
}

// ---------------- LayerNorm (block per row), fp32 in -> fp16 out ----------------
__global__ void k_ln_h(const float* __restrict__ X, const float* __restrict__ g,
                       const float* __restrict__ bta, half_t* __restrict__ Y, int D){
  const int row = blockIdx.x, tid = threadIdx.x;
  __shared__ float red[256];
  const float* xr = X + (size_t)row*D;
  float s = 0.f;
  for (int c = tid; c < D; c += 256) s += xr[c];
  float mean = bsum256(s, red) / (float)D;
  float s2 = 0.f;
  for (int c = tid; c < D; c += 256){ float d = xr[c]-mean; s2 += d*d; }
  float var = bsum256(s2, red) / (float)D;
  float inv = 1.f / sqrtf(var + 1e-5f);
  half_t* yr = Y + (size_t)row*D;
  for (int c = tid; c < D; c += 256) yr[c] = (half_t)((xr[c]-mean)*inv*g[c] + bta[c]);
}

// ---- sum 6 synpart + bias2 -> GLU -> LN -> trace slot ----
__global__ void k_glu_ln(const float* __restrict__ synpart, const float* __restrict__ bias2,
                         const float* __restrict__ g, const float* __restrict__ bta,
                         float* __restrict__ traceSlot){
  const int b = blockIdx.x, tid = threadIdx.x;
  __shared__ float vals[D_MODEL];
  __shared__ float red[256];
  for (int c = tid; c < 1024; c += 256){
    float a = bias2[c], gg = bias2[c+1024];
#pragma unroll
    for (int z = 0; z < SYNZ; z++){
      const float* sp = synpart + (size_t)z*BB*2048 + (size_t)b*2048;
      a  += sp[c];
      gg += sp[c+1024];
    }
    vals[c] = a * sigmoidf_(gg);
  }
  __syncthreads();
  float s = 0.f;
  for (int c = tid; c < 1024; c += 256) s += vals[c];
  float mean = bsum256(s, red) * (1.f/1024.f);
  float s2 = 0.f;
  for (int c = tid; c < 1024; c += 256){ float d = vals[c]-mean; s2 += d*d; }
  float var = bsum256(s2, red) * (1.f/1024.f);
  float inv = 1.f / sqrtf(var + 1e-5f);
  float* out = traceSlot + (size_t)b*(TRACE_SLOTS*D_MODEL);
  for (int c = tid; c < 1024; c += 256) out[c] = (vals[c]-mean)*inv*g[c] + bta[c];
}

// ---------------- attention: block per (b,h); q = sum of 4 qpart + bqf ----------------
__global__ void k_attn(const float* __restrict__ qpart, const float* __restrict__ bqf,
                       const float* __restrict__ Km, const float* __restrict__ Vm,
                       float* __restrict__ o){
  const int bh = blockIdx.x, b = bh >> 3, h = bh & 7;
  const int tid = threadIdx.x;
  __shared__ float qs[DHH];
  __shared__ float attn[SS];
  __shared__ float red[128];
  if (tid < DHH){
    int d = h*DHH + tid;
    float qv = bqf[d];
#pragma unroll
    for (int z = 0; z < 4; z++) qv += qpart[(size_t)z*BB*D_IN + (size_t)b*D_IN + d];
    qs[tid] = qv;
  }
  __syncthreads();
  float sc = -1e30f;
  if (tid < SS){
    const float* kp = Km + ((size_t)(b*SS+tid)*HEADS + h)*DHH;
    float d = 0.f;
#pragma unroll
    for (int i = 0; i < DHH; i++) d = fmaf(qs[i], kp[i], d);
    sc = d * 0.125f;
  }
  red[tid] = sc; __syncthreads();
  for (int s2 = 64; s2 > 0; s2 >>= 1){ if (tid < s2) red[tid] = fmaxf(red[tid], red[tid+s2]); __syncthreads(); }
  float m = red[0]; __syncthreads();
  float e = (tid < SS) ? expf(sc - m) : 0.f;
  red[tid] = e; __syncthreads();
  for (int s2 = 64; s2 > 0; s2 >>= 1){ if (tid < s2) red[tid] += red[tid+s2]; __syncthreads(); }
  float inv = 1.f / red[0]; __syncthreads();
  if (tid < SS) attn[tid] = e * inv;
  __syncthreads();
  if (tid < DHH){
    const float* vp = Vm + ((size_t)(b*SS)*HEADS + h)*DHH + tid;
    float acc = 0.f;
    for (int s2 = 0; s2 < SS; s2++) acc = fmaf(attn[s2], vp[(size_t)s2*D_IN], acc);
    o[(size_t)b*D_IN + h*DHH + tid] = acc;
  }
}

// ---- neuron update (trace->tp1->GLU->tp2->GLU), register-lean ----
__global__ void k_neuron(const float* __restrict__ trace,
                         const float* __restrict__ tp1w, const float* __restrict__ tp1b,
                         const float* __restrict__ tp2w, const float* __restrict__ tp2b,
                         float* __restrict__ act, int t){
  int gid = blockIdx.x*256 + threadIdx.x;
  if (gid >= BB*D_MODEL) return;
  int b = gid >> 10, d = gid & 1023;
  const float* tr = trace + (size_t)b*(TRACE_SLOTS*D_MODEL) + (size_t)(t+1)*D_MODEL + d;
  float trv[MEMN];
#pragma unroll
  for (int m = 0; m < MEMN; m++) trv[m] = tr[(size_t)m*D_MODEL];
  float o0 = tp2b[d*2+0], o1 = tp2b[d*2+1];
#pragma unroll
  for (int j = 0; j < 16; j++){
    const float* wpj = tp1w + (size_t)j*1024 + d;
    const float* wpg = tp1w + (size_t)(j+16)*1024 + d;
    float hj = tp1b[d*32 + j];
    float hg = tp1b[d*32 + j + 16];
#pragma unroll
    for (int m = 0; m < MEMN; m++){
      float tv = trv[m];
      hj = fmaf(tv, wpj[(size_t)m*32*1024], hj);
      hg = fmaf(tv, wpg[(size_t)m*32*1024], hg);
    }
    float hgv = hj * sigmoidf_(hg);
    o0 = fmaf(hgv, tp2w[(size_t)(j*2+0)*1024 + d], o0);
    o1 = fmaf(hgv, tp2w[(size_t)(j*2+1)*1024 + d], o1);
  }
  act[gid] = o0 * sigmoidf_(o1);
}

// ---------------- sync accumulators ----------------
__global__ void k_syncA(const float* __restrict__ act, const float* __restrict__ rv,
                        const int2* __restrict__ pairs, float* __restrict__ aa,
                        float* __restrict__ syncv, int t){
  int p = blockIdx.x*256 + threadIdx.x;
  if (p >= SA_SZ) return;
  int b = blockIdx.y;
  int2 ij = pairs[p];
  const float* ab = act + (size_t)b*D_MODEL + (D_MODEL - N_SA);
  float r = rv[p];
  size_t idx = (size_t)b*SA_SZ + p;
  float a = fmaf(r, aa[idx], ab[ij.x]*ab[ij.y]);
  aa[idx] = a;
  float bb = 0.f;
  for (int i = 0; i <= t; i++) bb = fmaf(r, bb, 1.f);
  syncv[idx] = a / sqrtf(bb);
}

__global__ void k_syncO(const float* __restrict__ act, const float* __restrict__ rv,
                        const int2* __restrict__ pairs, float* __restrict__ ao,
                        half_t* __restrict__ syncv, int t){
  int p = blockIdx.x*256 + threadIdx.x;
  if (p >= SO_SZ) return;
  int b = blockIdx.y;
  int2 ij = pairs[p];
  const float* ab = act + (size_t)b*D_MODEL;
  float r = rv[p];
  size_t idx = (size_t)b*SO_SZ + p;
  float a = fmaf(r, ao[idx], ab[ij.x]*ab[ij.y]);
  ao[idx] = a;
  float bb = 1.f;
  for (int i = 0; i <= t; i++) bb = fmaf(r, bb, 1.f);
  syncv[idx] = (half_t)(a / sqrtf(bb));
}

// ---------------- big GEMM, fp16-W path ----------------
__global__ __launch_bounds__(256)
void k_bigemm2h(const half_t* __restrict__ Ah, const half_t* __restrict__ Wh,
                float* __restrict__ part){
  __shared__ half_t As[2][128*64];
  __shared__ half_t Ws[2][64*66];
  const int tid = threadIdx.x;
  const int z = blockIdx.y;
  const int nb0 = blockIdx.x * BGN;
  const int l = tid & 63, wv = tid >> 6;
  const int mw = (wv >> 1) * 64, nw = (wv & 1) * 32;
  const int c = l & 15, g = l >> 4;
  const int k0 = z * BGKLEN;

  f32x4v acc[4][2];
#pragma unroll
  for (int i = 0; i < 4; i++)
#pragma unroll
    for (int j2 = 0; j2 < 2; j2++)
#pragma unroll
      for (int r = 0; r < 4; r++) acc[i][j2][r] = 0.f;

  auto stage = [&](int s, int buf){
    const int kv = min(64, BGKLEN - s*64);
#pragma unroll
    for (int it = 0; it < 4; it++){
      int ch = tid + it*256;
      int m = ch >> 3, kg = ch & 7, kl = kg*8;
      half8 v;
      if (kl < kv) v = *(const half8*)(Ah + (size_t)m*SO_SZ + k0 + s*64 + kl);
      else {
#pragma unroll
        for (int j = 0; j < 8; j++) v[j] = (half_t)0.f;
      }
      *(half8*)((char*)(&As[buf][0]) + swzA(ch*16)) = v;
    }
    {
      int k = tid >> 2, cs = (tid & 3) * 16;
      const half_t* wr = Wh + (size_t)(k0 + s*64 + k) * WHLD + nb0 + cs;
      char* dst = (char*)(&Ws[buf][0]) + (size_t)(k*66 + cs) * 2;
      union { half8 v; unsigned int u[4]; } p0, p1;
      if (k < kv){ p0.v = *(const half8*)wr; p1.v = *(const half8*)(wr + 8); }
      else {
#pragma unroll
        for (int j = 0; j < 8; j++){ p0.v[j] = (half_t)0.f; p1.v[j] = (half_t)0.f; }
      }
#pragma unroll
      for (int q = 0; q < 4; q++){
        ((unsigned int*)dst)[q]        = p0.u[q];
        ((unsigned int*)(dst + 16))[q] = p1.u[q];
      }
    }
  };

  stage(0, 0);
  __syncthreads();
  for (int s = 0; s < BGSTEPS; s++){
    int buf = s & 1;
    if (s + 1 < BGSTEPS) stage(s+1, buf^1);
#pragma unroll
    for (int h = 0; h < 2; h++){
      half8 a8[4];
#pragma unroll
      for (int mb = 0; mb < 4; mb++)
        a8[mb] = *(const half8*)((const char*)(&As[buf][0]) +
                   swzA(((mw + mb*16 + c)*64 + h*32 + g*8)*2));
#pragma unroll
      for (int nb = 0; nb < 2; nb++){
        half8 b8;
        const half_t* wp = &Ws[buf][(h*32 + g*8)*66 + nw + nb*16 + c];
#pragma unroll
        for (int j = 0; j < 8; j++) b8[j] = wp[j*66];
#pragma unroll
        for (int mb = 0; mb < 4; mb++)
          acc[mb][nb] = __builtin_amdgcn_mfma_f32_16x16x32_f16(a8[mb], b8, acc[mb][nb], 0, 0, 0);
      }
    }
    __syncthreads();
  }
  float* pz = part + (size_t)z * 128 * NPART;
#pragma unroll
  for (int mb = 0; mb < 4; mb++)
#pragma unroll
    for (int nb = 0; nb < 2; nb++){
      int m = mw + mb*16 + g*4;
      int n = nb0 + nw + nb*16 + c;
#pragma unroll
      for (int r = 0; r < 4; r++)
        pz[(size_t)(m + r) * NPART + n] = acc[mb][nb][r];
    }
}

// ---------------- combine partials + bias, write preds + certainties ----------------
__global__ void k_output(const float* __restrict__ part, const float* __restrict__ outb,
                         float* __restrict__ dout, int t){
  const int b = blockIdx.x, tid = threadIdx.x;
  __shared__ float pred[NCLS];
  __shared__ float red[256];
  float lmax = -1e30f;
  for (int c = tid; c < NCLS; c += 256){
    float s = outb[c];
    const float* pp = part + (size_t)b*NPART + c;
#pragma unroll
    for (int z = 0; z < BGKS; z++) s += pp[(size_t)z*128*NPART];
    pred[c] = s;
    dout[((size_t)b*NCLS + c)*NITER + t] = s;
    lmax = fmaxf(lmax, s);
  }
  red[tid] = lmax; __syncthreads();
  for (int s2 = 128; s2 > 0; s2 >>= 1){ if (tid < s2) red[tid] = fmaxf(red[tid], red[tid+s2]); __syncthreads(); }
  float m = red[0]; __syncthreads();
  float se = 0.f;
  for (int c = tid; c < NCLS; c += 256) se += expf(pred[c]-m);
  float Z = bsum256(se, red);
  float logZ = m + logf(Z);
  float ent = 0.f;
  for (int c = tid; c < NCLS; c += 256){ float lp = pred[c]-logZ; ent += expf(lp)*lp; }
  float E = bsum256(ent, red);
  if (tid == 0){
    float ne = -E * (1.f/logf((float)NCLS));
    float* cp = dout + (size_t)BB*NCLS*NITER + (size_t)b*2*NITER + t;
    cp[0]     = ne;
    cp[NITER] = 1.f - ne;
  }
}

// ---------------- launch ----------------
extern "C" void kernel_launch(void* const* d_in, const int* in_sizes, int n_in,
                              void* d_out, int out_size, void* d_ws, size_t ws_size,
                              hipStream_t stream){
  const int*   x           = (const int*)  d_in[0];
  const float* emb         = (const float*)d_in[1];
  const float* kv_w        = (const float*)d_in[2];
  const float* kv_b        = (const float*)d_in[3];
  const float* kv_ln_g     = (const float*)d_in[4];
  const float* kv_ln_b     = (const float*)d_in[5];
  const float* q_w         = (const float*)d_in[6];
  const float* q_b         = (const float*)d_in[7];
  const float* in_proj_w   = (const float*)d_in[8];
  const float* in_proj_b   = (const float*)d_in[9];
  const float* out_proj_w  = (const float*)d_in[10];
  const float* out_proj_b  = (const float*)d_in[11];
  const float* syn_w       = (const float*)d_in[12];
  const float* syn_b       = (const float*)d_in[13];
  const float* syn_ln_g    = (const float*)d_in[14];
  const float* syn_ln_b    = (const float*)d_in[15];
  const float* tp1_w       = (const float*)d_in[16];
  const float* tp1_b       = (const float*)d_in[17];
  const float* tp2_w       = (const float*)d_in[18];
  const float* tp2_b       = (const float*)d_in[19];
  const float* start_act   = (const float*)d_in[20];
  const float* start_trace = (const float*)d_in[21];
  const float* decay_action= (const float*)d_in[22];
  const float* decay_out   = (const float*)d_in[23];
  const float* out_w       = (const float*)d_in[24];
  const float* out_b       = (const float*)d_in[25];
  float* dout = (float*)d_out;

  // ---- workspace layout (float units, 16B-aligned allocs) ----
  float* w = (float*)d_ws;
  size_t off = 0;
  auto alloc = [&](size_t n){ n = (n + 3) & ~(size_t)3; float* p = w + off; off += n; return p; };
  float* region0 = alloc((size_t)BGKS*128*NPART);    // setup: embx_h/kvh | iter: synpart+part
  float* region1 = alloc((size_t)ROWS*D_IN);         // setup: kvbuf | iter: a_o
  float* Kmat    = alloc((size_t)ROWS*D_IN);
  float* Vmat    = alloc((size_t)ROWS*D_IN);
  float* trace   = alloc((size_t)BB*TRACE_SLOTS*D_MODEL);
  half_t* sync_oh= (half_t*)alloc((size_t)BB*SO_SZ/2);
  float* a_a     = alloc((size_t)BB*SA_SZ);
  float* sync_a  = alloc((size_t)BB*SA_SZ);
  float* act     = alloc((size_t)BB*D_MODEL);
  float* qpart   = alloc((size_t)4*BB*D_IN);
  float* obuf    = alloc((size_t)BB*D_IN);
  float* qfw     = alloc((size_t)SA_SZ*D_IN);        // q_w @ Wq
  float* Wf2     = alloc((size_t)D_IN*2048);         // out_proj @ syn_w_top
  float* bqf     = alloc(D_IN);
  float* bias2   = alloc(2048);
  float* r_a     = alloc(SA_SZ);
  float* r_o     = alloc(SO_SZ);
  int2*  pairsA  = (int2*)alloc(2*SA_SZ);
  int2*  pairsO  = (int2*)alloc(2*SO_SZ);
  half_t* embh   = (half_t*)alloc((size_t)VOCAB*TED/2);
  half_t* kvwh   = (half_t*)alloc((size_t)TED*D_IN/2);
  half_t* Wkh    = (half_t*)alloc((size_t)D_IN*D_IN/2);
  half_t* Wvh    = (half_t*)alloc((size_t)D_IN*D_IN/2);
  half_t* Wh     = (half_t*)alloc(((size_t)SO_SZ*WHLD)/2);   // fp16 out_w
  // optional fp16 syn path (gated on ws headroom)
  half_t* Ah16   = (half_t*)alloc((size_t)BB*1536/2);
  half_t* Wsynh  = (half_t*)alloc((size_t)1536*2048/2);
  const bool use_syn16 = (off * sizeof(float) <= ws_size);

  half_t* embx_h = (half_t*)region0;
  half_t* kvh    = (half_t*)region0;
  float* part    = region0;
  float* synpart = region0;
  float* kvbuf = region1;
  float* a_o   = region1;

  dim3 blk(256);

  // ---- setup ----
  k_conv<<<(VOCAB*TED+255)/256, blk, 0, stream>>>(emb, embh, VOCAB*TED);
  k_convslice<<<(TED*D_IN+255)/256, blk, 0, stream>>>(kv_w, D_IN, 0, kvwh, TED, D_IN);
  k_convslice<<<(D_IN*D_IN+255)/256, blk, 0, stream>>>(in_proj_w, 1536, 512,  Wkh, D_IN, D_IN);
  k_convslice<<<(D_IN*D_IN+255)/256, blk, 0, stream>>>(in_proj_w, 1536, 1024, Wvh, D_IN, D_IN);
  k_embed_h<<<(ROWS*(TED/8)+255)/256, blk, 0, stream>>>(x, embh, embx_h);
  k_pgemm<<<dim3(8, ROWS/128), blk, 0, stream>>>(embx_h, TED, kvwh, kv_b, kvbuf, TED/64);
  k_ln_h<<<ROWS, blk, 0, stream>>>(kvbuf, kv_ln_g, kv_ln_b, kvh, D_IN);
  k_pgemm<<<dim3(8, ROWS/128), blk, 0, stream>>>(kvh, D_IN, Wkh, in_proj_b+512,  Kmat, D_IN/64);
  k_pgemm<<<dim3(8, ROWS/128), blk, 0, stream>>>(kvh, D_IN, Wvh, in_proj_b+1024, Vmat, D_IN/64);
  // fused weights (fp32-exact), MB=4 for block count
  k_gemm<4><<<dim3(2, SA_SZ/4), blk, 0, stream>>>(q_w, D_IN, in_proj_w, 1536, 0, 0, nullptr, qfw, D_IN, D_IN, D_IN);
  k_gemm<4><<<dim3(8, D_IN/4), blk, 0, stream>>>(out_proj_w, D_IN, syn_w, 2048, 0, 0, nullptr, Wf2, 2048, 2048, D_IN);
  k_colsum<<<2, blk, 0, stream>>>(q_b, in_proj_w, 1536, in_proj_b, bqf, D_IN, D_IN);
  k_colsum<<<8, blk, 0, stream>>>(out_proj_b, syn_w, 2048, syn_b, bias2, 2048, D_IN);
  k_convw<<<(SO_SZ*WCHUNKS+255)/256, blk, 0, stream>>>(out_w, Wh);
  if (use_syn16){
    k_conv<<<(512*2048+255)/256, blk, 0, stream>>>(Wf2, Wsynh, 512*2048);
    k_conv<<<(1024*2048+255)/256, blk, 0, stream>>>(syn_w + (size_t)512*2048, Wsynh + (size_t)512*2048, 1024*2048);
  }
  k_init_pairs<<<(SA_SZ+255)/256, blk, 0, stream>>>(N_SA, SA_SZ, decay_action, pairsA, r_a);
  k_init_pairs<<<(SO_SZ+255)/256, blk, 0, stream>>>(N_SO, SO_SZ, decay_out,    pairsO, r_o);
  k_init_act<<<(BB*D_MODEL+255)/256, blk, 0, stream>>>(start_act, act);
  k_zero<<<(BB*SA_SZ+255)/256, blk, 0, stream>>>(a_a, BB*SA_SZ);
  k_init_trace<<<(BB*MEMN*D_MODEL+255)/256, blk, 0, stream>>>(start_trace, trace);
  k_init_ao<<<dim3((SO_SZ+255)/256, BB), blk, 0, stream>>>(start_act, pairsO, a_o);

  // ---- 16 recurrent iterations ----
  for (int t = 0; t < NITER; t++){
    k_syncA<<<dim3((SA_SZ+255)/256, BB), blk, 0, stream>>>(act, r_a, pairsA, a_a, sync_a, t);
    k_gemmq<<<dim3(2, 32, 4), blk, 0, stream>>>(sync_a, qfw, qpart);
    k_attn<<<BB*HEADS, 128, 0, stream>>>(qpart, bqf, Kmat, Vmat, obuf);
    if (use_syn16){
      k_cat16<<<(BB*192+255)/256, blk, 0, stream>>>(obuf, act, Ah16);
      k_syn16<<<dim3(32, SYNZ), blk, 0, stream>>>(Ah16, Wsynh, synpart);
    } else {
      k_gemm2srcZ<<<dim3(8, 16, SYNZ), blk, 0, stream>>>(obuf, act, Wf2, syn_w, synpart);
    }
    k_glu_ln<<<BB, blk, 0, stream>>>(synpart, bias2, syn_ln_g, syn_ln_b, trace + (size_t)(MEMN+t)*D_MODEL);
    k_neuron<<<(BB*D_MODEL+255)/256, blk, 0, stream>>>(trace, tp1_w, tp1_b, tp2_w, tp2_b, act, t);
    k_syncO<<<dim3((SO_SZ+255)/256, BB), blk, 0, stream>>>(act, r_o, pairsO, a_o, sync_oh, t);
    k_bigemm2h<<<dim3(31, BGKS), blk, 0, stream>>>(sync_oh, Wh, part);
    k_output<<<BB, blk, 0, stream>>>(part, out_b, dout, t);
  }
}

// Round 9
// 2993.500 us; speedup vs baseline: 11.8472x; 1.0160x over previous
//
#include <hip/hip_runtime.h>
#include <math.h>

#define BB 128
#define SS 72
#define NITER 16
#define D_IN 512
#define D_MODEL 1024
#define MEMN 25
#define HEADS 8
#define DHH 64
#define N_SO 256
#define N_SA 64
#define SA_SZ 2080
#define SO_SZ 32896
#define NCLS 1968
#define TED 128
#define VOCAB 32
#define ROWS (BB*SS)
#define TRACE_SLOTS (MEMN + NITER)   /* 41 */

/* big-GEMM (sync_o @ out_w) tiling */
#define BGN 64
#define BGKS 16
#define BGKLEN 2056
#define BGSTEPS 33
#define NPART 1984
#define WHLD 1984
#define WCHUNKS 124
#define SYNZ 6

typedef _Float16 half_t;
typedef _Float16 half8 __attribute__((ext_vector_type(8)));
typedef float f32x4v __attribute__((ext_vector_type(4)));

__device__ __forceinline__ float sigmoidf_(float x){ return 1.f/(1.f+expf(-x)); }

__device__ __forceinline__ float bsum256(float v, float* red){
  int tid = threadIdx.x; red[tid] = v; __syncthreads();
#pragma unroll
  for (int s = 128; s > 0; s >>= 1){ if (tid < s) red[tid] += red[tid+s]; __syncthreads(); }
  float r = red[0]; __syncthreads(); return r;
}

__device__ __forceinline__ long triu_off(int n, int i){
  return (long)i*n - ((long)i*(i-1))/2;
}

__device__ __forceinline__ int swzA(int b){ return b ^ (((b>>9)&1)<<5); }

// ---------------- setup kernels ----------------
__global__ void k_conv(const float* __restrict__ src, half_t* __restrict__ dst, int n){
  int gid = blockIdx.x*256 + threadIdx.x;
  if (gid < n) dst[gid] = (half_t)src[gid];
}

// merged fp32->fp16 weight conversions: emb, kv_w, Wk slice, Wv slice
#define CV0 (VOCAB*TED)            /* 4096 */
#define CV1 (CV0 + TED*D_IN)       /* +65536 */
#define CV2 (CV1 + D_IN*D_IN)      /* +262144 */
#define CV3 (CV2 + D_IN*D_IN)
__global__ void k_convall(const float* __restrict__ emb, const float* __restrict__ kv_w,
                          const float* __restrict__ in_proj_w,
                          half_t* __restrict__ embh, half_t* __restrict__ kvwh,
                          half_t* __restrict__ Wkh, half_t* __restrict__ Wvh){
  int gid = blockIdx.x*256 + threadIdx.x;
  if (gid < CV0){ embh[gid] = (half_t)emb[gid]; return; }
  if (gid < CV1){ int i = gid - CV0; kvwh[i] = (half_t)kv_w[i]; return; }
  if (gid < CV2){ int i = gid - CV1; int r = i >> 9, c = i & 511;
                  Wkh[i] = (half_t)in_proj_w[(size_t)r*1536 + 512 + c]; return; }
  if (gid < CV3){ int i = gid - CV2; int r = i >> 9, c = i & 511;
                  Wvh[i] = (half_t)in_proj_w[(size_t)r*1536 + 1024 + c]; return; }
}

// Wsynh[1536][2048]: rows 0..511 from Wf2, rows 512..1535 from syn_w (same flat index)
__global__ void k_convsyn(const float* __restrict__ Wf2, const float* __restrict__ syn_w,
                          half_t* __restrict__ Wsynh){
  int gid = blockIdx.x*256 + threadIdx.x;
  if (gid >= 1536*2048) return;
  Wsynh[gid] = (half_t)((gid < 512*2048) ? Wf2[gid] : syn_w[gid]);
}

__global__ void k_embed_h(const int* __restrict__ x, const half_t* __restrict__ embh,
                          half_t* __restrict__ out){
  int gid = blockIdx.x*256 + threadIdx.x;
  if (gid >= ROWS*(TED/8)) return;
  int row = gid >> 4, c0 = (gid & 15)*8;
  *(half8*)(out + (size_t)row*TED + c0) = *(const half8*)(embh + (size_t)x[row]*TED + c0);
}

__global__ void k_init_pairs(int n, int npairs, const float* __restrict__ decay,
                             int2* __restrict__ pairs, float* __restrict__ rv){
  int p = blockIdx.x*256 + threadIdx.x;
  if (p >= npairs) return;
  double nn = (double)n;
  double disc = (2.0*nn+1.0)*(2.0*nn+1.0) - 8.0*(double)p;
  int i = (int)floor(((2.0*nn+1.0) - sqrt(disc))*0.5);
  if (i < 0) i = 0; if (i > n-1) i = n-1;
  while (i+1 < n && triu_off(n, i+1) <= (long)p) i++;
  while (i > 0 && triu_off(n, i) > (long)p) i--;
  int j = i + (int)((long)p - triu_off(n, i));
  pairs[p] = make_int2(i, j);
  float dc = decay[p]; dc = fminf(fmaxf(dc, 0.f), 15.f);
  rv[p] = expf(-dc);
}

// act init + Ah16 tail seed (act for t=0 is start_act broadcast)
__global__ void k_init_act(const float* __restrict__ sa, float* __restrict__ act,
                           half_t* __restrict__ Ah16){
  int gid = blockIdx.x*256 + threadIdx.x;
  if (gid >= BB*D_MODEL) return;
  int b = gid >> 10, d = gid & 1023;
  float v = sa[d];
  act[gid] = v;
  Ah16[(size_t)b*1536 + 512 + d] = (half_t)v;
}

__global__ void k_zero(float* __restrict__ p, int n){
  int gid = blockIdx.x*256 + threadIdx.x;
  if (gid < n) p[gid] = 0.f;
}

__global__ void k_init_trace(const float* __restrict__ st, float* __restrict__ trace){
  int gid = blockIdx.x*256 + threadIdx.x;
  if (gid >= BB*MEMN*D_MODEL) return;
  int d = gid & 1023;
  int m = (gid >> 10) % MEMN;
  int b = (gid >> 10) / MEMN;
  trace[(size_t)b*TRACE_SLOTS*D_MODEL + (size_t)m*D_MODEL + d] = st[d*MEMN + m];
}

__global__ void k_init_ao(const float* __restrict__ sa, const int2* __restrict__ pairs,
                          float* __restrict__ ao){
  int p = blockIdx.x*256 + threadIdx.x;
  if (p >= SO_SZ) return;
  int b = blockIdx.y;
  int2 ij = pairs[p];
  ao[(size_t)b*SO_SZ + p] = sa[ij.x]*sa[ij.y];
}

// out_w (fp32 [32896][1968]) -> Wh (fp16 [32896][1984], zero-padded). One thread = 16 halfs.
__global__ void k_convw(const float* __restrict__ W, half_t* __restrict__ Wh){
  int gid = blockIdx.x*256 + threadIdx.x;
  if (gid >= SO_SZ*WCHUNKS) return;
  int row = gid / WCHUNKS, ch = gid - row*WCHUNKS;
  int c0 = ch*16;
  half_t* dst = Wh + (size_t)row*WHLD + c0;
  if (ch < 123){
    const float4* src = (const float4*)(W + (size_t)row*NCLS + c0);
    float4 f0 = src[0], f1 = src[1], f2 = src[2], f3 = src[3];
    half8 h0, h1;
    h0[0]=(half_t)f0.x; h0[1]=(half_t)f0.y; h0[2]=(half_t)f0.z; h0[3]=(half_t)f0.w;
    h0[4]=(half_t)f1.x; h0[5]=(half_t)f1.y; h0[6]=(half_t)f1.z; h0[7]=(half_t)f1.w;
    h1[0]=(half_t)f2.x; h1[1]=(half_t)f2.y; h1[2]=(half_t)f2.z; h1[3]=(half_t)f2.w;
    h1[4]=(half_t)f3.x; h1[5]=(half_t)f3.y; h1[6]=(half_t)f3.z; h1[7]=(half_t)f3.w;
    *(half8*)dst = h0; *(half8*)(dst+8) = h1;
  } else {
    half8 zz;
#pragma unroll
    for (int j = 0; j < 8; j++) zz[j] = (half_t)0.f;
    *(half8*)dst = zz; *(half8*)(dst+8) = zz;
  }
}

// out[col] = sum_k vec[k]*W[k*ldw+col] + (addb?addb[col]:0)
__global__ void k_colsum(const float* __restrict__ vec, const float* __restrict__ W,
                         int ldw, const float* __restrict__ addb,
                         float* __restrict__ out, int N, int K){
  int col = blockIdx.x*256 + threadIdx.x;
  if (col >= N) return;
  float s = addb ? addb[col] : 0.f;
  for (int k = 0; k < K; k++) s = fmaf(vec[k], W[(size_t)k*ldw + col], s);
  out[col] = s;
}

// ---- generic fp32 GEMM (setup only). REQUIRES K % 32 == 0 ----
template<int MB>
__global__ void k_gemm(const float* __restrict__ A, int lda,
                       const float* __restrict__ W, int ldw, int wrow0, int wcol0,
                       const float* __restrict__ bias,
                       float* __restrict__ C, int ldc, int N, int K){
  constexpr int KC = 32;
  const int tid = threadIdx.x;
  const int col = blockIdx.x*256 + tid;
  const int row0 = blockIdx.y*MB;
  __shared__ float As[MB][KC];
  float acc[MB];
#pragma unroll
  for (int r = 0; r < MB; r++) acc[r] = 0.f;
  for (int kk = 0; kk < K; kk += KC){
    __syncthreads();
    for (int idx = tid; idx < MB*KC; idx += 256){
      int r = idx / KC, k = idx % KC;
      As[r][k] = A[(size_t)(row0+r)*lda + kk + k];
    }
    __syncthreads();
#pragma unroll
    for (int k = 0; k < KC; k++){
      float w = W[(size_t)(wrow0+kk+k)*ldw + wcol0 + col];
#pragma unroll
      for (int r = 0; r < MB; r++) acc[r] = fmaf(As[r][k], w, acc[r]);
    }
  }
#pragma unroll
  for (int r = 0; r < MB; r++){
    size_t o = (size_t)(row0+r)*ldc + col;
    C[o] = acc[r] + (bias ? bias[col] : 0.f);
  }
}

// ---- fp16 MFMA projection GEMM: C[M,512] = Ah[M][ldah] @ Wh16[ldah][512] + bias ----
__global__ __launch_bounds__(256)
void k_pgemm(const half_t* __restrict__ Ah, int ldah,
             const half_t* __restrict__ Wh16, const float* __restrict__ bias,
             float* __restrict__ C, int ksteps){
  __shared__ half_t As[2][128*64];
  __shared__ half_t Ws[2][64*66];
  const int tid = threadIdx.x;
  const int nb0 = blockIdx.x * 64;
  const int row0 = blockIdx.y * 128;
  const int l = tid & 63, wv = tid >> 6;
  const int mw = (wv >> 1) * 64, nw = (wv & 1) * 32;
  const int c = l & 15, g = l >> 4;

  f32x4v acc[4][2];
#pragma unroll
  for (int i = 0; i < 4; i++)
#pragma unroll
    for (int j2 = 0; j2 < 2; j2++)
#pragma unroll
      for (int r = 0; r < 4; r++) acc[i][j2][r] = 0.f;

  auto stage = [&](int s, int buf){
#pragma unroll
    for (int it = 0; it < 4; it++){
      int ch = tid + it*256;
      int m = ch >> 3, kl = (ch & 7)*8;
      half8 v = *(const half8*)(Ah + (size_t)(row0+m)*ldah + s*64 + kl);
      *(half8*)((char*)(&As[buf][0]) + swzA(ch*16)) = v;
    }
    {
      int k = tid >> 2, cs = (tid & 3) * 16;
      const half_t* wr = Wh16 + (size_t)(s*64 + k) * D_IN + nb0 + cs;
      char* dst = (char*)(&Ws[buf][0]) + (size_t)(k*66 + cs) * 2;
      union { half8 v; unsigned int u[4]; } p0, p1;
      p0.v = *(const half8*)wr; p1.v = *(const half8*)(wr + 8);
#pragma unroll
      for (int q = 0; q < 4; q++){
        ((unsigned int*)dst)[q]        = p0.u[q];
        ((unsigned int*)(dst + 16))[q] = p1.u[q];
      }
    }
  };

  stage(0, 0);
  __syncthreads();
  for (int s = 0; s < ksteps; s++){
    int buf = s & 1;
    if (s + 1 < ksteps) stage(s+1, buf^1);
#pragma unroll
    for (int h = 0; h < 2; h++){
      half8 a8[4];
#pragma unroll
      for (int mb = 0; mb < 4; mb++)
        a8[mb] = *(const half8*)((const char*)(&As[buf][0]) +
                   swzA(((mw + mb*16 + c)*64 + h*32 + g*8)*2));
#pragma unroll
      for (int nb = 0; nb < 2; nb++){
        half8 b8;
        const half_t* wp = &Ws[buf][(h*32 + g*8)*66 + nw + nb*16 + c];
#pragma unroll
        for (int j = 0; j < 8; j++) b8[j] = wp[j*66];
#pragma unroll
        for (int mb = 0; mb < 4; mb++)
          acc[mb][nb] = __builtin_amdgcn_mfma_f32_16x16x32_f16(a8[mb], b8, acc[mb][nb], 0, 0, 0);
      }
    }
    __syncthreads();
  }
#pragma unroll
  for (int mb = 0; mb < 4; mb++)
#pragma unroll
    for (int nb = 0; nb < 2; nb++){
      int m = mw + mb*16 + g*4;
      int n = nb0 + nw + nb*16 + c;
      float bv = bias[n];
#pragma unroll
      for (int r = 0; r < 4; r++)
        C[(size_t)(row0 + m + r) * D_IN + n] = acc[mb][nb][r] + bv;
    }
}

// ---- syn fp16 MFMA GEMM ----
__global__ __launch_bounds__(256)
void k_syn16(const half_t* __restrict__ Ah, const half_t* __restrict__ Wh16,
             float* __restrict__ outp){
  __shared__ half_t As[2][128*64];
  __shared__ half_t Ws[2][64*66];
  const int tid = threadIdx.x;
  const int nb0 = blockIdx.x * 64;
  const int z = blockIdx.y;
  const int l = tid & 63, wv = tid >> 6;
  const int mw = (wv >> 1) * 64, nw = (wv & 1) * 32;
  const int c = l & 15, g = l >> 4;
  const int kbase = z * 256;

  f32x4v acc[4][2];
#pragma unroll
  for (int i = 0; i < 4; i++)
#pragma unroll
    for (int j2 = 0; j2 < 2; j2++)
#pragma unroll
      for (int r = 0; r < 4; r++) acc[i][j2][r] = 0.f;

  auto stage = [&](int s, int buf){
#pragma unroll
    for (int it = 0; it < 4; it++){
      int ch = tid + it*256;
      int m = ch >> 3, kl = (ch & 7)*8;
      half8 v = *(const half8*)(Ah + (size_t)m*1536 + kbase + s*64 + kl);
      *(half8*)((char*)(&As[buf][0]) + swzA(ch*16)) = v;
    }
    {
      int k = tid >> 2, cs = (tid & 3) * 16;
      const half_t* wr = Wh16 + (size_t)(kbase + s*64 + k) * 2048 + nb0 + cs;
      char* dst = (char*)(&Ws[buf][0]) + (size_t)(k*66 + cs) * 2;
      union { half8 v; unsigned int u[4]; } p0, p1;
      p0.v = *(const half8*)wr; p1.v = *(const half8*)(wr + 8);
#pragma unroll
      for (int q = 0; q < 4; q++){
        ((unsigned int*)dst)[q]        = p0.u[q];
        ((unsigned int*)(dst + 16))[q] = p1.u[q];
      }
    }
  };

  stage(0, 0);
  __syncthreads();
  for (int s = 0; s < 4; s++){
    int buf = s & 1;
    if (s + 1 < 4) stage(s+1, buf^1);
#pragma unroll
    for (int h = 0; h < 2; h++){
      half8 a8[4];
#pragma unroll
      for (int mb = 0; mb < 4; mb++)
        a8[mb] = *(const half8*)((const char*)(&As[buf][0]) +
                   swzA(((mw + mb*16 + c)*64 + h*32 + g*8)*2));
#pragma unroll
      for (int nb = 0; nb < 2; nb++){
        half8 b8;
        const half_t* wp = &Ws[buf][(h*32 + g*8)*66 + nw + nb*16 + c];
#pragma unroll
        for (int j = 0; j < 8; j++) b8[j] = wp[j*66];
#pragma unroll
        for (int mb = 0; mb < 4; mb++)
          acc[mb][nb] = __builtin_amdgcn_mfma_f32_16x16x32_f16(a8[mb], b8, acc[mb][nb], 0, 0, 0);
      }
    }
    __syncthreads();
  }
  float* pz = outp + (size_t)z * BB * 2048;
#pragma unroll
  for (int mb = 0; mb < 4; mb++)
#pragma unroll
    for (int nb = 0; nb < 2; nb++){
      int m = mw + mb*16 + g*4;
      int n = nb0 + nw + nb*16 + c;
#pragma unroll
      for (int r = 0; r < 4; r++)
        pz[(size_t)(m + r) * 2048 + n] = acc[mb][nb][r];
    }
}

// ---- fused syncA + q-GEMM (4-way K-split, fp16 W):
// computes sync_a inline from a_a ping-pong; colblock 0 writes updated a_a.
__global__ void k_gemmq(const float* __restrict__ act,
                        const float* __restrict__ r_a, const int2* __restrict__ pairsA,
                        const float* __restrict__ aaIn, float* __restrict__ aaOut,
                        const half_t* __restrict__ Wh, float* __restrict__ qpart, int t){
  constexpr int KC = 32;
  const int tid = threadIdx.x;
  const int col = blockIdx.x*256 + tid;        // N=512, grid.x=2
  const int row0 = blockIdx.y*4;               // M=128, grid.y=32
  const int z = blockIdx.z;                    // 4 splits
  const int kstart = z*544;
  const int kend = min(SA_SZ, kstart + 544);   // all chunk counts %32==0
  const bool writer = (blockIdx.x == 0);
  __shared__ float As[4][KC];
  float acc[4] = {0.f,0.f,0.f,0.f};
  for (int kk = kstart; kk < kend; kk += KC){
    __syncthreads();
    if (tid < 4*KC){
      int r = tid >> 5, k = tid & 31;
      int p = kk + k;
      int b = row0 + r;
      int2 ij = pairsA[p];
      const float* ab = act + (size_t)b*D_MODEL + (D_MODEL - N_SA);
      float rv = r_a[p];
      size_t idx = (size_t)b*SA_SZ + p;
      float a = fmaf(rv, aaIn[idx], ab[ij.x]*ab[ij.y]);
      if (writer) aaOut[idx] = a;
      float bb = 0.f;
      for (int i = 0; i <= t; i++) bb = fmaf(rv, bb, 1.f);
      As[r][k] = a / sqrtf(bb);
    }
    __syncthreads();
#pragma unroll
    for (int k = 0; k < KC; k++){
      float w = (float)Wh[(size_t)(kk+k)*D_IN + col];
#pragma unroll
      for (int r = 0; r < 4; r++) acc[r] = fmaf(As[r][k], w, acc[r]);
    }
  }
#pragma unroll
  for (int r = 0; r < 4; r++)
    qpart[(size_t)z*BB*D_IN + (size_t)(row0+r)*D_IN + col] = acc[r];
}

// ---- fused syn GEMM fp32 fallback, 6-way K-split ----
__global__ void k_gemm2srcZ(const float* __restrict__ A1, const float* __restrict__ A2,
                            const float* __restrict__ W1, const float* __restrict__ W2,
                            float* __restrict__ outp){
  constexpr int MB = 8, KC = 32;
  const int tid = threadIdx.x;
  const int col = blockIdx.x*256 + tid;
  const int row0 = blockIdx.y*MB;
  const int z = blockIdx.z;
  __shared__ float As[MB][KC];
  float acc[MB];
#pragma unroll
  for (int r = 0; r < MB; r++) acc[r] = 0.f;
  for (int kk = z*256; kk < z*256 + 256; kk += KC){
    __syncthreads();
    for (int idx = tid; idx < MB*KC; idx += 256){
      int r = idx / KC, k = idx % KC;
      int kg = kk + k;
      As[r][k] = (kg < D_IN) ? A1[(size_t)(row0+r)*D_IN + kg]
                             : A2[(size_t)(row0+r)*D_MODEL + kg - D_IN];
    }
    __syncthreads();
    const float* Wp = (kk < D_IN) ? W1 : W2;
#pragma unroll
    for (int k = 0; k < KC; k++){
      float w = Wp[(size_t)(kk+k)*2048 + col];
#pragma unroll
      for (int r = 0; r < MB; r++) acc[r] = fmaf(As[r][k], w, acc[r]);
    }
  }
#pragma unroll
  for (int r = 0; r < MB; r++)
    outp[(size_t)z*BB*2048 + (size_t)(row0+r)*2048 + col] = acc[r];
}

// ---------------- LayerNorm (block per row), fp32 in -> fp16 out ----------------
__global__ void k_ln_h(const float* __restrict__ X, const float* __restrict__ g,
                       const float* __restrict__ bta, half_t* __restrict__ Y, int D){
  const int row = blockIdx.x, tid = threadIdx.x;
  __shared__ float red[256];
  const float* xr = X + (size_t)row*D;
  float s = 0.f;
  for (int c = tid; c < D; c += 256) s += xr[c];
  float mean = bsum256(s, red) / (float)D;
  float s2 = 0.f;
  for (int c = tid; c < D; c += 256){ float d = xr[c]-mean; s2 += d*d; }
  float var = bsum256(s2, red) / (float)D;
  float inv = 1.f / sqrtf(var + 1e-5f);
  half_t* yr = Y + (size_t)row*D;
  for (int c = tid; c < D; c += 256) yr[c] = (half_t)((xr[c]-mean)*inv*g[c] + bta[c]);
}

// ---- sum 6 synpart + bias2 -> GLU -> LN -> trace slot ----
__global__ void k_glu_ln(const float* __restrict__ synpart, const float* __restrict__ bias2,
                         const float* __restrict__ g, const float* __restrict__ bta,
                         float* __restrict__ traceSlot){
  const int b = blockIdx.x, tid = threadIdx.x;
  __shared__ float vals[D_MODEL];
  __shared__ float red[256];
  for (int c = tid; c < 1024; c += 256){
    float a = bias2[c], gg = bias2[c+1024];
#pragma unroll
    for (int z = 0; z < SYNZ; z++){
      const float* sp = synpart + (size_t)z*BB*2048 + (size_t)b*2048;
      a  += sp[c];
      gg += sp[c+1024];
    }
    vals[c] = a * sigmoidf_(gg);
  }
  __syncthreads();
  float s = 0.f;
  for (int c = tid; c < 1024; c += 256) s += vals[c];
  float mean = bsum256(s, red) * (1.f/1024.f);
  float s2 = 0.f;
  for (int c = tid; c < 1024; c += 256){ float d = vals[c]-mean; s2 += d*d; }
  float var = bsum256(s2, red) * (1.f/1024.f);
  float inv = 1.f / sqrtf(var + 1e-5f);
  float* out = traceSlot + (size_t)b*(TRACE_SLOTS*D_MODEL);
  for (int c = tid; c < 1024; c += 256) out[c] = (vals[c]-mean)*inv*g[c] + bta[c];
}

// ---------------- attention: writes obuf (fp32) AND Ah16 head (fp16) ----------------
__global__ void k_attn(const float* __restrict__ qpart, const float* __restrict__ bqf,
                       const float* __restrict__ Km, const float* __restrict__ Vm,
                       float* __restrict__ o, half_t* __restrict__ Ah16){
  const int bh = blockIdx.x, b = bh >> 3, h = bh & 7;
  const int tid = threadIdx.x;
  __shared__ float qs[DHH];
  __shared__ float attn[SS];
  __shared__ float red[128];
  if (tid < DHH){
    int d = h*DHH + tid;
    float qv = bqf[d];
#pragma unroll
    for (int z = 0; z < 4; z++) qv += qpart[(size_t)z*BB*D_IN + (size_t)b*D_IN + d];
    qs[tid] = qv;
  }
  __syncthreads();
  float sc = -1e30f;
  if (tid < SS){
    const float* kp = Km + ((size_t)(b*SS+tid)*HEADS + h)*DHH;
    float d = 0.f;
#pragma unroll
    for (int i = 0; i < DHH; i++) d = fmaf(qs[i], kp[i], d);
    sc = d * 0.125f;
  }
  red[tid] = sc; __syncthreads();
  for (int s2 = 64; s2 > 0; s2 >>= 1){ if (tid < s2) red[tid] = fmaxf(red[tid], red[tid+s2]); __syncthreads(); }
  float m = red[0]; __syncthreads();
  float e = (tid < SS) ? expf(sc - m) : 0.f;
  red[tid] = e; __syncthreads();
  for (int s2 = 64; s2 > 0; s2 >>= 1){ if (tid < s2) red[tid] += red[tid+s2]; __syncthreads(); }
  float inv = 1.f / red[0]; __syncthreads();
  if (tid < SS) attn[tid] = e * inv;
  __syncthreads();
  if (tid < DHH){
    const float* vp = Vm + ((size_t)(b*SS)*HEADS + h)*DHH + tid;
    float acc = 0.f;
    for (int s2 = 0; s2 < SS; s2++) acc = fmaf(attn[s2], vp[(size_t)s2*D_IN], acc);
    int d = h*DHH + tid;
    o[(size_t)b*D_IN + d] = acc;
    Ah16[(size_t)b*1536 + d] = (half_t)acc;
  }
}

// ---- neuron update; writes act (fp32) AND Ah16 tail (fp16) for next iter ----
__global__ void k_neuron(const float* __restrict__ trace,
                         const float* __restrict__ tp1w, const float* __restrict__ tp1b,
                         const float* __restrict__ tp2w, const float* __restrict__ tp2b,
                         float* __restrict__ act, half_t* __restrict__ Ah16, int t){
  int gid = blockIdx.x*256 + threadIdx.x;
  if (gid >= BB*D_MODEL) return;
  int b = gid >> 10, d = gid & 1023;
  const float* tr = trace + (size_t)b*(TRACE_SLOTS*D_MODEL) + (size_t)(t+1)*D_MODEL + d;
  float trv[MEMN];
#pragma unroll
  for (int m = 0; m < MEMN; m++) trv[m] = tr[(size_t)m*D_MODEL];
  float o0 = tp2b[d*2+0], o1 = tp2b[d*2+1];
#pragma unroll
  for (int j = 0; j < 16; j++){
    const float* wpj = tp1w + (size_t)j*1024 + d;
    const float* wpg = tp1w + (size_t)(j+16)*1024 + d;
    float hj = tp1b[d*32 + j];
    float hg = tp1b[d*32 + j + 16];
#pragma unroll
    for (int m = 0; m < MEMN; m++){
      float tv = trv[m];
      hj = fmaf(tv, wpj[(size_t)m*32*1024], hj);
      hg = fmaf(tv, wpg[(size_t)m*32*1024], hg);
    }
    float hgv = hj * sigmoidf_(hg);
    o0 = fmaf(hgv, tp2w[(size_t)(j*2+0)*1024 + d], o0);
    o1 = fmaf(hgv, tp2w[(size_t)(j*2+1)*1024 + d], o1);
  }
  float v = o0 * sigmoidf_(o1);
  act[gid] = v;
  Ah16[(size_t)b*1536 + 512 + d] = (half_t)v;
}

// ---------------- syncO ----------------
__global__ void k_syncO(const float* __restrict__ act, const float* __restrict__ rv,
                        const int2* __restrict__ pairs, float* __restrict__ ao,
                        half_t* __restrict__ syncv, int t){
  int p = blockIdx.x*256 + threadIdx.x;
  if (p >= SO_SZ) return;
  int b = blockIdx.y;
  int2 ij = pairs[p];
  const float* ab = act + (size_t)b*D_MODEL;
  float r = rv[p];
  size_t idx = (size_t)b*SO_SZ + p;
  float a = fmaf(r, ao[idx], ab[ij.x]*ab[ij.y]);
  ao[idx] = a;
  float bb = 1.f;
  for (int i = 0; i <= t; i++) bb = fmaf(r, bb, 1.f);
  syncv[idx] = (half_t)(a / sqrtf(bb));
}

// ---------------- big GEMM, fp16-W path ----------------
__global__ __launch_bounds__(256)
void k_bigemm2h(const half_t* __restrict__ Ah, const half_t* __restrict__ Wh,
                float* __restrict__ part){
  __shared__ half_t As[2][128*64];
  __shared__ half_t Ws[2][64*66];
  const int tid = threadIdx.x;
  const int z = blockIdx.y;
  const int nb0 = blockIdx.x * BGN;
  const int l = tid & 63, wv = tid >> 6;
  const int mw = (wv >> 1) * 64, nw = (wv & 1) * 32;
  const int c = l & 15, g = l >> 4;
  const int k0 = z * BGKLEN;

  f32x4v acc[4][2];
#pragma unroll
  for (int i = 0; i < 4; i++)
#pragma unroll
    for (int j2 = 0; j2 < 2; j2++)
#pragma unroll
      for (int r = 0; r < 4; r++) acc[i][j2][r] = 0.f;

  auto stage = [&](int s, int buf){
    const int kv = min(64, BGKLEN - s*64);
#pragma unroll
    for (int it = 0; it < 4; it++){
      int ch = tid + it*256;
      int m = ch >> 3, kg = ch & 7, kl = kg*8;
      half8 v;
      if (kl < kv) v = *(const half8*)(Ah + (size_t)m*SO_SZ + k0 + s*64 + kl);
      else {
#pragma unroll
        for (int j = 0; j < 8; j++) v[j] = (half_t)0.f;
      }
      *(half8*)((char*)(&As[buf][0]) + swzA(ch*16)) = v;
    }
    {
      int k = tid >> 2, cs = (tid & 3) * 16;
      const half_t* wr = Wh + (size_t)(k0 + s*64 + k) * WHLD + nb0 + cs;
      char* dst = (char*)(&Ws[buf][0]) + (size_t)(k*66 + cs) * 2;
      union { half8 v; unsigned int u[4]; } p0, p1;
      if (k < kv){ p0.v = *(const half8*)wr; p1.v = *(const half8*)(wr + 8); }
      else {
#pragma unroll
        for (int j = 0; j < 8; j++){ p0.v[j] = (half_t)0.f; p1.v[j] = (half_t)0.f; }
      }
#pragma unroll
      for (int q = 0; q < 4; q++){
        ((unsigned int*)dst)[q]        = p0.u[q];
        ((unsigned int*)(dst + 16))[q] = p1.u[q];
      }
    }
  };

  stage(0, 0);
  __syncthreads();
  for (int s = 0; s < BGSTEPS; s++){
    int buf = s & 1;
    if (s + 1 < BGSTEPS) stage(s+1, buf^1);
#pragma unroll
    for (int h = 0; h < 2; h++){
      half8 a8[4];
#pragma unroll
      for (int mb = 0; mb < 4; mb++)
        a8[mb] = *(const half8*)((const char*)(&As[buf][0]) +
                   swzA(((mw + mb*16 + c)*64 + h*32 + g*8)*2));
#pragma unroll
      for (int nb = 0; nb < 2; nb++){
        half8 b8;
        const half_t* wp = &Ws[buf][(h*32 + g*8)*66 + nw + nb*16 + c];
#pragma unroll
        for (int j = 0; j < 8; j++) b8[j] = wp[j*66];
#pragma unroll
        for (int mb = 0; mb < 4; mb++)
          acc[mb][nb] = __builtin_amdgcn_mfma_f32_16x16x32_f16(a8[mb], b8, acc[mb][nb], 0, 0, 0);
      }
    }
    __syncthreads();
  }
  float* pz = part + (size_t)z * 128 * NPART;
#pragma unroll
  for (int mb = 0; mb < 4; mb++)
#pragma unroll
    for (int nb = 0; nb < 2; nb++){
      int m = mw + mb*16 + g*4;
      int n = nb0 + nw + nb*16 + c;
#pragma unroll
      for (int r = 0; r < 4; r++)
        pz[(size_t)(m + r) * NPART + n] = acc[mb][nb][r];
    }
}

// ---------------- combine partials + bias, write preds + certainties ----------------
__global__ void k_output(const float* __restrict__ part, const float* __restrict__ outb,
                         float* __restrict__ dout, int t){
  const int b = blockIdx.x, tid = threadIdx.x;
  __shared__ float pred[NCLS];
  __shared__ float red[256];
  float lmax = -1e30f;
  for (int c = tid; c < NCLS; c += 256){
    float s = outb[c];
    const float* pp = part + (size_t)b*NPART + c;
#pragma unroll
    for (int z = 0; z < BGKS; z++) s += pp[(size_t)z*128*NPART];
    pred[c] = s;
    dout[((size_t)b*NCLS + c)*NITER + t] = s;
    lmax = fmaxf(lmax, s);
  }
  red[tid] = lmax; __syncthreads();
  for (int s2 = 128; s2 > 0; s2 >>= 1){ if (tid < s2) red[tid] = fmaxf(red[tid], red[tid+s2]); __syncthreads(); }
  float m = red[0]; __syncthreads();
  float se = 0.f;
  for (int c = tid; c < NCLS; c += 256) se += expf(pred[c]-m);
  float Z = bsum256(se, red);
  float logZ = m + logf(Z);
  float ent = 0.f;
  for (int c = tid; c < NCLS; c += 256){ float lp = pred[c]-logZ; ent += expf(lp)*lp; }
  float E = bsum256(ent, red);
  if (tid == 0){
    float ne = -E * (1.f/logf((float)NCLS));
    float* cp = dout + (size_t)BB*NCLS*NITER + (size_t)b*2*NITER + t;
    cp[0]     = ne;
    cp[NITER] = 1.f - ne;
  }
}

// ---------------- launch ----------------
extern "C" void kernel_launch(void* const* d_in, const int* in_sizes, int n_in,
                              void* d_out, int out_size, void* d_ws, size_t ws_size,
                              hipStream_t stream){
  const int*   x           = (const int*)  d_in[0];
  const float* emb         = (const float*)d_in[1];
  const float* kv_w        = (const float*)d_in[2];
  const float* kv_b        = (const float*)d_in[3];
  const float* kv_ln_g     = (const float*)d_in[4];
  const float* kv_ln_b     = (const float*)d_in[5];
  const float* q_w         = (const float*)d_in[6];
  const float* q_b         = (const float*)d_in[7];
  const float* in_proj_w   = (const float*)d_in[8];
  const float* in_proj_b   = (const float*)d_in[9];
  const float* out_proj_w  = (const float*)d_in[10];
  const float* out_proj_b  = (const float*)d_in[11];
  const float* syn_w       = (const float*)d_in[12];
  const float* syn_b       = (const float*)d_in[13];
  const float* syn_ln_g    = (const float*)d_in[14];
  const float* syn_ln_b    = (const float*)d_in[15];
  const float* tp1_w       = (const float*)d_in[16];
  const float* tp1_b       = (const float*)d_in[17];
  const float* tp2_w       = (const float*)d_in[18];
  const float* tp2_b       = (const float*)d_in[19];
  const float* start_act   = (const float*)d_in[20];
  const float* start_trace = (const float*)d_in[21];
  const float* decay_action= (const float*)d_in[22];
  const float* decay_out   = (const float*)d_in[23];
  const float* out_w       = (const float*)d_in[24];
  const float* out_b       = (const float*)d_in[25];
  float* dout = (float*)d_out;

  // ---- workspace layout ----
  float* w = (float*)d_ws;
  size_t off = 0;
  auto alloc = [&](size_t n){ n = (n + 3) & ~(size_t)3; float* p = w + off; off += n; return p; };
  float* region0 = alloc((size_t)BGKS*128*NPART);    // setup: embx_h/kvh | iter: synpart+part
  float* region1 = alloc((size_t)ROWS*D_IN);         // setup: kvbuf | iter: a_o
  float* Kmat    = alloc((size_t)ROWS*D_IN);
  float* Vmat    = alloc((size_t)ROWS*D_IN);
  float* trace   = alloc((size_t)BB*TRACE_SLOTS*D_MODEL);
  half_t* sync_oh= (half_t*)alloc((size_t)BB*SO_SZ/2);
  float* a_aP    = alloc((size_t)2*BB*SA_SZ);        // ping-pong a_a state
  float* act     = alloc((size_t)BB*D_MODEL);
  float* qpart   = alloc((size_t)4*BB*D_IN);
  float* obuf    = alloc((size_t)BB*D_IN);
  float* qfw     = alloc((size_t)SA_SZ*D_IN);        // fp32 q_w @ Wq (conversion source)
  float* Wf2     = alloc((size_t)D_IN*2048);
  float* bqf     = alloc(D_IN);
  float* bias2   = alloc(2048);
  float* r_a     = alloc(SA_SZ);
  float* r_o     = alloc(SO_SZ);
  int2*  pairsA  = (int2*)alloc(2*SA_SZ);
  int2*  pairsO  = (int2*)alloc(2*SO_SZ);
  half_t* embh   = (half_t*)alloc((size_t)VOCAB*TED/2);
  half_t* kvwh   = (half_t*)alloc((size_t)TED*D_IN/2);
  half_t* Wkh    = (half_t*)alloc((size_t)D_IN*D_IN/2);
  half_t* Wvh    = (half_t*)alloc((size_t)D_IN*D_IN/2);
  half_t* qfwh   = (half_t*)alloc((size_t)SA_SZ*D_IN/2);
  half_t* Wh     = (half_t*)alloc(((size_t)SO_SZ*WHLD)/2);
  half_t* Ah16   = (half_t*)alloc((size_t)BB*1536/2);
  half_t* Wsynh  = (half_t*)alloc((size_t)1536*2048/2);
  const bool use_syn16 = (off * sizeof(float) <= ws_size);

  half_t* embx_h = (half_t*)region0;
  half_t* kvh    = (half_t*)region0;
  float* part    = region0;
  float* synpart = region0;
  float* kvbuf = region1;
  float* a_o   = region1;

  dim3 blk(256);

  // ---- setup ----
  k_convall<<<(CV3+255)/256, blk, 0, stream>>>(emb, kv_w, in_proj_w, embh, kvwh, Wkh, Wvh);
  k_embed_h<<<(ROWS*(TED/8)+255)/256, blk, 0, stream>>>(x, embh, embx_h);
  k_pgemm<<<dim3(8, ROWS/128), blk, 0, stream>>>(embx_h, TED, kvwh, kv_b, kvbuf, TED/64);
  k_ln_h<<<ROWS, blk, 0, stream>>>(kvbuf, kv_ln_g, kv_ln_b, kvh, D_IN);
  k_pgemm<<<dim3(8, ROWS/128), blk, 0, stream>>>(kvh, D_IN, Wkh, in_proj_b+512,  Kmat, D_IN/64);
  k_pgemm<<<dim3(8, ROWS/128), blk, 0, stream>>>(kvh, D_IN, Wvh, in_proj_b+1024, Vmat, D_IN/64);
  k_gemm<4><<<dim3(2, SA_SZ/4), blk, 0, stream>>>(q_w, D_IN, in_proj_w, 1536, 0, 0, nullptr, qfw, D_IN, D_IN, D_IN);
  k_gemm<4><<<dim3(8, D_IN/4), blk, 0, stream>>>(out_proj_w, D_IN, syn_w, 2048, 0, 0, nullptr, Wf2, 2048, 2048, D_IN);
  k_conv<<<(SA_SZ*D_IN+255)/256, blk, 0, stream>>>(qfw, qfwh, SA_SZ*D_IN);
  k_colsum<<<2, blk, 0, stream>>>(q_b, in_proj_w, 1536, in_proj_b, bqf, D_IN, D_IN);
  k_colsum<<<8, blk, 0, stream>>>(out_proj_b, syn_w, 2048, syn_b, bias2, 2048, D_IN);
  k_convw<<<(SO_SZ*WCHUNKS+255)/256, blk, 0, stream>>>(out_w, Wh);
  if (use_syn16)
    k_convsyn<<<(1536*2048+255)/256, blk, 0, stream>>>(Wf2, syn_w, Wsynh);
  k_init_pairs<<<(SA_SZ+255)/256, blk, 0, stream>>>(N_SA, SA_SZ, decay_action, pairsA, r_a);
  k_init_pairs<<<(SO_SZ+255)/256, blk, 0, stream>>>(N_SO, SO_SZ, decay_out,    pairsO, r_o);
  k_init_act<<<(BB*D_MODEL+255)/256, blk, 0, stream>>>(start_act, act, Ah16);
  k_zero<<<(2*BB*SA_SZ+255)/256, blk, 0, stream>>>(a_aP, 2*BB*SA_SZ);
  k_init_trace<<<(BB*MEMN*D_MODEL+255)/256, blk, 0, stream>>>(start_trace, trace);
  k_init_ao<<<dim3((SO_SZ+255)/256, BB), blk, 0, stream>>>(start_act, pairsO, a_o);

  // ---- 16 recurrent iterations ----
  for (int t = 0; t < NITER; t++){
    float* aaIn  = a_aP + (size_t)(t & 1)*BB*SA_SZ;
    float* aaOut = a_aP + (size_t)((t+1) & 1)*BB*SA_SZ;
    k_gemmq<<<dim3(2, 32, 4), blk, 0, stream>>>(act, r_a, pairsA, aaIn, aaOut, qfwh, qpart, t);
    k_attn<<<BB*HEADS, 128, 0, stream>>>(qpart, bqf, Kmat, Vmat, obuf, Ah16);
    if (use_syn16)
      k_syn16<<<dim3(32, SYNZ), blk, 0, stream>>>(Ah16, Wsynh, synpart);
    else
      k_gemm2srcZ<<<dim3(8, 16, SYNZ), blk, 0, stream>>>(obuf, act, Wf2, syn_w, synpart);
    k_glu_ln<<<BB, blk, 0, stream>>>(synpart, bias2, syn_ln_g, syn_ln_b, trace + (size_t)(MEMN+t)*D_MODEL);
    k_neuron<<<(BB*D_MODEL+255)/256, blk, 0, stream>>>(trace, tp1_w, tp1_b, tp2_w, tp2_b, act, Ah16, t);
    k_syncO<<<dim3((SO_SZ+255)/256, BB), blk, 0, stream>>>(act, r_o, pairsO, a_o, sync_oh, t);
    k_bigemm2h<<<dim3(31, BGKS), blk, 0, stream>>>(sync_oh, Wh, part);
    k_output<<<BB, blk, 0, stream>>>(part, out_b, dout, t);
  }
}

// Round 10
// 2813.075 us; speedup vs baseline: 12.6071x; 1.0641x over previous
//
#include <hip/hip_runtime.h>
#include <math.h>

#define BB 128
#define SS 72
#define NITER 16
#define D_IN 512
#define D_MODEL 1024
#define MEMN 25
#define HEADS 8
#define DHH 64
#define N_SO 256
#define N_SA 64
#define SA_SZ 2080
#define SO_SZ 32896
#define NCLS 1968
#define TED 128
#define VOCAB 32
#define ROWS (BB*SS)
#define TRACE_SLOTS (MEMN + NITER)   /* 41 */
#define QPAD 2176                    /* SA_SZ padded to 17*128 */

/* big-GEMM (sync_o @ out_w) tiling */
#define BGN 64
#define BGKS 16
#define BGKLEN 2056
#define BGSTEPS 33
#define NPART 1984
#define WHLD 1984
#define WCHUNKS 124
#define SYNZ 6

typedef _Float16 half_t;
typedef _Float16 half8 __attribute__((ext_vector_type(8)));
typedef float f32x4v __attribute__((ext_vector_type(4)));

__device__ __forceinline__ float sigmoidf_(float x){ return 1.f/(1.f+expf(-x)); }

__device__ __forceinline__ float bsum256(float v, float* red){
  int tid = threadIdx.x; red[tid] = v; __syncthreads();
#pragma unroll
  for (int s = 128; s > 0; s >>= 1){ if (tid < s) red[tid] += red[tid+s]; __syncthreads(); }
  float r = red[0]; __syncthreads(); return r;
}

__device__ __forceinline__ long triu_off(int n, int i){
  return (long)i*n - ((long)i*(i-1))/2;
}

__device__ __forceinline__ int swzA(int b){ return b ^ (((b>>9)&1)<<5); }

// ---------------- setup kernels ----------------
__global__ void k_conv(const float* __restrict__ src, half_t* __restrict__ dst, int n){
  int gid = blockIdx.x*256 + threadIdx.x;
  if (gid < n) dst[gid] = (half_t)src[gid];
}

// merged fp32->fp16 weight conversions
#define CV0 (VOCAB*TED)              /* emb */
#define CV1 (CV0 + TED*D_IN)         /* kv_w */
#define CV2 (CV1 + D_IN*D_IN)        /* Wk slice */
#define CV3 (CV2 + D_IN*D_IN)        /* Wv slice */
#define CV4 (CV3 + D_IN*D_IN)        /* Wq slice */
#define CV5 (CV4 + D_IN*D_IN)        /* out_proj_w */
#define CV6 (CV5 + D_IN*2048)        /* syn_w top (rows 0..511) */
#define CV7 (CV6 + QPAD*D_IN)        /* q_w zero-padded to 2176 rows */
__global__ void k_convall(const float* __restrict__ emb, const float* __restrict__ kv_w,
                          const float* __restrict__ in_proj_w,
                          const float* __restrict__ out_proj_w,
                          const float* __restrict__ syn_w, const float* __restrict__ q_w,
                          half_t* __restrict__ embh, half_t* __restrict__ kvwh,
                          half_t* __restrict__ Wkh, half_t* __restrict__ Wvh,
                          half_t* __restrict__ Wqh, half_t* __restrict__ oph,
                          half_t* __restrict__ synth, half_t* __restrict__ qwh){
  int gid = blockIdx.x*256 + threadIdx.x;
  if (gid < CV0){ embh[gid] = (half_t)emb[gid]; return; }
  if (gid < CV1){ int i = gid - CV0; kvwh[i] = (half_t)kv_w[i]; return; }
  if (gid < CV2){ int i = gid - CV1; int r = i >> 9, c = i & 511;
                  Wkh[i] = (half_t)in_proj_w[(size_t)r*1536 + 512 + c]; return; }
  if (gid < CV3){ int i = gid - CV2; int r = i >> 9, c = i & 511;
                  Wvh[i] = (half_t)in_proj_w[(size_t)r*1536 + 1024 + c]; return; }
  if (gid < CV4){ int i = gid - CV3; int r = i >> 9, c = i & 511;
                  Wqh[i] = (half_t)in_proj_w[(size_t)r*1536 + c]; return; }
  if (gid < CV5){ int i = gid - CV4; oph[i] = (half_t)out_proj_w[i]; return; }
  if (gid < CV6){ int i = gid - CV5; synth[i] = (half_t)syn_w[i]; return; }
  if (gid < CV7){ int i = gid - CV6; int r = i >> 9;
                  qwh[i] = (r < SA_SZ) ? (half_t)q_w[i] : (half_t)0.f; return; }
}

// Wsynh[1536][2048]: rows 0..511 from Wf2, rows 512..1535 from syn_w (same flat index)
__global__ void k_convsyn(const float* __restrict__ Wf2, const float* __restrict__ syn_w,
                          half_t* __restrict__ Wsynh){
  int gid = blockIdx.x*256 + threadIdx.x;
  if (gid >= 1536*2048) return;
  Wsynh[gid] = (half_t)((gid < 512*2048) ? Wf2[gid] : syn_w[gid]);
}

__global__ void k_embed_h(const int* __restrict__ x, const half_t* __restrict__ embh,
                          half_t* __restrict__ out){
  int gid = blockIdx.x*256 + threadIdx.x;
  if (gid >= ROWS*(TED/8)) return;
  int row = gid >> 4, c0 = (gid & 15)*8;
  *(half8*)(out + (size_t)row*TED + c0) = *(const half8*)(embh + (size_t)x[row]*TED + c0);
}

__global__ void k_init_pairs(int n, int npairs, const float* __restrict__ decay,
                             int2* __restrict__ pairs, float* __restrict__ rv){
  int p = blockIdx.x*256 + threadIdx.x;
  if (p >= npairs) return;
  double nn = (double)n;
  double disc = (2.0*nn+1.0)*(2.0*nn+1.0) - 8.0*(double)p;
  int i = (int)floor(((2.0*nn+1.0) - sqrt(disc))*0.5);
  if (i < 0) i = 0; if (i > n-1) i = n-1;
  while (i+1 < n && triu_off(n, i+1) <= (long)p) i++;
  while (i > 0 && triu_off(n, i) > (long)p) i--;
  int j = i + (int)((long)p - triu_off(n, i));
  pairs[p] = make_int2(i, j);
  float dc = decay[p]; dc = fminf(fmaxf(dc, 0.f), 15.f);
  rv[p] = expf(-dc);
}

__global__ void k_init_act(const float* __restrict__ sa, float* __restrict__ act,
                           half_t* __restrict__ Ah16){
  int gid = blockIdx.x*256 + threadIdx.x;
  if (gid >= BB*D_MODEL) return;
  int b = gid >> 10, d = gid & 1023;
  float v = sa[d];
  act[gid] = v;
  Ah16[(size_t)b*1536 + 512 + d] = (half_t)v;
}

__global__ void k_zero(float* __restrict__ p, int n){
  int gid = blockIdx.x*256 + threadIdx.x;
  if (gid < n) p[gid] = 0.f;
}

__global__ void k_init_trace(const float* __restrict__ st, float* __restrict__ trace){
  int gid = blockIdx.x*256 + threadIdx.x;
  if (gid >= BB*MEMN*D_MODEL) return;
  int d = gid & 1023;
  int m = (gid >> 10) % MEMN;
  int b = (gid >> 10) / MEMN;
  trace[(size_t)b*TRACE_SLOTS*D_MODEL + (size_t)m*D_MODEL + d] = st[d*MEMN + m];
}

__global__ void k_init_ao(const float* __restrict__ sa, const int2* __restrict__ pairs,
                          float* __restrict__ ao){
  int p = blockIdx.x*256 + threadIdx.x;
  if (p >= SO_SZ) return;
  int b = blockIdx.y;
  int2 ij = pairs[p];
  ao[(size_t)b*SO_SZ + p] = sa[ij.x]*sa[ij.y];
}

// out_w (fp32 [32896][1968]) -> Wh (fp16 [32896][1984], zero-padded). One thread = 16 halfs.
__global__ void k_convw(const float* __restrict__ W, half_t* __restrict__ Wh){
  int gid = blockIdx.x*256 + threadIdx.x;
  if (gid >= SO_SZ*WCHUNKS) return;
  int row = gid / WCHUNKS, ch = gid - row*WCHUNKS;
  int c0 = ch*16;
  half_t* dst = Wh + (size_t)row*WHLD + c0;
  if (ch < 123){
    const float4* src = (const float4*)(W + (size_t)row*NCLS + c0);
    float4 f0 = src[0], f1 = src[1], f2 = src[2], f3 = src[3];
    half8 h0, h1;
    h0[0]=(half_t)f0.x; h0[1]=(half_t)f0.y; h0[2]=(half_t)f0.z; h0[3]=(half_t)f0.w;
    h0[4]=(half_t)f1.x; h0[5]=(half_t)f1.y; h0[6]=(half_t)f1.z; h0[7]=(half_t)f1.w;
    h1[0]=(half_t)f2.x; h1[1]=(half_t)f2.y; h1[2]=(half_t)f2.z; h1[3]=(half_t)f2.w;
    h1[4]=(half_t)f3.x; h1[5]=(half_t)f3.y; h1[6]=(half_t)f3.z; h1[7]=(half_t)f3.w;
    *(half8*)dst = h0; *(half8*)(dst+8) = h1;
  } else {
    half8 zz;
#pragma unroll
    for (int j = 0; j < 8; j++) zz[j] = (half_t)0.f;
    *(half8*)dst = zz; *(half8*)(dst+8) = zz;
  }
}

// ---- colsum 2-stage (latency fix): part[kz][col] = sum_{k in chunk} vec[k]*W[k*ldw+col] ----
__global__ void k_colsumP(const float* __restrict__ vec, const float* __restrict__ W,
                          int ldw, float* __restrict__ part, int N){
  int col = blockIdx.x*256 + threadIdx.x;
  int kz = blockIdx.y;                       // 16 chunks of 32
  if (col >= N) return;
  float s = 0.f;
#pragma unroll
  for (int k = kz*32; k < kz*32 + 32; k++)
    s = fmaf(vec[k], W[(size_t)k*ldw + col], s);
  part[(size_t)kz*N + col] = s;
}

__global__ void k_colsumR(const float* __restrict__ part, const float* __restrict__ addb,
                          float* __restrict__ out, int N){
  int col = blockIdx.x*256 + threadIdx.x;
  if (col >= N) return;
  float s = addb[col];
#pragma unroll
  for (int z = 0; z < 16; z++) s += part[(size_t)z*N + col];
  out[col] = s;
}

// ---- fp16 MFMA GEMM (generalized): C[M,ldc-cols N] = Ah[M][ldah] @ Wh16[K][ldw] + bias ----
__global__ __launch_bounds__(256)
void k_pgemm(const half_t* __restrict__ Ah, int ldah,
             const half_t* __restrict__ Wh16, int ldw, const float* __restrict__ bias,
             float* __restrict__ C, int ldc, int ksteps){
  __shared__ half_t As[2][128*64];
  __shared__ half_t Ws[2][64*66];
  const int tid = threadIdx.x;
  const int nb0 = blockIdx.x * 64;
  const int row0 = blockIdx.y * 128;
  const int l = tid & 63, wv = tid >> 6;
  const int mw = (wv >> 1) * 64, nw = (wv & 1) * 32;
  const int c = l & 15, g = l >> 4;

  f32x4v acc[4][2];
#pragma unroll
  for (int i = 0; i < 4; i++)
#pragma unroll
    for (int j2 = 0; j2 < 2; j2++)
#pragma unroll
      for (int r = 0; r < 4; r++) acc[i][j2][r] = 0.f;

  auto stage = [&](int s, int buf){
#pragma unroll
    for (int it = 0; it < 4; it++){
      int ch = tid + it*256;
      int m = ch >> 3, kl = (ch & 7)*8;
      half8 v = *(const half8*)(Ah + (size_t)(row0+m)*ldah + s*64 + kl);
      *(half8*)((char*)(&As[buf][0]) + swzA(ch*16)) = v;
    }
    {
      int k = tid >> 2, cs = (tid & 3) * 16;
      const half_t* wr = Wh16 + (size_t)(s*64 + k) * ldw + nb0 + cs;
      char* dst = (char*)(&Ws[buf][0]) + (size_t)(k*66 + cs) * 2;
      union { half8 v; unsigned int u[4]; } p0, p1;
      p0.v = *(const half8*)wr; p1.v = *(const half8*)(wr + 8);
#pragma unroll
      for (int q = 0; q < 4; q++){
        ((unsigned int*)dst)[q]        = p0.u[q];
        ((unsigned int*)(dst + 16))[q] = p1.u[q];
      }
    }
  };

  stage(0, 0);
  __syncthreads();
  for (int s = 0; s < ksteps; s++){
    int buf = s & 1;
    if (s + 1 < ksteps) stage(s+1, buf^1);
#pragma unroll
    for (int h = 0; h < 2; h++){
      half8 a8[4];
#pragma unroll
      for (int mb = 0; mb < 4; mb++)
        a8[mb] = *(const half8*)((const char*)(&As[buf][0]) +
                   swzA(((mw + mb*16 + c)*64 + h*32 + g*8)*2));
#pragma unroll
      for (int nb = 0; nb < 2; nb++){
        half8 b8;
        const half_t* wp = &Ws[buf][(h*32 + g*8)*66 + nw + nb*16 + c];
#pragma unroll
        for (int j = 0; j < 8; j++) b8[j] = wp[j*66];
#pragma unroll
        for (int mb = 0; mb < 4; mb++)
          acc[mb][nb] = __builtin_amdgcn_mfma_f32_16x16x32_f16(a8[mb], b8, acc[mb][nb], 0, 0, 0);
      }
    }
    __syncthreads();
  }
#pragma unroll
  for (int mb = 0; mb < 4; mb++)
#pragma unroll
    for (int nb = 0; nb < 2; nb++){
      int m = mw + mb*16 + g*4;
      int n = nb0 + nw + nb*16 + c;
      float bv = bias ? bias[n] : 0.f;
#pragma unroll
      for (int r = 0; r < 4; r++)
        C[(size_t)(row0 + m + r) * ldc + n] = acc[mb][nb][r] + bv;
    }
}

// ---- syn fp16 MFMA GEMM ----
__global__ __launch_bounds__(256)
void k_syn16(const half_t* __restrict__ Ah, const half_t* __restrict__ Wh16,
             float* __restrict__ outp){
  __shared__ half_t As[2][128*64];
  __shared__ half_t Ws[2][64*66];
  const int tid = threadIdx.x;
  const int nb0 = blockIdx.x * 64;
  const int z = blockIdx.y;
  const int l = tid & 63, wv = tid >> 6;
  const int mw = (wv >> 1) * 64, nw = (wv & 1) * 32;
  const int c = l & 15, g = l >> 4;
  const int kbase = z * 256;

  f32x4v acc[4][2];
#pragma unroll
  for (int i = 0; i < 4; i++)
#pragma unroll
    for (int j2 = 0; j2 < 2; j2++)
#pragma unroll
      for (int r = 0; r < 4; r++) acc[i][j2][r] = 0.f;

  auto stage = [&](int s, int buf){
#pragma unroll
    for (int it = 0; it < 4; it++){
      int ch = tid + it*256;
      int m = ch >> 3, kl = (ch & 7)*8;
      half8 v = *(const half8*)(Ah + (size_t)m*1536 + kbase + s*64 + kl);
      *(half8*)((char*)(&As[buf][0]) + swzA(ch*16)) = v;
    }
    {
      int k = tid >> 2, cs = (tid & 3) * 16;
      const half_t* wr = Wh16 + (size_t)(kbase + s*64 + k) * 2048 + nb0 + cs;
      char* dst = (char*)(&Ws[buf][0]) + (size_t)(k*66 + cs) * 2;
      union { half8 v; unsigned int u[4]; } p0, p1;
      p0.v = *(const half8*)wr; p1.v = *(const half8*)(wr + 8);
#pragma unroll
      for (int q = 0; q < 4; q++){
        ((unsigned int*)dst)[q]        = p0.u[q];
        ((unsigned int*)(dst + 16))[q] = p1.u[q];
      }
    }
  };

  stage(0, 0);
  __syncthreads();
  for (int s = 0; s < 4; s++){
    int buf = s & 1;
    if (s + 1 < 4) stage(s+1, buf^1);
#pragma unroll
    for (int h = 0; h < 2; h++){
      half8 a8[4];
#pragma unroll
      for (int mb = 0; mb < 4; mb++)
        a8[mb] = *(const half8*)((const char*)(&As[buf][0]) +
                   swzA(((mw + mb*16 + c)*64 + h*32 + g*8)*2));
#pragma unroll
      for (int nb = 0; nb < 2; nb++){
        half8 b8;
        const half_t* wp = &Ws[buf][(h*32 + g*8)*66 + nw + nb*16 + c];
#pragma unroll
        for (int j = 0; j < 8; j++) b8[j] = wp[j*66];
#pragma unroll
        for (int mb = 0; mb < 4; mb++)
          acc[mb][nb] = __builtin_amdgcn_mfma_f32_16x16x32_f16(a8[mb], b8, acc[mb][nb], 0, 0, 0);
      }
    }
    __syncthreads();
  }
  float* pz = outp + (size_t)z * BB * 2048;
#pragma unroll
  for (int mb = 0; mb < 4; mb++)
#pragma unroll
    for (int nb = 0; nb < 2; nb++){
      int m = mw + mb*16 + g*4;
      int n = nb0 + nw + nb*16 + c;
#pragma unroll
      for (int r = 0; r < 4; r++)
        pz[(size_t)(m + r) * 2048 + n] = acc[mb][nb][r];
    }
}

// ---- fused syncA + q-GEMM (4-way K-split, fp16 W) ----
__global__ void k_gemmq(const float* __restrict__ act,
                        const float* __restrict__ r_a, const int2* __restrict__ pairsA,
                        const float* __restrict__ aaIn, float* __restrict__ aaOut,
                        const half_t* __restrict__ Wh, float* __restrict__ qpart, int t){
  constexpr int KC = 32;
  const int tid = threadIdx.x;
  const int col = blockIdx.x*256 + tid;
  const int row0 = blockIdx.y*4;
  const int z = blockIdx.z;
  const int kstart = z*544;
  const int kend = min(SA_SZ, kstart + 544);
  const bool writer = (blockIdx.x == 0);
  __shared__ float As[4][KC];
  float acc[4] = {0.f,0.f,0.f,0.f};
  for (int kk = kstart; kk < kend; kk += KC){
    __syncthreads();
    if (tid < 4*KC){
      int r = tid >> 5, k = tid & 31;
      int p = kk + k;
      int b = row0 + r;
      int2 ij = pairsA[p];
      const float* ab = act + (size_t)b*D_MODEL + (D_MODEL - N_SA);
      float rv = r_a[p];
      size_t idx = (size_t)b*SA_SZ + p;
      float a = fmaf(rv, aaIn[idx], ab[ij.x]*ab[ij.y]);
      if (writer) aaOut[idx] = a;
      float bb = 0.f;
      for (int i = 0; i <= t; i++) bb = fmaf(rv, bb, 1.f);
      As[r][k] = a / sqrtf(bb);
    }
    __syncthreads();
#pragma unroll
    for (int k = 0; k < KC; k++){
      float w = (float)Wh[(size_t)(kk+k)*D_IN + col];
#pragma unroll
      for (int r = 0; r < 4; r++) acc[r] = fmaf(As[r][k], w, acc[r]);
    }
  }
#pragma unroll
  for (int r = 0; r < 4; r++)
    qpart[(size_t)z*BB*D_IN + (size_t)(row0+r)*D_IN + col] = acc[r];
}

// ---- fused syn GEMM fp32 fallback ----
__global__ void k_gemm2srcZ(const float* __restrict__ A1, const float* __restrict__ A2,
                            const float* __restrict__ W1, const float* __restrict__ W2,
                            float* __restrict__ outp){
  constexpr int MB = 8, KC = 32;
  const int tid = threadIdx.x;
  const int col = blockIdx.x*256 + tid;
  const int row0 = blockIdx.y*MB;
  const int z = blockIdx.z;
  __shared__ float As[MB][KC];
  float acc[MB];
#pragma unroll
  for (int r = 0; r < MB; r++) acc[r] = 0.f;
  for (int kk = z*256; kk < z*256 + 256; kk += KC){
    __syncthreads();
    for (int idx = tid; idx < MB*KC; idx += 256){
      int r = idx / KC, k = idx % KC;
      int kg = kk + k;
      As[r][k] = (kg < D_IN) ? A1[(size_t)(row0+r)*D_IN + kg]
                             : A2[(size_t)(row0+r)*D_MODEL + kg - D_IN];
    }
    __syncthreads();
    const float* Wp = (kk < D_IN) ? W1 : W2;
#pragma unroll
    for (int k = 0; k < KC; k++){
      float w = Wp[(size_t)(kk+k)*2048 + col];
#pragma unroll
      for (int r = 0; r < MB; r++) acc[r] = fmaf(As[r][k], w, acc[r]);
    }
  }
#pragma unroll
  for (int r = 0; r < MB; r++)
    outp[(size_t)z*BB*2048 + (size_t)(row0+r)*2048 + col] = acc[r];
}

// ---------------- LayerNorm (block per row), fp32 in -> fp16 out ----------------
__global__ void k_ln_h(const float* __restrict__ X, const float* __restrict__ g,
                       const float* __restrict__ bta, half_t* __restrict__ Y, int D){
  const int row = blockIdx.x, tid = threadIdx.x;
  __shared__ float red[256];
  const float* xr = X + (size_t)row*D;
  float s = 0.f;
  for (int c = tid; c < D; c += 256) s += xr[c];
  float mean = bsum256(s, red) / (float)D;
  float s2 = 0.f;
  for (int c = tid; c < D; c += 256){ float d = xr[c]-mean; s2 += d*d; }
  float var = bsum256(s2, red) / (float)D;
  float inv = 1.f / sqrtf(var + 1e-5f);
  half_t* yr = Y + (size_t)row*D;
  for (int c = tid; c < D; c += 256) yr[c] = (half_t)((xr[c]-mean)*inv*g[c] + bta[c]);
}

// ---- sum 6 synpart + bias2 -> GLU -> LN -> trace slot ----
__global__ void k_glu_ln(const float* __restrict__ synpart, const float* __restrict__ bias2,
                         const float* __restrict__ g, const float* __restrict__ bta,
                         float* __restrict__ traceSlot){
  const int b = blockIdx.x, tid = threadIdx.x;
  __shared__ float vals[D_MODEL];
  __shared__ float red[256];
  for (int c = tid; c < 1024; c += 256){
    float a = bias2[c], gg = bias2[c+1024];
#pragma unroll
    for (int z = 0; z < SYNZ; z++){
      const float* sp = synpart + (size_t)z*BB*2048 + (size_t)b*2048;
      a  += sp[c];
      gg += sp[c+1024];
    }
    vals[c] = a * sigmoidf_(gg);
  }
  __syncthreads();
  float s = 0.f;
  for (int c = tid; c < 1024; c += 256) s += vals[c];
  float mean = bsum256(s, red) * (1.f/1024.f);
  float s2 = 0.f;
  for (int c = tid; c < 1024; c += 256){ float d = vals[c]-mean; s2 += d*d; }
  float var = bsum256(s2, red) * (1.f/1024.f);
  float inv = 1.f / sqrtf(var + 1e-5f);
  float* out = traceSlot + (size_t)b*(TRACE_SLOTS*D_MODEL);
  for (int c = tid; c < 1024; c += 256) out[c] = (vals[c]-mean)*inv*g[c] + bta[c];
}

// ---------------- attention: writes obuf (fp32) AND Ah16 head (fp16) ----------------
__global__ void k_attn(const float* __restrict__ qpart, const float* __restrict__ bqf,
                       const float* __restrict__ Km, const float* __restrict__ Vm,
                       float* __restrict__ o, half_t* __restrict__ Ah16){
  const int bh = blockIdx.x, b = bh >> 3, h = bh & 7;
  const int tid = threadIdx.x;
  __shared__ float qs[DHH];
  __shared__ float attn[SS];
  __shared__ float red[128];
  if (tid < DHH){
    int d = h*DHH + tid;
    float qv = bqf[d];
#pragma unroll
    for (int z = 0; z < 4; z++) qv += qpart[(size_t)z*BB*D_IN + (size_t)b*D_IN + d];
    qs[tid] = qv;
  }
  __syncthreads();
  float sc = -1e30f;
  if (tid < SS){
    const float* kp = Km + ((size_t)(b*SS+tid)*HEADS + h)*DHH;
    float d = 0.f;
#pragma unroll
    for (int i = 0; i < DHH; i++) d = fmaf(qs[i], kp[i], d);
    sc = d * 0.125f;
  }
  red[tid] = sc; __syncthreads();
  for (int s2 = 64; s2 > 0; s2 >>= 1){ if (tid < s2) red[tid] = fmaxf(red[tid], red[tid+s2]); __syncthreads(); }
  float m = red[0]; __syncthreads();
  float e = (tid < SS) ? expf(sc - m) : 0.f;
  red[tid] = e; __syncthreads();
  for (int s2 = 64; s2 > 0; s2 >>= 1){ if (tid < s2) red[tid] += red[tid+s2]; __syncthreads(); }
  float inv = 1.f / red[0]; __syncthreads();
  if (tid < SS) attn[tid] = e * inv;
  __syncthreads();
  if (tid < DHH){
    const float* vp = Vm + ((size_t)(b*SS)*HEADS + h)*DHH + tid;
    float acc = 0.f;
    for (int s2 = 0; s2 < SS; s2++) acc = fmaf(attn[s2], vp[(size_t)s2*D_IN], acc);
    int d = h*DHH + tid;
    o[(size_t)b*D_IN + d] = acc;
    Ah16[(size_t)b*1536 + d] = (half_t)acc;
  }
}

// ---- neuron update; writes act (fp32) AND Ah16 tail (fp16) ----
__global__ void k_neuron(const float* __restrict__ trace,
                         const float* __restrict__ tp1w, const float* __restrict__ tp1b,
                         const float* __restrict__ tp2w, const float* __restrict__ tp2b,
                         float* __restrict__ act, half_t* __restrict__ Ah16, int t){
  int gid = blockIdx.x*256 + threadIdx.x;
  if (gid >= BB*D_MODEL) return;
  int b = gid >> 10, d = gid & 1023;
  const float* tr = trace + (size_t)b*(TRACE_SLOTS*D_MODEL) + (size_t)(t+1)*D_MODEL + d;
  float trv[MEMN];
#pragma unroll
  for (int m = 0; m < MEMN; m++) trv[m] = tr[(size_t)m*D_MODEL];
  float o0 = tp2b[d*2+0], o1 = tp2b[d*2+1];
#pragma unroll
  for (int j = 0; j < 16; j++){
    const float* wpj = tp1w + (size_t)j*1024 + d;
    const float* wpg = tp1w + (size_t)(j+16)*1024 + d;
    float hj = tp1b[d*32 + j];
    float hg = tp1b[d*32 + j + 16];
#pragma unroll
    for (int m = 0; m < MEMN; m++){
      float tv = trv[m];
      hj = fmaf(tv, wpj[(size_t)m*32*1024], hj);
      hg = fmaf(tv, wpg[(size_t)m*32*1024], hg);
    }
    float hgv = hj * sigmoidf_(hg);
    o0 = fmaf(hgv, tp2w[(size_t)(j*2+0)*1024 + d], o0);
    o1 = fmaf(hgv, tp2w[(size_t)(j*2+1)*1024 + d], o1);
  }
  float v = o0 * sigmoidf_(o1);
  act[gid] = v;
  Ah16[(size_t)b*1536 + 512 + d] = (half_t)v;
}

// ---------------- syncO ----------------
__global__ void k_syncO(const float* __restrict__ act, const float* __restrict__ rv,
                        const int2* __restrict__ pairs, float* __restrict__ ao,
                        half_t* __restrict__ syncv, int t){
  int p = blockIdx.x*256 + threadIdx.x;
  if (p >= SO_SZ) return;
  int b = blockIdx.y;
  int2 ij = pairs[p];
  const float* ab = act + (size_t)b*D_MODEL;
  float r = rv[p];
  size_t idx = (size_t)b*SO_SZ + p;
  float a = fmaf(r, ao[idx], ab[ij.x]*ab[ij.y]);
  ao[idx] = a;
  float bb = 1.f;
  for (int i = 0; i <= t; i++) bb = fmaf(r, bb, 1.f);
  syncv[idx] = (half_t)(a / sqrtf(bb));
}

// ---------------- big GEMM, fp16-W path ----------------
__global__ __launch_bounds__(256)
void k_bigemm2h(const half_t* __restrict__ Ah, const half_t* __restrict__ Wh,
                float* __restrict__ part){
  __shared__ half_t As[2][128*64];
  __shared__ half_t Ws[2][64*66];
  const int tid = threadIdx.x;
  const int z = blockIdx.y;
  const int nb0 = blockIdx.x * BGN;
  const int l = tid & 63, wv = tid >> 6;
  const int mw = (wv >> 1) * 64, nw = (wv & 1) * 32;
  const int c = l & 15, g = l >> 4;
  const int k0 = z * BGKLEN;

  f32x4v acc[4][2];
#pragma unroll
  for (int i = 0; i < 4; i++)
#pragma unroll
    for (int j2 = 0; j2 < 2; j2++)
#pragma unroll
      for (int r = 0; r < 4; r++) acc[i][j2][r] = 0.f;

  auto stage = [&](int s, int buf){
    const int kv = min(64, BGKLEN - s*64);
#pragma unroll
    for (int it = 0; it < 4; it++){
      int ch = tid + it*256;
      int m = ch >> 3, kg = ch & 7, kl = kg*8;
      half8 v;
      if (kl < kv) v = *(const half8*)(Ah + (size_t)m*SO_SZ + k0 + s*64 + kl);
      else {
#pragma unroll
        for (int j = 0; j < 8; j++) v[j] = (half_t)0.f;
      }
      *(half8*)((char*)(&As[buf][0]) + swzA(ch*16)) = v;
    }
    {
      int k = tid >> 2, cs = (tid & 3) * 16;
      const half_t* wr = Wh + (size_t)(k0 + s*64 + k) * WHLD + nb0 + cs;
      char* dst = (char*)(&Ws[buf][0]) + (size_t)(k*66 + cs) * 2;
      union { half8 v; unsigned int u[4]; } p0, p1;
      if (k < kv){ p0.v = *(const half8*)wr; p1.v = *(const half8*)(wr + 8); }
      else {
#pragma unroll
        for (int j = 0; j < 8; j++){ p0.v[j] = (half_t)0.f; p1.v[j] = (half_t)0.f; }
      }
#pragma unroll
      for (int q = 0; q < 4; q++){
        ((unsigned int*)dst)[q]        = p0.u[q];
        ((unsigned int*)(dst + 16))[q] = p1.u[q];
      }
    }
  };

  stage(0, 0);
  __syncthreads();
  for (int s = 0; s < BGSTEPS; s++){
    int buf = s & 1;
    if (s + 1 < BGSTEPS) stage(s+1, buf^1);
#pragma unroll
    for (int h = 0; h < 2; h++){
      half8 a8[4];
#pragma unroll
      for (int mb = 0; mb < 4; mb++)
        a8[mb] = *(const half8*)((const char*)(&As[buf][0]) +
                   swzA(((mw + mb*16 + c)*64 + h*32 + g*8)*2));
#pragma unroll
      for (int nb = 0; nb < 2; nb++){
        half8 b8;
        const half_t* wp = &Ws[buf][(h*32 + g*8)*66 + nw + nb*16 + c];
#pragma unroll
        for (int j = 0; j < 8; j++) b8[j] = wp[j*66];
#pragma unroll
        for (int mb = 0; mb < 4; mb++)
          acc[mb][nb] = __builtin_amdgcn_mfma_f32_16x16x32_f16(a8[mb], b8, acc[mb][nb], 0, 0, 0);
      }
    }
    __syncthreads();
  }
  float* pz = part + (size_t)z * 128 * NPART;
#pragma unroll
  for (int mb = 0; mb < 4; mb++)
#pragma unroll
    for (int nb = 0; nb < 2; nb++){
      int m = mw + mb*16 + g*4;
      int n = nb0 + nw + nb*16 + c;
#pragma unroll
      for (int r = 0; r < 4; r++)
        pz[(size_t)(m + r) * NPART + n] = acc[mb][nb][r];
    }
}

// ---------------- combine partials + bias, write preds + certainties ----------------
__global__ void k_output(const float* __restrict__ part, const float* __restrict__ outb,
                         float* __restrict__ dout, int t){
  const int b = blockIdx.x, tid = threadIdx.x;
  __shared__ float pred[NCLS];
  __shared__ float red[256];
  float lmax = -1e30f;
  for (int c = tid; c < NCLS; c += 256){
    float s = outb[c];
    const float* pp = part + (size_t)b*NPART + c;
#pragma unroll
    for (int z = 0; z < BGKS; z++) s += pp[(size_t)z*128*NPART];
    pred[c] = s;
    dout[((size_t)b*NCLS + c)*NITER + t] = s;
    lmax = fmaxf(lmax, s);
  }
  red[tid] = lmax; __syncthreads();
  for (int s2 = 128; s2 > 0; s2 >>= 1){ if (tid < s2) red[tid] = fmaxf(red[tid], red[tid+s2]); __syncthreads(); }
  float m = red[0]; __syncthreads();
  float se = 0.f;
  for (int c = tid; c < NCLS; c += 256) se += expf(pred[c]-m);
  float Z = bsum256(se, red);
  float logZ = m + logf(Z);
  float ent = 0.f;
  for (int c = tid; c < NCLS; c += 256){ float lp = pred[c]-logZ; ent += expf(lp)*lp; }
  float E = bsum256(ent, red);
  if (tid == 0){
    float ne = -E * (1.f/logf((float)NCLS));
    float* cp = dout + (size_t)BB*NCLS*NITER + (size_t)b*2*NITER + t;
    cp[0]     = ne;
    cp[NITER] = 1.f - ne;
  }
}

// ---------------- launch ----------------
extern "C" void kernel_launch(void* const* d_in, const int* in_sizes, int n_in,
                              void* d_out, int out_size, void* d_ws, size_t ws_size,
                              hipStream_t stream){
  const int*   x           = (const int*)  d_in[0];
  const float* emb         = (const float*)d_in[1];
  const float* kv_w        = (const float*)d_in[2];
  const float* kv_b        = (const float*)d_in[3];
  const float* kv_ln_g     = (const float*)d_in[4];
  const float* kv_ln_b     = (const float*)d_in[5];
  const float* q_w         = (const float*)d_in[6];
  const float* q_b         = (const float*)d_in[7];
  const float* in_proj_w   = (const float*)d_in[8];
  const float* in_proj_b   = (const float*)d_in[9];
  const float* out_proj_w  = (const float*)d_in[10];
  const float* out_proj_b  = (const float*)d_in[11];
  const float* syn_w       = (const float*)d_in[12];
  const float* syn_b       = (const float*)d_in[13];
  const float* syn_ln_g    = (const float*)d_in[14];
  const float* syn_ln_b    = (const float*)d_in[15];
  const float* tp1_w       = (const float*)d_in[16];
  const float* tp1_b       = (const float*)d_in[17];
  const float* tp2_w       = (const float*)d_in[18];
  const float* tp2_b       = (const float*)d_in[19];
  const float* start_act   = (const float*)d_in[20];
  const float* start_trace = (const float*)d_in[21];
  const float* decay_action= (const float*)d_in[22];
  const float* decay_out   = (const float*)d_in[23];
  const float* out_w       = (const float*)d_in[24];
  const float* out_b       = (const float*)d_in[25];
  float* dout = (float*)d_out;

  // ---- workspace layout ----
  float* w = (float*)d_ws;
  size_t off = 0;
  auto alloc = [&](size_t n){ n = (n + 3) & ~(size_t)3; float* p = w + off; off += n; return p; };
  float* region0 = alloc((size_t)BGKS*128*NPART);    // setup: embx_h/kvh | iter: synpart+part
  float* region1 = alloc((size_t)ROWS*D_IN);         // setup: kvbuf | iter: a_o
  float* Kmat    = alloc((size_t)ROWS*D_IN);
  float* Vmat    = alloc((size_t)ROWS*D_IN);
  float* trace   = alloc((size_t)BB*TRACE_SLOTS*D_MODEL);
  half_t* sync_oh= (half_t*)alloc((size_t)BB*SO_SZ/2);
  float* a_aP    = alloc((size_t)2*BB*SA_SZ);
  float* act     = alloc((size_t)BB*D_MODEL);
  float* qpart   = alloc((size_t)4*BB*D_IN);
  float* obuf    = alloc((size_t)BB*D_IN);
  float* qfwPad  = alloc((size_t)QPAD*D_IN);         // fp32 q_w @ Wq (padded rows)
  float* Wf2     = alloc((size_t)D_IN*2048);
  float* bqf     = alloc(D_IN);
  float* bias2   = alloc(2048);
  float* colpart = alloc((size_t)16*2048);
  float* r_a     = alloc(SA_SZ);
  float* r_o     = alloc(SO_SZ);
  int2*  pairsA  = (int2*)alloc(2*SA_SZ);
  int2*  pairsO  = (int2*)alloc(2*SO_SZ);
  half_t* embh   = (half_t*)alloc((size_t)VOCAB*TED/2);
  half_t* kvwh   = (half_t*)alloc((size_t)TED*D_IN/2);
  half_t* Wkh    = (half_t*)alloc((size_t)D_IN*D_IN/2);
  half_t* Wvh    = (half_t*)alloc((size_t)D_IN*D_IN/2);
  half_t* Wqh    = (half_t*)alloc((size_t)D_IN*D_IN/2);
  half_t* oph    = (half_t*)alloc((size_t)D_IN*D_IN/2);
  half_t* synth  = (half_t*)alloc((size_t)D_IN*2048/2);
  half_t* qwh    = (half_t*)alloc((size_t)QPAD*D_IN/2);
  half_t* qfwh   = (half_t*)alloc((size_t)SA_SZ*D_IN/2);
  half_t* Wh     = (half_t*)alloc(((size_t)SO_SZ*WHLD)/2);
  half_t* Ah16   = (half_t*)alloc((size_t)BB*1536/2);
  half_t* Wsynh  = (half_t*)alloc((size_t)1536*2048/2);
  const bool use_syn16 = (off * sizeof(float) <= ws_size);

  half_t* embx_h = (half_t*)region0;
  half_t* kvh    = (half_t*)region0;
  float* part    = region0;
  float* synpart = region0;
  float* kvbuf = region1;
  float* a_o   = region1;

  dim3 blk(256);

  // ---- setup ----
  k_convall<<<(CV7+255)/256, blk, 0, stream>>>(emb, kv_w, in_proj_w, out_proj_w, syn_w, q_w,
                                               embh, kvwh, Wkh, Wvh, Wqh, oph, synth, qwh);
  k_embed_h<<<(ROWS*(TED/8)+255)/256, blk, 0, stream>>>(x, embh, embx_h);
  k_pgemm<<<dim3(8, ROWS/128), blk, 0, stream>>>(embx_h, TED, kvwh, D_IN, kv_b, kvbuf, D_IN, TED/64);
  k_ln_h<<<ROWS, blk, 0, stream>>>(kvbuf, kv_ln_g, kv_ln_b, kvh, D_IN);
  k_pgemm<<<dim3(8, ROWS/128), blk, 0, stream>>>(kvh, D_IN, Wkh, D_IN, in_proj_b+512,  Kmat, D_IN, D_IN/64);
  k_pgemm<<<dim3(8, ROWS/128), blk, 0, stream>>>(kvh, D_IN, Wvh, D_IN, in_proj_b+1024, Vmat, D_IN, D_IN/64);
  k_pgemm<<<dim3(8, QPAD/128), blk, 0, stream>>>(qwh, D_IN, Wqh, D_IN, nullptr, qfwPad, D_IN, D_IN/64);
  k_pgemm<<<dim3(32, D_IN/128), blk, 0, stream>>>(oph, D_IN, synth, 2048, nullptr, Wf2, 2048, D_IN/64);
  k_conv<<<(SA_SZ*D_IN+255)/256, blk, 0, stream>>>(qfwPad, qfwh, SA_SZ*D_IN);
  k_colsumP<<<dim3(2, 16), blk, 0, stream>>>(q_b, in_proj_w, 1536, colpart, D_IN);
  k_colsumR<<<2, blk, 0, stream>>>(colpart, in_proj_b, bqf, D_IN);
  k_colsumP<<<dim3(8, 16), blk, 0, stream>>>(out_proj_b, syn_w, 2048, colpart, 2048);
  k_colsumR<<<8, blk, 0, stream>>>(colpart, syn_b, bias2, 2048);
  k_convw<<<(SO_SZ*WCHUNKS+255)/256, blk, 0, stream>>>(out_w, Wh);
  if (use_syn16)
    k_convsyn<<<(1536*2048+255)/256, blk, 0, stream>>>(Wf2, syn_w, Wsynh);
  k_init_pairs<<<(SA_SZ+255)/256, blk, 0, stream>>>(N_SA, SA_SZ, decay_action, pairsA, r_a);
  k_init_pairs<<<(SO_SZ+255)/256, blk, 0, stream>>>(N_SO, SO_SZ, decay_out,    pairsO, r_o);
  k_init_act<<<(BB*D_MODEL+255)/256, blk, 0, stream>>>(start_act, act, Ah16);
  k_zero<<<(2*BB*SA_SZ+255)/256, blk, 0, stream>>>(a_aP, 2*BB*SA_SZ);
  k_init_trace<<<(BB*MEMN*D_MODEL+255)/256, blk, 0, stream>>>(start_trace, trace);
  k_init_ao<<<dim3((SO_SZ+255)/256, BB), blk, 0, stream>>>(start_act, pairsO, a_o);

  // ---- 16 recurrent iterations ----
  for (int t = 0; t < NITER; t++){
    float* aaIn  = a_aP + (size_t)(t & 1)*BB*SA_SZ;
    float* aaOut = a_aP + (size_t)((t+1) & 1)*BB*SA_SZ;
    k_gemmq<<<dim3(2, 32, 4), blk, 0, stream>>>(act, r_a, pairsA, aaIn, aaOut, qfwh, qpart, t);
    k_attn<<<BB*HEADS, 128, 0, stream>>>(qpart, bqf, Kmat, Vmat, obuf, Ah16);
    if (use_syn16)
      k_syn16<<<dim3(32, SYNZ), blk, 0, stream>>>(Ah16, Wsynh, synpart);
    else
      k_gemm2srcZ<<<dim3(8, 16, SYNZ), blk, 0, stream>>>(obuf, act, Wf2, syn_w, synpart);
    k_glu_ln<<<BB, blk, 0, stream>>>(synpart, bias2, syn_ln_g, syn_ln_b, trace + (size_t)(MEMN+t)*D_MODEL);
    k_neuron<<<(BB*D_MODEL+255)/256, blk, 0, stream>>>(trace, tp1_w, tp1_b, tp2_w, tp2_b, act, Ah16, t);
    k_syncO<<<dim3((SO_SZ+255)/256, BB), blk, 0, stream>>>(act, r_o, pairsO, a_o, sync_oh, t);
    k_bigemm2h<<<dim3(31, BGKS), blk, 0, stream>>>(sync_oh, Wh, part);
    k_output<<<BB, blk, 0, stream>>>(part, out_b, dout, t);
  }
}